// Round 1
// 1371.579 us; speedup vs baseline: 1.3875x; 1.3875x over previous
//
#include <hip/hip_runtime.h>
#include <math.h>

// ---------------------------------------------------------------------------
// VQ-VAE forward. Round 8: decoder ConvTranspose layers 1-3 converted from
// scalar-FMA LDS kernels (483 us, MfmaUtil=0) to bf16 hi/lo split MFMA
// implicit GEMM via the 4-parity decomposition:
//   out(2i+dy, 2j+dx) = sum_ci sum_{r,s in {0,1}}
//       in(ci, i-1+dy+r, j-1+dx+s) * w[ci][co][3-dy-2r][3-dx-2s]
// Each parity plane = stride-1 2x2 conv = GEMM with K = 4*Cin.
// Encoder path identical to proven R7 kernel.
// ---------------------------------------------------------------------------

typedef __attribute__((ext_vector_type(8))) short bf16x8;
typedef __attribute__((ext_vector_type(4))) float f32x4;
union FragU { unsigned u[4]; bf16x8 v; };

__device__ __forceinline__ unsigned bf16_rne(unsigned u) {
    return (u + 0x7FFFu + ((u >> 16) & 1u)) >> 16;
}
// pack fp32 -> u32: low16 = bf16(v), high16 = bf16(v - bf16(v))
__device__ __forceinline__ unsigned pack_split(float v) {
    unsigned u = __builtin_bit_cast(unsigned, v);
    unsigned hi = bf16_rne(u);
    float hif = __builtin_bit_cast(float, hi << 16);
    float r = v - hif;
    unsigned lo = bf16_rne(__builtin_bit_cast(unsigned, r));
    return hi | (lo << 16);
}

__global__ void __launch_bounds__(256) pack_tensor(
    const float* __restrict__ s, unsigned* __restrict__ d, int n)
{
    int i = blockIdx.x * 256 + threadIdx.x;
    if (i < n) d[i] = pack_split(s[i]);
}

// repack ConvTranspose weights (torch layout Cin,Cout,4,4) into
// wq[par][co][ci*4 + t], t = 2r+s, packed hi/lo. par = dy*2+dx.
template<int Cin, int Cout>
__global__ void __launch_bounds__(256) repack_wt(
    const float* __restrict__ w, unsigned* __restrict__ wq)
{
    constexpr int TOT = 16 * Cin * Cout;
    int idx = blockIdx.x * 256 + threadIdx.x;
    if (idx >= TOT) return;
    int t  = idx & 3;
    int ci = (idx >> 2) % Cin;
    int rest = (idx >> 2) / Cin;
    int co  = rest % Cout;
    int par = rest / Cout;
    int dy = par >> 1, dx = par & 1;
    int r = t >> 1, s = t & 1;
    int ky = 3 - dy - 2 * r;
    int kx = 3 - dx - 2 * s;
    float v = w[(((size_t)ci * Cout + co) * 4 + ky) * 4 + kx];
    wq[idx] = pack_split(v);
}

// ================= MFMA conv k=4 s=2 p=1 + ReLU (implicit GEMM) ============
// (encoder; unchanged from R7)
template<int Cin, int H, int W, int Cout, int PACKO>
__global__ void __launch_bounds__(256) conv4s2_mfma(
    const unsigned* __restrict__ xp, const unsigned* __restrict__ wp,
    const float* __restrict__ bias, float* __restrict__ y)
{
    constexpr int OH = H / 2, OW = W / 2;
    constexpr int LOG_OW = (OW == 64) ? 6 : (OW == 32) ? 5 : 4;
    constexpr int R   = 64 / OW;
    constexpr int RT  = 2 * R + 2;
    constexpr int CS  = W + 2;
    constexpr int XEL = 2 * RT * CS;
    constexpr int XIT = (XEL + 255) / 256;
    constexpr int K   = Cin * 16;
    constexpr int NC  = Cin / 2;
    constexpr int NB  = 128;
    constexpr int MBC = 32 * OH * OW / 64;

    __shared__ unsigned smem[8704];
    unsigned* raw = smem;
    unsigned* wb  = smem + ((XEL + 7) & ~7);

    int bid = blockIdx.x;
    int mb = bid % MBC, ng = bid / MBC;
    int oc0 = ng * NB;
    int m0 = mb * 64;
    int nimg = m0 / (OH * OW);
    int sp0 = m0 % (OH * OW);
    int oyb = sp0 >> LOG_OW;

    int tid  = threadIdx.x;
    int lane = tid & 63, wv = tid >> 6;
    int lm = lane & 15, q = lane >> 4;
    int n0w = wv * 32;

    const unsigned* xbase = xp + (size_t)nimg * Cin * H * W;

    int  goff[XIT];
    bool gok[XIT];
#pragma unroll
    for (int s = 0; s < XIT; ++s) {
        int i = tid + 256 * s;
        goff[s] = 0; gok[s] = false;
        if (i < XEL) {
            int lc = i % CS;
            int t2 = i / CS;
            int lr = t2 % RT;
            int c  = t2 / RT;
            int gr = 2 * oyb - 1 + lr;
            int gc = lc - 1;
            bool ok = ((unsigned)gr < (unsigned)H) && ((unsigned)gc < (unsigned)W);
            goff[s] = ok ? (c * H * W + gr * W + gc) : 0;
            gok[s]  = ok;
        }
    }
    const unsigned* wbase = wp + (size_t)(oc0 + (tid >> 5)) * K + (tid & 31);
    int wlds0 = (tid >> 5) * 36 + (tid & 31);

    f32x4 acc[4][2];
#pragma unroll
    for (int nt = 0; nt < 2; ++nt) {
        float b = bias[oc0 + n0w + nt * 16 + lm];
#pragma unroll
        for (int mt = 0; mt < 4; ++mt)
#pragma unroll
            for (int r = 0; r < 4; ++r) acc[mt][nt][r] = b;
    }

    unsigned pfa[XIT];
    unsigned pfb[16];

    auto load_chunk = [&](int ch) {
        const unsigned* cb = xbase + (size_t)(ch * 2) * (H * W);
#pragma unroll
        for (int s = 0; s < XIT; ++s) {
            unsigned v = 0;
            if (gok[s]) v = cb[goff[s]];
            pfa[s] = v;
        }
        const unsigned* wc = wbase + ch * 32;
#pragma unroll
        for (int s = 0; s < 16; ++s) pfb[s] = wc[(size_t)s * 8 * K];
    };
    auto store_chunk = [&]() {
#pragma unroll
        for (int s = 0; s < XIT; ++s) {
            int i = tid + 256 * s;
            if (i < XEL) raw[i] = pfa[s];
        }
#pragma unroll
        for (int s = 0; s < 16; ++s) wb[wlds0 + s * 288] = pfb[s];
    };

    load_chunk(0);
#pragma unroll 1
    for (int ch = 0; ch < NC; ++ch) {
        __syncthreads();
        store_chunk();
        __syncthreads();
        if (ch + 1 < NC) load_chunk(ch + 1);

        FragU bhi[2], blo[2];
#pragma unroll
        for (int nt = 0; nt < 2; ++nt) {
            const unsigned* bp = &wb[(n0w + nt * 16 + lm) * 36 + q * 8];
            uint4 p0 = *(const uint4*)bp;
            uint4 p1 = *(const uint4*)(bp + 4);
            unsigned e0 = p0.x, e1 = p0.y, e2 = p0.z, e3 = p0.w;
            unsigned e4 = p1.x, e5 = p1.y, e6 = p1.z, e7 = p1.w;
            bhi[nt].u[0] = (e0 & 0xffffu) | (e1 << 16);
            bhi[nt].u[1] = (e2 & 0xffffu) | (e3 << 16);
            bhi[nt].u[2] = (e4 & 0xffffu) | (e5 << 16);
            bhi[nt].u[3] = (e6 & 0xffffu) | (e7 << 16);
            blo[nt].u[0] = (e0 >> 16) | (e1 & 0xffff0000u);
            blo[nt].u[1] = (e2 >> 16) | (e3 & 0xffff0000u);
            blo[nt].u[2] = (e4 >> 16) | (e5 & 0xffff0000u);
            blo[nt].u[3] = (e6 >> 16) | (e7 & 0xffff0000u);
        }
#pragma unroll
        for (int mt = 0; mt < 4; ++mt) {
            int m = mt * 16 + lm;
            int oyl = m >> LOG_OW, oxl = m & (OW - 1);
            int c = q >> 1, rb = 2 * oyl + (q & 1) * 2;
            const unsigned* rp = &raw[(c * RT + rb) * CS + 2 * oxl];
            uint2 a0 = *(const uint2*)rp;
            uint2 a1 = *(const uint2*)(rp + 2);
            uint2 a2 = *(const uint2*)(rp + CS);
            uint2 a3 = *(const uint2*)(rp + CS + 2);
            FragU ahi, alo;
            ahi.u[0] = (a0.x & 0xffffu) | (a0.y << 16);
            ahi.u[1] = (a1.x & 0xffffu) | (a1.y << 16);
            ahi.u[2] = (a2.x & 0xffffu) | (a2.y << 16);
            ahi.u[3] = (a3.x & 0xffffu) | (a3.y << 16);
            alo.u[0] = (a0.x >> 16) | (a0.y & 0xffff0000u);
            alo.u[1] = (a1.x >> 16) | (a1.y & 0xffff0000u);
            alo.u[2] = (a2.x >> 16) | (a2.y & 0xffff0000u);
            alo.u[3] = (a3.x >> 16) | (a3.y & 0xffff0000u);
#pragma unroll
            for (int nt = 0; nt < 2; ++nt) {
                acc[mt][nt] = __builtin_amdgcn_mfma_f32_16x16x32_bf16(
                    ahi.v, bhi[nt].v, acc[mt][nt], 0, 0, 0);
                acc[mt][nt] = __builtin_amdgcn_mfma_f32_16x16x32_bf16(
                    ahi.v, blo[nt].v, acc[mt][nt], 0, 0, 0);
                acc[mt][nt] = __builtin_amdgcn_mfma_f32_16x16x32_bf16(
                    alo.v, bhi[nt].v, acc[mt][nt], 0, 0, 0);
            }
        }
    }

    __syncthreads();
    float* cs = (float*)smem;
#pragma unroll
    for (int mt = 0; mt < 4; ++mt)
#pragma unroll
        for (int nt = 0; nt < 2; ++nt) {
            int nl = n0w + nt * 16 + lm;
#pragma unroll
            for (int r = 0; r < 4; ++r)
                cs[nl * 68 + mt * 16 + q * 4 + r] = acc[mt][nt][r];
        }
    __syncthreads();
    {
        int nl = tid >> 1, half = tid & 1;
        size_t gb = ((size_t)(nimg * Cout + oc0 + nl)) * (OH * OW) + sp0 + half * 32;
#pragma unroll
        for (int i2 = 0; i2 < 8; ++i2) {
            float4 v = *(float4*)&cs[nl * 68 + half * 32 + 4 * i2];
            v.x = fmaxf(v.x, 0.0f); v.y = fmaxf(v.y, 0.0f);
            v.z = fmaxf(v.z, 0.0f); v.w = fmaxf(v.w, 0.0f);
            if (PACKO) {
                uint4 p;
                p.x = pack_split(v.x); p.y = pack_split(v.y);
                p.z = pack_split(v.z); p.w = pack_split(v.w);
                *(uint4*)((unsigned*)y + gb + 4 * i2) = p;
            } else {
                *(float4*)(y + gb + 4 * i2) = v;
            }
        }
    }
}

// ============ MFMA ConvTranspose k=4 s=2 p=1 + ReLU (parity GEMM) ==========
// One block = one parity (dy,dx) x 64 parity-plane positions x Cout channels.
// GEMM: C[m][co] = sum_k A[m][k] B[k][co], k = ci*4 + (2r+s),
// A[m][ci*4+2r+s] = in(ci, i-1+dy+r, j-1+dx+s),
// B[k][co] = w[ci][co][3-dy-2r][3-dx-2s]  (pre-repacked by repack_wt).
// K-chunk = 32 (8 channels). 4 waves; layout WM x WN set by MT/NT.
template<int Cin, int Hh, int Wh, int Cout, int MT, int NT, int PACKO>
__global__ void __launch_bounds__(256) convt4s2_mfma(
    const unsigned* __restrict__ xp, const unsigned* __restrict__ wq,
    const float* __restrict__ bias, float* __restrict__ y)
{
    constexpr int W = Wh;
    constexpr int LOG_W = (W == 64) ? 6 : (W == 32) ? 5 : 4;
    constexpr int R   = 64 / W;             // parity-plane rows per block
    constexpr int RT  = R + 1;              // staged input rows (halo 1)
    constexpr int CS  = W + 2;              // staged cols (-1 .. W)
    constexpr int XEL = 8 * RT * CS;        // 8 channels per chunk
    constexpr int XIT = (XEL + 255) / 256;
    constexpr int K   = Cin * 4;
    constexpr int NC  = Cin / 8;            // chunks of 32 k
    constexpr int NB  = Cout;
    constexpr int WIT = NB / 8;             // B-load iters
    constexpr int WN  = Cout / (16 * NT);
    constexpr int WM  = 4 / WN;
    static_assert(WM * MT * 16 == 64, "M tiling");
    static_assert(WN * NT * 16 == Cout, "N tiling");
    constexpr int MBC = 32 * Hh * W / 64;
    constexpr int XPAD = (XEL + 7) & ~7;
    constexpr int SM1 = XPAD + NB * 36;
    constexpr int SM2 = NB * 68;
    constexpr int SMEM = SM1 > SM2 ? SM1 : SM2;

    __shared__ unsigned smem[SMEM];
    unsigned* raw = smem;
    unsigned* wb  = smem + XPAD;            // [NB][36]

    int bid = blockIdx.x;
    int mb  = bid % MBC;
    int par = bid / MBC;
    int dy = par >> 1, dx = par & 1;

    int m0   = mb * 64;
    int nimg = m0 / (Hh * W);
    int sp0  = m0 % (Hh * W);
    int il0  = sp0 >> LOG_W;

    int tid = threadIdx.x;
    int lane = tid & 63, wv = tid >> 6;
    int lm = lane & 15, q = lane >> 4;
    int wm = wv / WN, wn = wv % WN;

    const unsigned* xbase = xp + (size_t)nimg * Cin * Hh * W;

    // ---- A-loader offsets (chunk-invariant) ----
    int  goff[XIT];
    bool gok[XIT];
#pragma unroll
    for (int s = 0; s < XIT; ++s) {
        int i = tid + 256 * s;
        goff[s] = 0; gok[s] = false;
        if (i < XEL) {
            int lc = i % CS;
            int t2 = i / CS;
            int lr = t2 % RT;
            int c  = t2 / RT;
            int gr = il0 - 1 + dy + lr;
            int gc = lc - 1;
            bool ok = ((unsigned)gr < (unsigned)Hh) && ((unsigned)gc < (unsigned)W);
            goff[s] = ok ? (c * Hh * W + gr * W + gc) : 0;
            gok[s]  = ok;
        }
    }
    // B loader: kk = tid&31, row = tid>>5 (+8 per iter)
    const unsigned* wbase = wq + (size_t)(par * Cout + (tid >> 5)) * K + (tid & 31);
    int wlds0 = (tid >> 5) * 36 + (tid & 31);

    f32x4 acc[MT][NT];
#pragma unroll
    for (int nt = 0; nt < NT; ++nt) {
        float b = bias[wn * NT * 16 + nt * 16 + lm];
#pragma unroll
        for (int mt = 0; mt < MT; ++mt)
#pragma unroll
            for (int r = 0; r < 4; ++r) acc[mt][nt][r] = b;
    }

    unsigned pfa[XIT];
    unsigned pfb[WIT];

    auto load_chunk = [&](int ch) {
        const unsigned* cb = xbase + (size_t)(ch * 8) * (Hh * W);
#pragma unroll
        for (int s = 0; s < XIT; ++s) {
            unsigned v = 0;
            if (gok[s]) v = cb[goff[s]];
            pfa[s] = v;
        }
        const unsigned* wc = wbase + ch * 32;
#pragma unroll
        for (int s = 0; s < WIT; ++s) pfb[s] = wc[(size_t)s * 8 * K];
    };
    auto store_chunk = [&]() {
#pragma unroll
        for (int s = 0; s < XIT; ++s) {
            int i = tid + 256 * s;
            if (i < XEL) raw[i] = pfa[s];
        }
#pragma unroll
        for (int s = 0; s < WIT; ++s) wb[wlds0 + s * 288] = pfb[s];
    };

    load_chunk(0);
#pragma unroll 1
    for (int ch = 0; ch < NC; ++ch) {
        __syncthreads();
        store_chunk();
        __syncthreads();
        if (ch + 1 < NC) load_chunk(ch + 1);

        // ---- B fragments (n = lane&15, k = q*8+jj) ----
        FragU bhi[NT], blo[NT];
#pragma unroll
        for (int nt = 0; nt < NT; ++nt) {
            const unsigned* bp = &wb[(wn * NT * 16 + nt * 16 + lm) * 36 + q * 8];
            uint4 p0 = *(const uint4*)bp;
            uint4 p1 = *(const uint4*)(bp + 4);
            unsigned e0 = p0.x, e1 = p0.y, e2 = p0.z, e3 = p0.w;
            unsigned e4 = p1.x, e5 = p1.y, e6 = p1.z, e7 = p1.w;
            bhi[nt].u[0] = (e0 & 0xffffu) | (e1 << 16);
            bhi[nt].u[1] = (e2 & 0xffffu) | (e3 << 16);
            bhi[nt].u[2] = (e4 & 0xffffu) | (e5 << 16);
            bhi[nt].u[3] = (e6 & 0xffffu) | (e7 << 16);
            blo[nt].u[0] = (e0 >> 16) | (e1 & 0xffff0000u);
            blo[nt].u[1] = (e2 >> 16) | (e3 & 0xffff0000u);
            blo[nt].u[2] = (e4 >> 16) | (e5 & 0xffff0000u);
            blo[nt].u[3] = (e6 >> 16) | (e7 & 0xffff0000u);
        }
        // ---- A fragments: ci pair (2q, 2q+1), taps t=2r+s per channel ----
#pragma unroll
        for (int mt = 0; mt < MT; ++mt) {
            int ml = wm * (MT * 16) + mt * 16 + lm;
            int il = ml >> LOG_W, jl = ml & (W - 1);
            const unsigned* rp = &raw[((2 * q) * RT + il) * CS + jl + dx];
            unsigned a00 = rp[0],               a01 = rp[1];
            unsigned a10 = rp[CS],              a11 = rp[CS + 1];
            unsigned a20 = rp[RT * CS],         a21 = rp[RT * CS + 1];
            unsigned a30 = rp[RT * CS + CS],    a31 = rp[RT * CS + CS + 1];
            FragU ahi, alo;
            ahi.u[0] = (a00 & 0xffffu) | (a01 << 16);
            ahi.u[1] = (a10 & 0xffffu) | (a11 << 16);
            ahi.u[2] = (a20 & 0xffffu) | (a21 << 16);
            ahi.u[3] = (a30 & 0xffffu) | (a31 << 16);
            alo.u[0] = (a00 >> 16) | (a01 & 0xffff0000u);
            alo.u[1] = (a10 >> 16) | (a11 & 0xffff0000u);
            alo.u[2] = (a20 >> 16) | (a21 & 0xffff0000u);
            alo.u[3] = (a30 >> 16) | (a31 & 0xffff0000u);
#pragma unroll
            for (int nt = 0; nt < NT; ++nt) {
                acc[mt][nt] = __builtin_amdgcn_mfma_f32_16x16x32_bf16(
                    ahi.v, bhi[nt].v, acc[mt][nt], 0, 0, 0);
                acc[mt][nt] = __builtin_amdgcn_mfma_f32_16x16x32_bf16(
                    ahi.v, blo[nt].v, acc[mt][nt], 0, 0, 0);
                acc[mt][nt] = __builtin_amdgcn_mfma_f32_16x16x32_bf16(
                    alo.v, bhi[nt].v, acc[mt][nt], 0, 0, 0);
            }
        }
    }

    // ---- epilogue: transpose via LDS, relu, strided (parity) NCHW store ----
    __syncthreads();
    float* cs = (float*)smem;               // [NB][68]
#pragma unroll
    for (int mt = 0; mt < MT; ++mt)
#pragma unroll
        for (int nt = 0; nt < NT; ++nt) {
            int nl  = wn * NT * 16 + nt * 16 + lm;
            int mb2 = wm * (MT * 16) + mt * 16 + q * 4;
#pragma unroll
            for (int r = 0; r < 4; ++r)
                cs[nl * 68 + mb2 + r] = acc[mt][nt][r];
        }
    __syncthreads();
    constexpr int EIT = NB * 64 / 256;
#pragma unroll
    for (int it = 0; it < EIT; ++it) {
        int idx = tid + 256 * it;
        int c = idx >> 6, m = idx & 63;
        int il = m >> LOG_W, jl = m & (W - 1);
        int oy = 2 * (il0 + il) + dy;
        int ox = 2 * jl + dx;
        float v = fmaxf(cs[c * 68 + m], 0.0f);
        size_t go = (((size_t)(nimg * Cout + c)) * (2 * Hh) + oy) * (2 * W) + ox;
        if (PACKO) ((unsigned*)y)[go] = pack_split(v);
        else       y[go] = v;
    }
}

// ================= direct conv (conv1, packs output) =======================
template<int Cin, int H, int W, int OCT, int UNR, bool INT>
__device__ __forceinline__ void conv_core(
    const float* __restrict__ xn, const float* __restrict__ wbase,
    int iy0, int ix0, float (&acc)[OCT][4])
{
#pragma unroll UNR
    for (int ic = 0; ic < Cin; ++ic) {
        const float* xc = xn + (size_t)ic * (H * W);
        float xv[4][10];
#pragma unroll
        for (int ky = 0; ky < 4; ++ky) {
            int iy = iy0 + ky;
            if (INT) {
                const float* xr = xc + (size_t)iy * W;
#pragma unroll
                for (int j = 0; j < 10; ++j) xv[ky][j] = xr[ix0 + j];
            } else {
                bool rv = ((unsigned)iy < (unsigned)H);
                const float* xr = xc + (size_t)(rv ? iy : 0) * W;
#pragma unroll
                for (int j = 0; j < 10; ++j) {
                    int ix = ix0 + j;
                    bool cv = rv && ((unsigned)ix < (unsigned)W);
                    xv[ky][j] = cv ? xr[cv ? ix : 0] : 0.0f;
                }
            }
        }
#pragma unroll
        for (int o = 0; o < OCT; ++o) {
            const float* wr = wbase + (size_t)o * (Cin * 16) + ic * 16;
#pragma unroll
            for (int ky = 0; ky < 4; ++ky) {
                float w0 = wr[ky * 4 + 0], w1 = wr[ky * 4 + 1];
                float w2 = wr[ky * 4 + 2], w3 = wr[ky * 4 + 3];
#pragma unroll
                for (int j = 0; j < 4; ++j) {
                    acc[o][j] = fmaf(xv[ky][2 * j],     w0, acc[o][j]);
                    acc[o][j] = fmaf(xv[ky][2 * j + 1], w1, acc[o][j]);
                    acc[o][j] = fmaf(xv[ky][2 * j + 2], w2, acc[o][j]);
                    acc[o][j] = fmaf(xv[ky][2 * j + 3], w3, acc[o][j]);
                }
            }
        }
    }
}

template<int Cin, int H, int W, int Cout, int OCT, int UNR, int PACKO>
__global__ void __launch_bounds__(256) conv4s2_k(
    const float* __restrict__ x, const float* __restrict__ w,
    const float* __restrict__ bias, float* __restrict__ y)
{
    constexpr int OH = H / 2, OW = W / 2, OWq = OW / 4;
    int id = blockIdx.x * 256 + threadIdx.x;
    int ox4 = id % OWq; int t = id / OWq;
    int oy  = t % OH;   t /= OH;
    int ocg = t % (Cout / OCT);
    int n   = t / (Cout / OCT);
    int oc0 = __builtin_amdgcn_readfirstlane(ocg * OCT);
    n       = __builtin_amdgcn_readfirstlane(n);

    float acc[OCT][4];
#pragma unroll
    for (int o = 0; o < OCT; ++o) {
        float b = bias[oc0 + o];
#pragma unroll
        for (int j = 0; j < 4; ++j) acc[o][j] = b;
    }

    const float* xn    = x + (size_t)n * Cin * H * W;
    const float* wbase = w + (size_t)oc0 * Cin * 16;
    int iy0 = 2 * oy - 1;
    int ix0 = 8 * ox4 - 1;

    bool interior = (oy >= 1) && (oy <= OH - 2) && (ox4 >= 1) && (ox4 <= OWq - 2);
    if (interior) conv_core<Cin, H, W, OCT, UNR, true >(xn, wbase, iy0, ix0, acc);
    else          conv_core<Cin, H, W, OCT, UNR, false>(xn, wbase, iy0, ix0, acc);

    int ox0 = ox4 * 4;
#pragma unroll
    for (int o = 0; o < OCT; ++o) {
        size_t gb = (((size_t)n * Cout + oc0 + o) * OH + oy) * OW + ox0;
#pragma unroll
        for (int j = 0; j < 4; ++j) {
            float v = fmaxf(acc[o][j], 0.0f);
            if (PACKO) ((unsigned*)y)[gb + j] = pack_split(v);
            else       y[gb + j] = v;
        }
    }
}

// ================= direct convT (g4, tanh) =================================
template<int Cin, int H, int W, int Cout, int COT, int ACT, int UNR>
__global__ void __launch_bounds__(256) convt4s2_k(
    const float* __restrict__ x, const float* __restrict__ w,
    const float* __restrict__ bias, float* __restrict__ y)
{
    constexpr int OH = 2 * H, OW = 2 * W, OWq = OW / 4;
    int id = blockIdx.x * 256 + threadIdx.x;
    int ox4 = id % OWq; int t = id / OWq;
    int oy  = t % OH;   t /= OH;
    int cog = t % (Cout / COT);
    int n   = t / (Cout / COT);
    int co0 = __builtin_amdgcn_readfirstlane(cog * COT);
    n       = __builtin_amdgcn_readfirstlane(n);

    int p   = (oy + 1) & 1;
    int iyA = (oy + 1 - p) >> 1;
    int iyB = iyA - 1;
    bool vA = (iyA < H);
    bool vB = (iyB >= 0);
    int iyAc = vA ? iyA : 0, iyBc = vB ? iyB : 0;

    int t0 = 2 * ox4;
    bool c0 = (t0 - 1 >= 0);
    bool c3 = (t0 + 2 <= W - 1);
    int j0 = c0 ? t0 - 1 : 0;
    int j3 = c3 ? t0 + 2 : 0;

    float acc[COT][4];
#pragma unroll
    for (int o = 0; o < COT; ++o) {
        float b = bias[co0 + o];
#pragma unroll
        for (int j = 0; j < 4; ++j) acc[o][j] = b;
    }

    const float* xn = x + (size_t)n * Cin * H * W;

#pragma unroll UNR
    for (int ci = 0; ci < Cin; ++ci) {
        const float* xc  = xn + (size_t)ci * (H * W);
        const float* xrA = xc + (size_t)iyAc * W;
        const float* xrB = xc + (size_t)iyBc * W;
        float a0 = (vA && c0) ? xrA[j0]     : 0.0f;
        float a1 =  vA        ? xrA[t0]     : 0.0f;
        float a2 =  vA        ? xrA[t0 + 1] : 0.0f;
        float a3 = (vA && c3) ? xrA[j3]     : 0.0f;
        float b0 = (vB && c0) ? xrB[j0]     : 0.0f;
        float b1 =  vB        ? xrB[t0]     : 0.0f;
        float b2 =  vB        ? xrB[t0 + 1] : 0.0f;
        float b3 = (vB && c3) ? xrB[j3]     : 0.0f;

        const float* wci = w + ((size_t)ci * Cout + co0) * 16;
#pragma unroll
        for (int o = 0; o < COT; ++o) {
            const float* wr = wci + (size_t)o * 16;
            float wA0 = wr[p * 4 + 0], wA1 = wr[p * 4 + 1];
            float wA2 = wr[p * 4 + 2], wA3 = wr[p * 4 + 3];
            float wB0 = wr[(p + 2) * 4 + 0], wB1 = wr[(p + 2) * 4 + 1];
            float wB2 = wr[(p + 2) * 4 + 2], wB3 = wr[(p + 2) * 4 + 3];
            acc[o][0] = fmaf(a1, wA1, acc[o][0]); acc[o][0] = fmaf(a0, wA3, acc[o][0]);
            acc[o][0] = fmaf(b1, wB1, acc[o][0]); acc[o][0] = fmaf(b0, wB3, acc[o][0]);
            acc[o][1] = fmaf(a2, wA0, acc[o][1]); acc[o][1] = fmaf(a1, wA2, acc[o][1]);
            acc[o][1] = fmaf(b2, wB0, acc[o][1]); acc[o][1] = fmaf(b1, wB2, acc[o][1]);
            acc[o][2] = fmaf(a2, wA1, acc[o][2]); acc[o][2] = fmaf(a1, wA3, acc[o][2]);
            acc[o][2] = fmaf(b2, wB1, acc[o][2]); acc[o][2] = fmaf(b1, wB3, acc[o][2]);
            acc[o][3] = fmaf(a3, wA0, acc[o][3]); acc[o][3] = fmaf(a2, wA2, acc[o][3]);
            acc[o][3] = fmaf(b3, wB0, acc[o][3]); acc[o][3] = fmaf(b2, wB2, acc[o][3]);
        }
    }

    int ox0 = ox4 * 4;
#pragma unroll
    for (int o = 0; o < COT; ++o) {
        float* yr = y + (((size_t)n * Cout + co0 + o) * OH + oy) * OW + ox0;
#pragma unroll
        for (int j = 0; j < 4; ++j) {
            float v = acc[o][j];
            yr[j] = (ACT == 0) ? fmaxf(v, 0.0f) : tanhf(v);
        }
    }
}

// =============================== quantizer =================================
__global__ void __launch_bounds__(256) embed_norms(
    const float* __restrict__ embed, float* __restrict__ norms)
{
    int c = blockIdx.x * 256 + threadIdx.x;
    const float* e = embed + (size_t)c * 512;
    float s = 0.0f;
    for (int k = 0; k < 512; ++k) s = fmaf(e[k], e[k], s);
    norms[c] = s;
}

__global__ void __launch_bounds__(256) vq_argmin8(
    const float* __restrict__ z, const float* __restrict__ embed,
    const float* __restrict__ norms, int* __restrict__ out)
{
    int row0 = blockIdx.x * 8;
    int n    = row0 >> 8;
    int yx0  = row0 & 255;

    __shared__ float zr[8 * 512];
    const float* zn = z + ((size_t)n * 512) * 256;
    for (int i = threadIdx.x; i < 8 * 512; i += 256) {
        int r = i >> 9, c = i & 511;
        zr[i] = zn[((size_t)c << 8) + yx0 + r];
    }
    __syncthreads();

    float best[8]; int bi[8];
#pragma unroll
    for (int r = 0; r < 8; ++r) { best[r] = 3.4e38f; bi[r] = 0; }

#pragma unroll
    for (int rep = 0; rep < 4; ++rep) {
        int code = rep * 256 + threadIdx.x;
        const float4* e4 = (const float4*)(embed + (size_t)code * 512);
        float dot[8];
#pragma unroll
        for (int r = 0; r < 8; ++r) dot[r] = 0.0f;
        for (int k4 = 0; k4 < 128; ++k4) {
            float4 e = e4[k4];
#pragma unroll
            for (int r = 0; r < 8; ++r) {
                const float4 zz = *(const float4*)&zr[r * 512 + k4 * 4];
                dot[r] = fmaf(e.x, zz.x, dot[r]);
                dot[r] = fmaf(e.y, zz.y, dot[r]);
                dot[r] = fmaf(e.z, zz.z, dot[r]);
                dot[r] = fmaf(e.w, zz.w, dot[r]);
            }
        }
        float nb = norms[code];
#pragma unroll
        for (int r = 0; r < 8; ++r) {
            float d = nb - 2.0f * dot[r];
            if (d < best[r]) { best[r] = d; bi[r] = code; }
        }
    }

    __shared__ float rbd[8 * 256];
    __shared__ int   rbi[8 * 256];
#pragma unroll
    for (int r = 0; r < 8; ++r) {
        rbd[r * 256 + threadIdx.x] = best[r];
        rbi[r * 256 + threadIdx.x] = bi[r];
    }
    __syncthreads();
    for (int s = 128; s > 0; s >>= 1) {
        if ((int)threadIdx.x < s) {
#pragma unroll
            for (int r = 0; r < 8; ++r) {
                int i0 = r * 256 + threadIdx.x;
                float od = rbd[i0 + s]; int oi = rbi[i0 + s];
                float md = rbd[i0];     int mi = rbi[i0];
                if (od < md || (od == md && oi < mi)) { rbd[i0] = od; rbi[i0] = oi; }
            }
        }
        __syncthreads();
    }
    if (threadIdx.x < 8) out[row0 + threadIdx.x] = rbi[threadIdx.x * 256];
}

__global__ void __launch_bounds__(256) vq_gather_pack(
    const int* __restrict__ vidx, const float* __restrict__ embed,
    unsigned* __restrict__ zq)
{
    int i = blockIdx.x * 256 + threadIdx.x;
    int yx = i & 255;
    int t  = i >> 8;
    int c  = t & 511;
    int n  = t >> 9;
    int row = (n << 8) + yx;
    zq[i] = pack_split(embed[(size_t)vidx[row] * 512 + c]);
}

// ================================ launch ===================================
extern "C" void kernel_launch(void* const* d_in, const int* in_sizes, int n_in,
                              void* d_out, int out_size, void* d_ws, size_t ws_size,
                              hipStream_t stream)
{
    (void)in_sizes; (void)n_in; (void)out_size; (void)ws_size;
    const float* x     = (const float*)d_in[0];
    const float* ew1   = (const float*)d_in[1];
    const float* eb1   = (const float*)d_in[2];
    const float* ew2   = (const float*)d_in[3];
    const float* eb2   = (const float*)d_in[4];
    const float* ew3   = (const float*)d_in[5];
    const float* eb3   = (const float*)d_in[6];
    const float* ew4   = (const float*)d_in[7];
    const float* eb4   = (const float*)d_in[8];
    const float* dw1   = (const float*)d_in[9];
    const float* db1   = (const float*)d_in[10];
    const float* dw2   = (const float*)d_in[11];
    const float* db2   = (const float*)d_in[12];
    const float* dw3   = (const float*)d_in[13];
    const float* db3   = (const float*)d_in[14];
    const float* dw4   = (const float*)d_in[15];
    const float* db4   = (const float*)d_in[16];
    const float* embed = (const float*)d_in[17];
    float* out = (float*)d_out;

    // ---- workspace layout (u32 units). Peak identical to R7 usage.
    unsigned* W0   = (unsigned*)d_ws;
    unsigned* h1p  = W0;                          // conv1 out (dead after conv2)
    unsigned* h2p  = W0 + 33554432;               // conv2 out
    unsigned* h3p  = W0;                          // overlays dead h1p
    float*    z    = (float*)(W0 + 8388608);      // conv4 out fp32
    unsigned* zq   = W0 + 12582912;               // quantized, packed u32
    float*    P0   = (float*)(W0 + 16777216);     // convt1 out (packed u32)
    float*    P1   = (float*)(W0 + 20971520);     // convt2 out (packed u32)
    int*      vidx = (int*)(W0 + 29360128);
    float*    norms= (float*)(W0 + 29368320);
    float*    g3o  = (float*)h2p;                 // convt3 out fp32 (h2p dead)

    // packed weights live in d_out until g4 overwrites it
    unsigned* wp2 = (unsigned*)d_out;             // 131,072
    unsigned* wp3 = wp2 + 131072;                 // 524,288
    unsigned* wp4 = wp2 + 655360;                 // 2,097,152
    unsigned* wq1 = wp2 + 2752512;                // 1,048,576 (4x128x2048)
    unsigned* wq2 = wq1 + 1048576;                // 131,072   (4x64x512)
    unsigned* wq3 = wq2 + 131072;                 // 32,768    (4x32x256)

    dim3 b256(256);

    // ---- pre-pass: pack encoder weights, repack decoder weights ----
    pack_tensor<<<dim3(512),  b256, 0, stream>>>(ew2, wp2, 131072);
    pack_tensor<<<dim3(2048), b256, 0, stream>>>(ew3, wp3, 524288);
    pack_tensor<<<dim3(8192), b256, 0, stream>>>(ew4, wp4, 2097152);
    repack_wt<512, 128><<<dim3(4096), b256, 0, stream>>>(dw1, wq1);
    repack_wt<128,  64><<<dim3(512),  b256, 0, stream>>>(dw2, wq2);
    repack_wt< 64,  32><<<dim3(128),  b256, 0, stream>>>(dw3, wq3);

    // ---- encoder ----
    conv4s2_k<3, 256, 256, 64, 4, 3, 1><<<dim3(8192), b256, 0, stream>>>(
        x, ew1, eb1, (float*)h1p);                         // h1 (packed)
    conv4s2_mfma<64, 128, 128, 128, 1><<<dim3(2048), b256, 0, stream>>>(
        h1p, wp2, eb2, (float*)h2p);                       // h2 (packed)
    conv4s2_mfma<128, 64, 64, 256, 1><<<dim3(1024), b256, 0, stream>>>(
        h2p, wp3, eb3, (float*)h3p);                       // h3 (packed)
    conv4s2_mfma<256, 32, 32, 512, 0><<<dim3(512), b256, 0, stream>>>(
        h3p, wp4, eb4, z);                                 // z (fp32)

    // ---- quantizer ----
    embed_norms<<<dim3(4), b256, 0, stream>>>(embed, norms);
    vq_argmin8<<<dim3(1024), b256, 0, stream>>>(z, embed, norms, vidx);
    vq_gather_pack<<<dim3(16384), b256, 0, stream>>>(vidx, embed, zq);

    // ---- decoder (MFMA parity-GEMM convT) ----
    convt4s2_mfma<512, 16, 16, 128, 4, 2, 1><<<dim3(4 * 128), b256, 0, stream>>>(
        zq, wq1, db1, P0);                                 // P0 (packed)
    convt4s2_mfma<128, 32, 32, 64, 4, 1, 1><<<dim3(4 * 512), b256, 0, stream>>>(
        (const unsigned*)P0, wq2, db2, P1);                // P1 (packed)
    convt4s2_mfma<64, 64, 64, 32, 2, 1, 0><<<dim3(4 * 2048), b256, 0, stream>>>(
        (const unsigned*)P1, wq3, db3, g3o);               // g3o (fp32)
    convt4s2_k<32, 128, 128, 3, 3, 1, 2><<<dim3(2048), b256, 0, stream>>>(
        g3o, dw4, db4, out);                               // tanh -> d_out
}

// Round 3
// 1271.754 us; speedup vs baseline: 1.4964x; 1.0785x over previous
//
#include <hip/hip_runtime.h>
#include <math.h>

// ---------------------------------------------------------------------------
// VQ-VAE forward. Round 10 (= R9 resubmit after infra failure): quantizer
// argmin rewritten as a register-tiled fp32 GEMM (16 rows x 1024 codes per
// block, transposed codebook for coalesced loads, broadcast LDS z-reads).
// Distances bit-identical to R8. Encoder + MFMA decoder identical to R8.
// ---------------------------------------------------------------------------

typedef __attribute__((ext_vector_type(8))) short bf16x8;
typedef __attribute__((ext_vector_type(4))) float f32x4;
union FragU { unsigned u[4]; bf16x8 v; };

__device__ __forceinline__ unsigned bf16_rne(unsigned u) {
    return (u + 0x7FFFu + ((u >> 16) & 1u)) >> 16;
}
// pack fp32 -> u32: low16 = bf16(v), high16 = bf16(v - bf16(v))
__device__ __forceinline__ unsigned pack_split(float v) {
    unsigned u = __builtin_bit_cast(unsigned, v);
    unsigned hi = bf16_rne(u);
    float hif = __builtin_bit_cast(float, hi << 16);
    float r = v - hif;
    unsigned lo = bf16_rne(__builtin_bit_cast(unsigned, r));
    return hi | (lo << 16);
}

__global__ void __launch_bounds__(256) pack_tensor(
    const float* __restrict__ s, unsigned* __restrict__ d, int n)
{
    int i = blockIdx.x * 256 + threadIdx.x;
    if (i < n) d[i] = pack_split(s[i]);
}

// repack ConvTranspose weights (torch layout Cin,Cout,4,4) into
// wq[par][co][ci*4 + t], t = 2r+s, packed hi/lo. par = dy*2+dx.
template<int Cin, int Cout>
__global__ void __launch_bounds__(256) repack_wt(
    const float* __restrict__ w, unsigned* __restrict__ wq)
{
    constexpr int TOT = 16 * Cin * Cout;
    int idx = blockIdx.x * 256 + threadIdx.x;
    if (idx >= TOT) return;
    int t  = idx & 3;
    int ci = (idx >> 2) % Cin;
    int rest = (idx >> 2) / Cin;
    int co  = rest % Cout;
    int par = rest / Cout;
    int dy = par >> 1, dx = par & 1;
    int r = t >> 1, s = t & 1;
    int ky = 3 - dy - 2 * r;
    int kx = 3 - dx - 2 * s;
    float v = w[(((size_t)ci * Cout + co) * 4 + ky) * 4 + kx];
    wq[idx] = pack_split(v);
}

// transpose codebook: embed[1024][512] -> et[512][1024]
__global__ void __launch_bounds__(256) embed_transpose(
    const float* __restrict__ embed, float* __restrict__ et)
{
    int idx = blockIdx.x * 256 + threadIdx.x;   // 2048 blocks x 256
    int c = idx & 1023, k = idx >> 10;
    et[idx] = embed[(size_t)c * 512 + k];
}

// ================= MFMA conv k=4 s=2 p=1 + ReLU (implicit GEMM) ============
template<int Cin, int H, int W, int Cout, int PACKO>
__global__ void __launch_bounds__(256) conv4s2_mfma(
    const unsigned* __restrict__ xp, const unsigned* __restrict__ wp,
    const float* __restrict__ bias, float* __restrict__ y)
{
    constexpr int OH = H / 2, OW = W / 2;
    constexpr int LOG_OW = (OW == 64) ? 6 : (OW == 32) ? 5 : 4;
    constexpr int R   = 64 / OW;
    constexpr int RT  = 2 * R + 2;
    constexpr int CS  = W + 2;
    constexpr int XEL = 2 * RT * CS;
    constexpr int XIT = (XEL + 255) / 256;
    constexpr int K   = Cin * 16;
    constexpr int NC  = Cin / 2;
    constexpr int NB  = 128;
    constexpr int MBC = 32 * OH * OW / 64;

    __shared__ unsigned smem[8704];
    unsigned* raw = smem;
    unsigned* wb  = smem + ((XEL + 7) & ~7);

    int bid = blockIdx.x;
    int mb = bid % MBC, ng = bid / MBC;
    int oc0 = ng * NB;
    int m0 = mb * 64;
    int nimg = m0 / (OH * OW);
    int sp0 = m0 % (OH * OW);
    int oyb = sp0 >> LOG_OW;

    int tid  = threadIdx.x;
    int lane = tid & 63, wv = tid >> 6;
    int lm = lane & 15, q = lane >> 4;
    int n0w = wv * 32;

    const unsigned* xbase = xp + (size_t)nimg * Cin * H * W;

    int  goff[XIT];
    bool gok[XIT];
#pragma unroll
    for (int s = 0; s < XIT; ++s) {
        int i = tid + 256 * s;
        goff[s] = 0; gok[s] = false;
        if (i < XEL) {
            int lc = i % CS;
            int t2 = i / CS;
            int lr = t2 % RT;
            int c  = t2 / RT;
            int gr = 2 * oyb - 1 + lr;
            int gc = lc - 1;
            bool ok = ((unsigned)gr < (unsigned)H) && ((unsigned)gc < (unsigned)W);
            goff[s] = ok ? (c * H * W + gr * W + gc) : 0;
            gok[s]  = ok;
        }
    }
    const unsigned* wbase = wp + (size_t)(oc0 + (tid >> 5)) * K + (tid & 31);
    int wlds0 = (tid >> 5) * 36 + (tid & 31);

    f32x4 acc[4][2];
#pragma unroll
    for (int nt = 0; nt < 2; ++nt) {
        float b = bias[oc0 + n0w + nt * 16 + lm];
#pragma unroll
        for (int mt = 0; mt < 4; ++mt)
#pragma unroll
            for (int r = 0; r < 4; ++r) acc[mt][nt][r] = b;
    }

    unsigned pfa[XIT];
    unsigned pfb[16];

    auto load_chunk = [&](int ch) {
        const unsigned* cb = xbase + (size_t)(ch * 2) * (H * W);
#pragma unroll
        for (int s = 0; s < XIT; ++s) {
            unsigned v = 0;
            if (gok[s]) v = cb[goff[s]];
            pfa[s] = v;
        }
        const unsigned* wc = wbase + ch * 32;
#pragma unroll
        for (int s = 0; s < 16; ++s) pfb[s] = wc[(size_t)s * 8 * K];
    };
    auto store_chunk = [&]() {
#pragma unroll
        for (int s = 0; s < XIT; ++s) {
            int i = tid + 256 * s;
            if (i < XEL) raw[i] = pfa[s];
        }
#pragma unroll
        for (int s = 0; s < 16; ++s) wb[wlds0 + s * 288] = pfb[s];
    };

    load_chunk(0);
#pragma unroll 1
    for (int ch = 0; ch < NC; ++ch) {
        __syncthreads();
        store_chunk();
        __syncthreads();
        if (ch + 1 < NC) load_chunk(ch + 1);

        FragU bhi[2], blo[2];
#pragma unroll
        for (int nt = 0; nt < 2; ++nt) {
            const unsigned* bp = &wb[(n0w + nt * 16 + lm) * 36 + q * 8];
            uint4 p0 = *(const uint4*)bp;
            uint4 p1 = *(const uint4*)(bp + 4);
            unsigned e0 = p0.x, e1 = p0.y, e2 = p0.z, e3 = p0.w;
            unsigned e4 = p1.x, e5 = p1.y, e6 = p1.z, e7 = p1.w;
            bhi[nt].u[0] = (e0 & 0xffffu) | (e1 << 16);
            bhi[nt].u[1] = (e2 & 0xffffu) | (e3 << 16);
            bhi[nt].u[2] = (e4 & 0xffffu) | (e5 << 16);
            bhi[nt].u[3] = (e6 & 0xffffu) | (e7 << 16);
            blo[nt].u[0] = (e0 >> 16) | (e1 & 0xffff0000u);
            blo[nt].u[1] = (e2 >> 16) | (e3 & 0xffff0000u);
            blo[nt].u[2] = (e4 >> 16) | (e5 & 0xffff0000u);
            blo[nt].u[3] = (e6 >> 16) | (e7 & 0xffff0000u);
        }
#pragma unroll
        for (int mt = 0; mt < 4; ++mt) {
            int m = mt * 16 + lm;
            int oyl = m >> LOG_OW, oxl = m & (OW - 1);
            int c = q >> 1, rb = 2 * oyl + (q & 1) * 2;
            const unsigned* rp = &raw[(c * RT + rb) * CS + 2 * oxl];
            uint2 a0 = *(const uint2*)rp;
            uint2 a1 = *(const uint2*)(rp + 2);
            uint2 a2 = *(const uint2*)(rp + CS);
            uint2 a3 = *(const uint2*)(rp + CS + 2);
            FragU ahi, alo;
            ahi.u[0] = (a0.x & 0xffffu) | (a0.y << 16);
            ahi.u[1] = (a1.x & 0xffffu) | (a1.y << 16);
            ahi.u[2] = (a2.x & 0xffffu) | (a2.y << 16);
            ahi.u[3] = (a3.x & 0xffffu) | (a3.y << 16);
            alo.u[0] = (a0.x >> 16) | (a0.y & 0xffff0000u);
            alo.u[1] = (a1.x >> 16) | (a1.y & 0xffff0000u);
            alo.u[2] = (a2.x >> 16) | (a2.y & 0xffff0000u);
            alo.u[3] = (a3.x >> 16) | (a3.y & 0xffff0000u);
#pragma unroll
            for (int nt = 0; nt < 2; ++nt) {
                acc[mt][nt] = __builtin_amdgcn_mfma_f32_16x16x32_bf16(
                    ahi.v, bhi[nt].v, acc[mt][nt], 0, 0, 0);
                acc[mt][nt] = __builtin_amdgcn_mfma_f32_16x16x32_bf16(
                    ahi.v, blo[nt].v, acc[mt][nt], 0, 0, 0);
                acc[mt][nt] = __builtin_amdgcn_mfma_f32_16x16x32_bf16(
                    alo.v, bhi[nt].v, acc[mt][nt], 0, 0, 0);
            }
        }
    }

    __syncthreads();
    float* cs = (float*)smem;
#pragma unroll
    for (int mt = 0; mt < 4; ++mt)
#pragma unroll
        for (int nt = 0; nt < 2; ++nt) {
            int nl = n0w + nt * 16 + lm;
#pragma unroll
            for (int r = 0; r < 4; ++r)
                cs[nl * 68 + mt * 16 + q * 4 + r] = acc[mt][nt][r];
        }
    __syncthreads();
    {
        int nl = tid >> 1, half = tid & 1;
        size_t gb = ((size_t)(nimg * Cout + oc0 + nl)) * (OH * OW) + sp0 + half * 32;
#pragma unroll
        for (int i2 = 0; i2 < 8; ++i2) {
            float4 v = *(float4*)&cs[nl * 68 + half * 32 + 4 * i2];
            v.x = fmaxf(v.x, 0.0f); v.y = fmaxf(v.y, 0.0f);
            v.z = fmaxf(v.z, 0.0f); v.w = fmaxf(v.w, 0.0f);
            if (PACKO) {
                uint4 p;
                p.x = pack_split(v.x); p.y = pack_split(v.y);
                p.z = pack_split(v.z); p.w = pack_split(v.w);
                *(uint4*)((unsigned*)y + gb + 4 * i2) = p;
            } else {
                *(float4*)(y + gb + 4 * i2) = v;
            }
        }
    }
}

// ============ MFMA ConvTranspose k=4 s=2 p=1 + ReLU (parity GEMM) ==========
template<int Cin, int Hh, int Wh, int Cout, int MT, int NT, int PACKO>
__global__ void __launch_bounds__(256) convt4s2_mfma(
    const unsigned* __restrict__ xp, const unsigned* __restrict__ wq,
    const float* __restrict__ bias, float* __restrict__ y)
{
    constexpr int W = Wh;
    constexpr int LOG_W = (W == 64) ? 6 : (W == 32) ? 5 : 4;
    constexpr int R   = 64 / W;
    constexpr int RT  = R + 1;
    constexpr int CS  = W + 2;
    constexpr int XEL = 8 * RT * CS;
    constexpr int XIT = (XEL + 255) / 256;
    constexpr int K   = Cin * 4;
    constexpr int NC  = Cin / 8;
    constexpr int NB  = Cout;
    constexpr int WIT = NB / 8;
    constexpr int WN  = Cout / (16 * NT);
    constexpr int WM  = 4 / WN;
    static_assert(WM * MT * 16 == 64, "M tiling");
    static_assert(WN * NT * 16 == Cout, "N tiling");
    constexpr int MBC = 32 * Hh * W / 64;
    constexpr int XPAD = (XEL + 7) & ~7;
    constexpr int SM1 = XPAD + NB * 36;
    constexpr int SM2 = NB * 68;
    constexpr int SMEM = SM1 > SM2 ? SM1 : SM2;

    __shared__ unsigned smem[SMEM];
    unsigned* raw = smem;
    unsigned* wb  = smem + XPAD;

    int bid = blockIdx.x;
    int mb  = bid % MBC;
    int par = bid / MBC;
    int dy = par >> 1, dx = par & 1;

    int m0   = mb * 64;
    int nimg = m0 / (Hh * W);
    int sp0  = m0 % (Hh * W);
    int il0  = sp0 >> LOG_W;

    int tid = threadIdx.x;
    int lane = tid & 63, wv = tid >> 6;
    int lm = lane & 15, q = lane >> 4;
    int wm = wv / WN, wn = wv % WN;

    const unsigned* xbase = xp + (size_t)nimg * Cin * Hh * W;

    int  goff[XIT];
    bool gok[XIT];
#pragma unroll
    for (int s = 0; s < XIT; ++s) {
        int i = tid + 256 * s;
        goff[s] = 0; gok[s] = false;
        if (i < XEL) {
            int lc = i % CS;
            int t2 = i / CS;
            int lr = t2 % RT;
            int c  = t2 / RT;
            int gr = il0 - 1 + dy + lr;
            int gc = lc - 1;
            bool ok = ((unsigned)gr < (unsigned)Hh) && ((unsigned)gc < (unsigned)W);
            goff[s] = ok ? (c * Hh * W + gr * W + gc) : 0;
            gok[s]  = ok;
        }
    }
    const unsigned* wbase = wq + (size_t)(par * Cout + (tid >> 5)) * K + (tid & 31);
    int wlds0 = (tid >> 5) * 36 + (tid & 31);

    f32x4 acc[MT][NT];
#pragma unroll
    for (int nt = 0; nt < NT; ++nt) {
        float b = bias[wn * NT * 16 + nt * 16 + lm];
#pragma unroll
        for (int mt = 0; mt < MT; ++mt)
#pragma unroll
            for (int r = 0; r < 4; ++r) acc[mt][nt][r] = b;
    }

    unsigned pfa[XIT];
    unsigned pfb[WIT];

    auto load_chunk = [&](int ch) {
        const unsigned* cb = xbase + (size_t)(ch * 8) * (Hh * W);
#pragma unroll
        for (int s = 0; s < XIT; ++s) {
            unsigned v = 0;
            if (gok[s]) v = cb[goff[s]];
            pfa[s] = v;
        }
        const unsigned* wc = wbase + ch * 32;
#pragma unroll
        for (int s = 0; s < WIT; ++s) pfb[s] = wc[(size_t)s * 8 * K];
    };
    auto store_chunk = [&]() {
#pragma unroll
        for (int s = 0; s < XIT; ++s) {
            int i = tid + 256 * s;
            if (i < XEL) raw[i] = pfa[s];
        }
#pragma unroll
        for (int s = 0; s < WIT; ++s) wb[wlds0 + s * 288] = pfb[s];
    };

    load_chunk(0);
#pragma unroll 1
    for (int ch = 0; ch < NC; ++ch) {
        __syncthreads();
        store_chunk();
        __syncthreads();
        if (ch + 1 < NC) load_chunk(ch + 1);

        FragU bhi[NT], blo[NT];
#pragma unroll
        for (int nt = 0; nt < NT; ++nt) {
            const unsigned* bp = &wb[(wn * NT * 16 + nt * 16 + lm) * 36 + q * 8];
            uint4 p0 = *(const uint4*)bp;
            uint4 p1 = *(const uint4*)(bp + 4);
            unsigned e0 = p0.x, e1 = p0.y, e2 = p0.z, e3 = p0.w;
            unsigned e4 = p1.x, e5 = p1.y, e6 = p1.z, e7 = p1.w;
            bhi[nt].u[0] = (e0 & 0xffffu) | (e1 << 16);
            bhi[nt].u[1] = (e2 & 0xffffu) | (e3 << 16);
            bhi[nt].u[2] = (e4 & 0xffffu) | (e5 << 16);
            bhi[nt].u[3] = (e6 & 0xffffu) | (e7 << 16);
            blo[nt].u[0] = (e0 >> 16) | (e1 & 0xffff0000u);
            blo[nt].u[1] = (e2 >> 16) | (e3 & 0xffff0000u);
            blo[nt].u[2] = (e4 >> 16) | (e5 & 0xffff0000u);
            blo[nt].u[3] = (e6 >> 16) | (e7 & 0xffff0000u);
        }
#pragma unroll
        for (int mt = 0; mt < MT; ++mt) {
            int ml = wm * (MT * 16) + mt * 16 + lm;
            int il = ml >> LOG_W, jl = ml & (W - 1);
            const unsigned* rp = &raw[((2 * q) * RT + il) * CS + jl + dx];
            unsigned a00 = rp[0],               a01 = rp[1];
            unsigned a10 = rp[CS],              a11 = rp[CS + 1];
            unsigned a20 = rp[RT * CS],         a21 = rp[RT * CS + 1];
            unsigned a30 = rp[RT * CS + CS],    a31 = rp[RT * CS + CS + 1];
            FragU ahi, alo;
            ahi.u[0] = (a00 & 0xffffu) | (a01 << 16);
            ahi.u[1] = (a10 & 0xffffu) | (a11 << 16);
            ahi.u[2] = (a20 & 0xffffu) | (a21 << 16);
            ahi.u[3] = (a30 & 0xffffu) | (a31 << 16);
            alo.u[0] = (a00 >> 16) | (a01 & 0xffff0000u);
            alo.u[1] = (a10 >> 16) | (a11 & 0xffff0000u);
            alo.u[2] = (a20 >> 16) | (a21 & 0xffff0000u);
            alo.u[3] = (a30 >> 16) | (a31 & 0xffff0000u);
#pragma unroll
            for (int nt = 0; nt < NT; ++nt) {
                acc[mt][nt] = __builtin_amdgcn_mfma_f32_16x16x32_bf16(
                    ahi.v, bhi[nt].v, acc[mt][nt], 0, 0, 0);
                acc[mt][nt] = __builtin_amdgcn_mfma_f32_16x16x32_bf16(
                    ahi.v, blo[nt].v, acc[mt][nt], 0, 0, 0);
                acc[mt][nt] = __builtin_amdgcn_mfma_f32_16x16x32_bf16(
                    alo.v, bhi[nt].v, acc[mt][nt], 0, 0, 0);
            }
        }
    }

    __syncthreads();
    float* cs = (float*)smem;
#pragma unroll
    for (int mt = 0; mt < MT; ++mt)
#pragma unroll
        for (int nt = 0; nt < NT; ++nt) {
            int nl  = wn * NT * 16 + nt * 16 + lm;
            int mb2 = wm * (MT * 16) + mt * 16 + q * 4;
#pragma unroll
            for (int r = 0; r < 4; ++r)
                cs[nl * 68 + mb2 + r] = acc[mt][nt][r];
        }
    __syncthreads();
    constexpr int EIT = NB * 64 / 256;
#pragma unroll
    for (int it = 0; it < EIT; ++it) {
        int idx = tid + 256 * it;
        int c = idx >> 6, m = idx & 63;
        int il = m >> LOG_W, jl = m & (W - 1);
        int oy = 2 * (il0 + il) + dy;
        int ox = 2 * jl + dx;
        float v = fmaxf(cs[c * 68 + m], 0.0f);
        size_t go = (((size_t)(nimg * Cout + c)) * (2 * Hh) + oy) * (2 * W) + ox;
        if (PACKO) ((unsigned*)y)[go] = pack_split(v);
        else       y[go] = v;
    }
}

// ================= direct conv (conv1, packs output) =======================
template<int Cin, int H, int W, int OCT, int UNR, bool INT>
__device__ __forceinline__ void conv_core(
    const float* __restrict__ xn, const float* __restrict__ wbase,
    int iy0, int ix0, float (&acc)[OCT][4])
{
#pragma unroll UNR
    for (int ic = 0; ic < Cin; ++ic) {
        const float* xc = xn + (size_t)ic * (H * W);
        float xv[4][10];
#pragma unroll
        for (int ky = 0; ky < 4; ++ky) {
            int iy = iy0 + ky;
            if (INT) {
                const float* xr = xc + (size_t)iy * W;
#pragma unroll
                for (int j = 0; j < 10; ++j) xv[ky][j] = xr[ix0 + j];
            } else {
                bool rv = ((unsigned)iy < (unsigned)H);
                const float* xr = xc + (size_t)(rv ? iy : 0) * W;
#pragma unroll
                for (int j = 0; j < 10; ++j) {
                    int ix = ix0 + j;
                    bool cv = rv && ((unsigned)ix < (unsigned)W);
                    xv[ky][j] = cv ? xr[cv ? ix : 0] : 0.0f;
                }
            }
        }
#pragma unroll
        for (int o = 0; o < OCT; ++o) {
            const float* wr = wbase + (size_t)o * (Cin * 16) + ic * 16;
#pragma unroll
            for (int ky = 0; ky < 4; ++ky) {
                float w0 = wr[ky * 4 + 0], w1 = wr[ky * 4 + 1];
                float w2 = wr[ky * 4 + 2], w3 = wr[ky * 4 + 3];
#pragma unroll
                for (int j = 0; j < 4; ++j) {
                    acc[o][j] = fmaf(xv[ky][2 * j],     w0, acc[o][j]);
                    acc[o][j] = fmaf(xv[ky][2 * j + 1], w1, acc[o][j]);
                    acc[o][j] = fmaf(xv[ky][2 * j + 2], w2, acc[o][j]);
                    acc[o][j] = fmaf(xv[ky][2 * j + 3], w3, acc[o][j]);
                }
            }
        }
    }
}

template<int Cin, int H, int W, int Cout, int OCT, int UNR, int PACKO>
__global__ void __launch_bounds__(256) conv4s2_k(
    const float* __restrict__ x, const float* __restrict__ w,
    const float* __restrict__ bias, float* __restrict__ y)
{
    constexpr int OH = H / 2, OW = W / 2, OWq = OW / 4;
    int id = blockIdx.x * 256 + threadIdx.x;
    int ox4 = id % OWq; int t = id / OWq;
    int oy  = t % OH;   t /= OH;
    int ocg = t % (Cout / OCT);
    int n   = t / (Cout / OCT);
    int oc0 = __builtin_amdgcn_readfirstlane(ocg * OCT);
    n       = __builtin_amdgcn_readfirstlane(n);

    float acc[OCT][4];
#pragma unroll
    for (int o = 0; o < OCT; ++o) {
        float b = bias[oc0 + o];
#pragma unroll
        for (int j = 0; j < 4; ++j) acc[o][j] = b;
    }

    const float* xn    = x + (size_t)n * Cin * H * W;
    const float* wbase = w + (size_t)oc0 * Cin * 16;
    int iy0 = 2 * oy - 1;
    int ix0 = 8 * ox4 - 1;

    bool interior = (oy >= 1) && (oy <= OH - 2) && (ox4 >= 1) && (ox4 <= OWq - 2);
    if (interior) conv_core<Cin, H, W, OCT, UNR, true >(xn, wbase, iy0, ix0, acc);
    else          conv_core<Cin, H, W, OCT, UNR, false>(xn, wbase, iy0, ix0, acc);

    int ox0 = ox4 * 4;
#pragma unroll
    for (int o = 0; o < OCT; ++o) {
        size_t gb = (((size_t)n * Cout + oc0 + o) * OH + oy) * OW + ox0;
#pragma unroll
        for (int j = 0; j < 4; ++j) {
            float v = fmaxf(acc[o][j], 0.0f);
            if (PACKO) ((unsigned*)y)[gb + j] = pack_split(v);
            else       y[gb + j] = v;
        }
    }
}

// ================= direct convT (g4, tanh) =================================
template<int Cin, int H, int W, int Cout, int COT, int ACT, int UNR>
__global__ void __launch_bounds__(256) convt4s2_k(
    const float* __restrict__ x, const float* __restrict__ w,
    const float* __restrict__ bias, float* __restrict__ y)
{
    constexpr int OH = 2 * H, OW = 2 * W, OWq = OW / 4;
    int id = blockIdx.x * 256 + threadIdx.x;
    int ox4 = id % OWq; int t = id / OWq;
    int oy  = t % OH;   t /= OH;
    int cog = t % (Cout / COT);
    int n   = t / (Cout / COT);
    int co0 = __builtin_amdgcn_readfirstlane(cog * COT);
    n       = __builtin_amdgcn_readfirstlane(n);

    int p   = (oy + 1) & 1;
    int iyA = (oy + 1 - p) >> 1;
    int iyB = iyA - 1;
    bool vA = (iyA < H);
    bool vB = (iyB >= 0);
    int iyAc = vA ? iyA : 0, iyBc = vB ? iyB : 0;

    int t0 = 2 * ox4;
    bool c0 = (t0 - 1 >= 0);
    bool c3 = (t0 + 2 <= W - 1);
    int j0 = c0 ? t0 - 1 : 0;
    int j3 = c3 ? t0 + 2 : 0;

    float acc[COT][4];
#pragma unroll
    for (int o = 0; o < COT; ++o) {
        float b = bias[co0 + o];
#pragma unroll
        for (int j = 0; j < 4; ++j) acc[o][j] = b;
    }

    const float* xn = x + (size_t)n * Cin * H * W;

#pragma unroll UNR
    for (int ci = 0; ci < Cin; ++ci) {
        const float* xc  = xn + (size_t)ci * (H * W);
        const float* xrA = xc + (size_t)iyAc * W;
        const float* xrB = xc + (size_t)iyBc * W;
        float a0 = (vA && c0) ? xrA[j0]     : 0.0f;
        float a1 =  vA        ? xrA[t0]     : 0.0f;
        float a2 =  vA        ? xrA[t0 + 1] : 0.0f;
        float a3 = (vA && c3) ? xrA[j3]     : 0.0f;
        float b0 = (vB && c0) ? xrB[j0]     : 0.0f;
        float b1 =  vB        ? xrB[t0]     : 0.0f;
        float b2 =  vB        ? xrB[t0 + 1] : 0.0f;
        float b3 = (vB && c3) ? xrB[j3]     : 0.0f;

        const float* wci = w + ((size_t)ci * Cout + co0) * 16;
#pragma unroll
        for (int o = 0; o < COT; ++o) {
            const float* wr = wci + (size_t)o * 16;
            float wA0 = wr[p * 4 + 0], wA1 = wr[p * 4 + 1];
            float wA2 = wr[p * 4 + 2], wA3 = wr[p * 4 + 3];
            float wB0 = wr[(p + 2) * 4 + 0], wB1 = wr[(p + 2) * 4 + 1];
            float wB2 = wr[(p + 2) * 4 + 2], wB3 = wr[(p + 2) * 4 + 3];
            acc[o][0] = fmaf(a1, wA1, acc[o][0]); acc[o][0] = fmaf(a0, wA3, acc[o][0]);
            acc[o][0] = fmaf(b1, wB1, acc[o][0]); acc[o][0] = fmaf(b0, wB3, acc[o][0]);
            acc[o][1] = fmaf(a2, wA0, acc[o][1]); acc[o][1] = fmaf(a1, wA2, acc[o][1]);
            acc[o][1] = fmaf(b2, wB0, acc[o][1]); acc[o][1] = fmaf(b1, wB2, acc[o][1]);
            acc[o][2] = fmaf(a2, wA1, acc[o][2]); acc[o][2] = fmaf(a1, wA3, acc[o][2]);
            acc[o][2] = fmaf(b2, wB1, acc[o][2]); acc[o][2] = fmaf(b1, wB3, acc[o][2]);
            acc[o][3] = fmaf(a3, wA0, acc[o][3]); acc[o][3] = fmaf(a2, wA2, acc[o][3]);
            acc[o][3] = fmaf(b3, wB0, acc[o][3]); acc[o][3] = fmaf(b2, wB2, acc[o][3]);
        }
    }

    int ox0 = ox4 * 4;
#pragma unroll
    for (int o = 0; o < COT; ++o) {
        float* yr = y + (((size_t)n * Cout + co0 + o) * OH + oy) * OW + ox0;
#pragma unroll
        for (int j = 0; j < 4; ++j) {
            float v = acc[o][j];
            yr[j] = (ACT == 0) ? fmaxf(v, 0.0f) : tanhf(v);
        }
    }
}

// =============================== quantizer =================================
__global__ void __launch_bounds__(256) embed_norms(
    const float* __restrict__ embed, float* __restrict__ norms)
{
    int c = blockIdx.x * 256 + threadIdx.x;
    const float* e = embed + (size_t)c * 512;
    float s = 0.0f;
    for (int k = 0; k < 512; ++k) s = fmaf(e[k], e[k], s);
    norms[c] = s;
}

// Register-tiled GEMM argmin: 16 rows x 1024 codes per block, thread owns
// 4 consecutive codes (float4 loads from transposed codebook et[512][1024]).
// Accumulation order over k is sequential ascending -> distances identical
// to the previous passing kernel.
__global__ void __launch_bounds__(256) vq_argmin16(
    const float* __restrict__ z, const float* __restrict__ et,
    const float* __restrict__ norms, int* __restrict__ out)
{
    constexpr int ZS = 516;                 // padded LDS row stride (floats)
    int row0 = blockIdx.x * 16;             // 512 blocks
    int n    = row0 >> 8;
    int yx0  = row0 & 255;
    int tid  = threadIdx.x;

    __shared__ float zr[16 * ZS];           // 33,024 B

    // stage 16 z rows: zr[r][k] = z[n][k][yx0+r]
    const float* zn = z + ((size_t)n * 512) * 256;
#pragma unroll
    for (int it = 0; it < 8; ++it) {
        int i  = tid + 256 * it;            // i in 0..2047
        int rq = i & 3, kc = i >> 2;
        float4 v = *(const float4*)&zn[(size_t)kc * 256 + yx0 + 4 * rq];
        zr[(4 * rq + 0) * ZS + kc] = v.x;
        zr[(4 * rq + 1) * ZS + kc] = v.y;
        zr[(4 * rq + 2) * ZS + kc] = v.z;
        zr[(4 * rq + 3) * ZS + kc] = v.w;
    }
    __syncthreads();

    float acc[16][4];
#pragma unroll
    for (int r = 0; r < 16; ++r)
#pragma unroll
        for (int j = 0; j < 4; ++j) acc[r][j] = 0.0f;

    const float* ebase = et + 4 * tid;      // codes 4*tid .. 4*tid+3
#pragma unroll 1
    for (int k4 = 0; k4 < 128; ++k4) {
        float4 e0 = *(const float4*)&ebase[(size_t)(4 * k4 + 0) * 1024];
        float4 e1 = *(const float4*)&ebase[(size_t)(4 * k4 + 1) * 1024];
        float4 e2 = *(const float4*)&ebase[(size_t)(4 * k4 + 2) * 1024];
        float4 e3 = *(const float4*)&ebase[(size_t)(4 * k4 + 3) * 1024];
#pragma unroll
        for (int r = 0; r < 16; ++r) {
            float4 zz = *(const float4*)&zr[r * ZS + 4 * k4];
            float a0 = acc[r][0], a1 = acc[r][1], a2 = acc[r][2], a3 = acc[r][3];
            a0 = fmaf(zz.x, e0.x, a0); a0 = fmaf(zz.y, e1.x, a0);
            a0 = fmaf(zz.z, e2.x, a0); a0 = fmaf(zz.w, e3.x, a0);
            a1 = fmaf(zz.x, e0.y, a1); a1 = fmaf(zz.y, e1.y, a1);
            a1 = fmaf(zz.z, e2.y, a1); a1 = fmaf(zz.w, e3.y, a1);
            a2 = fmaf(zz.x, e0.z, a2); a2 = fmaf(zz.y, e1.z, a2);
            a2 = fmaf(zz.z, e2.z, a2); a2 = fmaf(zz.w, e3.z, a2);
            a3 = fmaf(zz.x, e0.w, a3); a3 = fmaf(zz.y, e1.w, a3);
            a3 = fmaf(zz.z, e2.w, a3); a3 = fmaf(zz.w, e3.w, a3);
            acc[r][0] = a0; acc[r][1] = a1; acc[r][2] = a2; acc[r][3] = a3;
        }
    }

    // thread-local best over its 4 codes (ascending code order, ties -> low)
    float4 nb = *(const float4*)&norms[4 * tid];
    float best[16]; int bi[16];
#pragma unroll
    for (int r = 0; r < 16; ++r) {
        float d0 = nb.x - 2.0f * acc[r][0];
        float d1 = nb.y - 2.0f * acc[r][1];
        float d2 = nb.z - 2.0f * acc[r][2];
        float d3 = nb.w - 2.0f * acc[r][3];
        float b = d0; int ix = 4 * tid;
        if (d1 < b) { b = d1; ix = 4 * tid + 1; }
        if (d2 < b) { b = d2; ix = 4 * tid + 2; }
        if (d3 < b) { b = d3; ix = 4 * tid + 3; }
        best[r] = b; bi[r] = ix;
    }

    // block reduction (reuse zr LDS: 4096 floats + 4096 ints <= 16*516)
    __syncthreads();
    float* rbd = zr;
    int*   rbi = (int*)(zr + 4096);
#pragma unroll
    for (int r = 0; r < 16; ++r) {
        rbd[r * 256 + tid] = best[r];
        rbi[r * 256 + tid] = bi[r];
    }
    __syncthreads();
    for (int s = 128; s > 0; s >>= 1) {
        if (tid < s) {
#pragma unroll
            for (int r = 0; r < 16; ++r) {
                int i0 = r * 256 + tid;
                float od = rbd[i0 + s]; int oi = rbi[i0 + s];
                float md = rbd[i0];     int mi = rbi[i0];
                if (od < md || (od == md && oi < mi)) { rbd[i0] = od; rbi[i0] = oi; }
            }
        }
        __syncthreads();
    }
    if (tid < 16) out[row0 + tid] = rbi[tid * 256];
}

__global__ void __launch_bounds__(256) vq_gather_pack(
    const int* __restrict__ vidx, const float* __restrict__ embed,
    unsigned* __restrict__ zq)
{
    int i = blockIdx.x * 256 + threadIdx.x;
    int yx = i & 255;
    int t  = i >> 8;
    int c  = t & 511;
    int n  = t >> 9;
    int row = (n << 8) + yx;
    zq[i] = pack_split(embed[(size_t)vidx[row] * 512 + c]);
}

// ================================ launch ===================================
extern "C" void kernel_launch(void* const* d_in, const int* in_sizes, int n_in,
                              void* d_out, int out_size, void* d_ws, size_t ws_size,
                              hipStream_t stream)
{
    (void)in_sizes; (void)n_in; (void)out_size; (void)ws_size;
    const float* x     = (const float*)d_in[0];
    const float* ew1   = (const float*)d_in[1];
    const float* eb1   = (const float*)d_in[2];
    const float* ew2   = (const float*)d_in[3];
    const float* eb2   = (const float*)d_in[4];
    const float* ew3   = (const float*)d_in[5];
    const float* eb3   = (const float*)d_in[6];
    const float* ew4   = (const float*)d_in[7];
    const float* eb4   = (const float*)d_in[8];
    const float* dw1   = (const float*)d_in[9];
    const float* db1   = (const float*)d_in[10];
    const float* dw2   = (const float*)d_in[11];
    const float* db2   = (const float*)d_in[12];
    const float* dw3   = (const float*)d_in[13];
    const float* db3   = (const float*)d_in[14];
    const float* dw4   = (const float*)d_in[15];
    const float* db4   = (const float*)d_in[16];
    const float* embed = (const float*)d_in[17];
    float* out = (float*)d_out;

    // ---- workspace layout (u32 units). Peak identical to R8 usage.
    unsigned* W0   = (unsigned*)d_ws;
    unsigned* h1p  = W0;                          // conv1 out (dead after conv2)
    unsigned* h2p  = W0 + 33554432;               // conv2 out
    unsigned* h3p  = W0;                          // overlays dead h1p
    float*    z    = (float*)(W0 + 8388608);      // conv4 out fp32
    unsigned* zq   = W0 + 12582912;               // quantized, packed u32
    float*    P0   = (float*)(W0 + 16777216);     // convt1 out (packed u32)
    float*    P1   = (float*)(W0 + 20971520);     // convt2 out (packed u32)
    int*      vidx = (int*)(W0 + 29360128);
    float*    norms= (float*)(W0 + 29368320);
    float*    g3o  = (float*)h2p;                 // convt3 out fp32 (h2p dead)

    // packed weights + transposed codebook live in d_out until g4 overwrites
    unsigned* wp2 = (unsigned*)d_out;             // 131,072
    unsigned* wp3 = wp2 + 131072;                 // 524,288
    unsigned* wp4 = wp2 + 655360;                 // 2,097,152
    unsigned* wq1 = wp2 + 2752512;                // 1,048,576 (4x128x2048)
    unsigned* wq2 = wq1 + 1048576;                // 131,072   (4x64x512)
    unsigned* wq3 = wq2 + 131072;                 // 32,768    (4x32x256)
    float*    et  = (float*)(wq3 + 32768);        // 524,288 (512x1024)

    dim3 b256(256);

    // ---- pre-pass: pack encoder weights, repack decoder weights, et ----
    pack_tensor<<<dim3(512),  b256, 0, stream>>>(ew2, wp2, 131072);
    pack_tensor<<<dim3(2048), b256, 0, stream>>>(ew3, wp3, 524288);
    pack_tensor<<<dim3(8192), b256, 0, stream>>>(ew4, wp4, 2097152);
    repack_wt<512, 128><<<dim3(4096), b256, 0, stream>>>(dw1, wq1);
    repack_wt<128,  64><<<dim3(512),  b256, 0, stream>>>(dw2, wq2);
    repack_wt< 64,  32><<<dim3(128),  b256, 0, stream>>>(dw3, wq3);
    embed_transpose<<<dim3(2048), b256, 0, stream>>>(embed, et);

    // ---- encoder ----
    conv4s2_k<3, 256, 256, 64, 4, 3, 1><<<dim3(8192), b256, 0, stream>>>(
        x, ew1, eb1, (float*)h1p);                         // h1 (packed)
    conv4s2_mfma<64, 128, 128, 128, 1><<<dim3(2048), b256, 0, stream>>>(
        h1p, wp2, eb2, (float*)h2p);                       // h2 (packed)
    conv4s2_mfma<128, 64, 64, 256, 1><<<dim3(1024), b256, 0, stream>>>(
        h2p, wp3, eb3, (float*)h3p);                       // h3 (packed)
    conv4s2_mfma<256, 32, 32, 512, 0><<<dim3(512), b256, 0, stream>>>(
        h3p, wp4, eb4, z);                                 // z (fp32)

    // ---- quantizer ----
    embed_norms<<<dim3(4), b256, 0, stream>>>(embed, norms);
    vq_argmin16<<<dim3(512), b256, 0, stream>>>(z, et, norms, vidx);
    vq_gather_pack<<<dim3(16384), b256, 0, stream>>>(vidx, embed, zq);

    // ---- decoder (MFMA parity-GEMM convT) ----
    convt4s2_mfma<512, 16, 16, 128, 4, 2, 1><<<dim3(4 * 128), b256, 0, stream>>>(
        zq, wq1, db1, P0);                                 // P0 (packed)
    convt4s2_mfma<128, 32, 32, 64, 4, 1, 1><<<dim3(4 * 512), b256, 0, stream>>>(
        (const unsigned*)P0, wq2, db2, P1);                // P1 (packed)
    convt4s2_mfma<64, 64, 64, 32, 2, 1, 0><<<dim3(4 * 2048), b256, 0, stream>>>(
        (const unsigned*)P1, wq3, db3, g3o);               // g3o (fp32)
    convt4s2_k<32, 128, 128, 3, 3, 1, 2><<<dim3(2048), b256, 0, stream>>>(
        g3o, dw4, db4, out);                               // tanh -> d_out
}

// Round 4
// 1166.761 us; speedup vs baseline: 1.6310x; 1.0900x over previous
//
#include <hip/hip_runtime.h>
#include <math.h>

// ---------------------------------------------------------------------------
// VQ-VAE forward. Round 11: encoder conv1 (3->64, 256x256) moved from direct
// fp32 (216 us, latency-bound) to the MFMA implicit-GEMM path via a
// generalized template: sub-row M-tiles for OW=128 and zero-padded K
// (Cin=4, real channels CINR=3 masked at load). Input x packed hi/lo in a
// pre-pass. Everything else identical to proven R10 kernel.
// ---------------------------------------------------------------------------

typedef __attribute__((ext_vector_type(8))) short bf16x8;
typedef __attribute__((ext_vector_type(4))) float f32x4;
union FragU { unsigned u[4]; bf16x8 v; };

__device__ __forceinline__ unsigned bf16_rne(unsigned u) {
    return (u + 0x7FFFu + ((u >> 16) & 1u)) >> 16;
}
// pack fp32 -> u32: low16 = bf16(v), high16 = bf16(v - bf16(v))
__device__ __forceinline__ unsigned pack_split(float v) {
    unsigned u = __builtin_bit_cast(unsigned, v);
    unsigned hi = bf16_rne(u);
    float hif = __builtin_bit_cast(float, hi << 16);
    float r = v - hif;
    unsigned lo = bf16_rne(__builtin_bit_cast(unsigned, r));
    return hi | (lo << 16);
}

__global__ void __launch_bounds__(256) pack_tensor(
    const float* __restrict__ s, unsigned* __restrict__ d, int n)
{
    int i = blockIdx.x * 256 + threadIdx.x;
    if (i < n) d[i] = pack_split(s[i]);
}

// conv1 weights (64,3,4,4) -> padded packed [64][64] (k>=48 zero)
__global__ void __launch_bounds__(256) pack_w1(
    const float* __restrict__ w, unsigned* __restrict__ wq)
{
    int idx = blockIdx.x * 256 + threadIdx.x;
    if (idx >= 64 * 64) return;
    int k = idx & 63, oc = idx >> 6;
    float v = (k < 48) ? w[oc * 48 + k] : 0.0f;
    wq[idx] = pack_split(v);
}

// repack ConvTranspose weights (torch layout Cin,Cout,4,4) into
// wq[par][co][ci*4 + t], t = 2r+s, packed hi/lo. par = dy*2+dx.
template<int Cin, int Cout>
__global__ void __launch_bounds__(256) repack_wt(
    const float* __restrict__ w, unsigned* __restrict__ wq)
{
    constexpr int TOT = 16 * Cin * Cout;
    int idx = blockIdx.x * 256 + threadIdx.x;
    if (idx >= TOT) return;
    int t  = idx & 3;
    int ci = (idx >> 2) % Cin;
    int rest = (idx >> 2) / Cin;
    int co  = rest % Cout;
    int par = rest / Cout;
    int dy = par >> 1, dx = par & 1;
    int r = t >> 1, s = t & 1;
    int ky = 3 - dy - 2 * r;
    int kx = 3 - dx - 2 * s;
    float v = w[(((size_t)ci * Cout + co) * 4 + ky) * 4 + kx];
    wq[idx] = pack_split(v);
}

// transpose codebook: embed[1024][512] -> et[512][1024]
__global__ void __launch_bounds__(256) embed_transpose(
    const float* __restrict__ embed, float* __restrict__ et)
{
    int idx = blockIdx.x * 256 + threadIdx.x;   // 2048 blocks x 256
    int c = idx & 1023, k = idx >> 10;
    et[idx] = embed[(size_t)c * 512 + k];
}

// ================= MFMA conv k=4 s=2 p=1 + ReLU (implicit GEMM) ============
// (conv2..4; unchanged from R10)
template<int Cin, int H, int W, int Cout, int PACKO>
__global__ void __launch_bounds__(256) conv4s2_mfma(
    const unsigned* __restrict__ xp, const unsigned* __restrict__ wp,
    const float* __restrict__ bias, float* __restrict__ y)
{
    constexpr int OH = H / 2, OW = W / 2;
    constexpr int LOG_OW = (OW == 64) ? 6 : (OW == 32) ? 5 : 4;
    constexpr int R   = 64 / OW;
    constexpr int RT  = 2 * R + 2;
    constexpr int CS  = W + 2;
    constexpr int XEL = 2 * RT * CS;
    constexpr int XIT = (XEL + 255) / 256;
    constexpr int K   = Cin * 16;
    constexpr int NC  = Cin / 2;
    constexpr int NB  = 128;
    constexpr int MBC = 32 * OH * OW / 64;

    __shared__ unsigned smem[8704];
    unsigned* raw = smem;
    unsigned* wb  = smem + ((XEL + 7) & ~7);

    int bid = blockIdx.x;
    int mb = bid % MBC, ng = bid / MBC;
    int oc0 = ng * NB;
    int m0 = mb * 64;
    int nimg = m0 / (OH * OW);
    int sp0 = m0 % (OH * OW);
    int oyb = sp0 >> LOG_OW;

    int tid  = threadIdx.x;
    int lane = tid & 63, wv = tid >> 6;
    int lm = lane & 15, q = lane >> 4;
    int n0w = wv * 32;

    const unsigned* xbase = xp + (size_t)nimg * Cin * H * W;

    int  goff[XIT];
    bool gok[XIT];
#pragma unroll
    for (int s = 0; s < XIT; ++s) {
        int i = tid + 256 * s;
        goff[s] = 0; gok[s] = false;
        if (i < XEL) {
            int lc = i % CS;
            int t2 = i / CS;
            int lr = t2 % RT;
            int c  = t2 / RT;
            int gr = 2 * oyb - 1 + lr;
            int gc = lc - 1;
            bool ok = ((unsigned)gr < (unsigned)H) && ((unsigned)gc < (unsigned)W);
            goff[s] = ok ? (c * H * W + gr * W + gc) : 0;
            gok[s]  = ok;
        }
    }
    const unsigned* wbase = wp + (size_t)(oc0 + (tid >> 5)) * K + (tid & 31);
    int wlds0 = (tid >> 5) * 36 + (tid & 31);

    f32x4 acc[4][2];
#pragma unroll
    for (int nt = 0; nt < 2; ++nt) {
        float b = bias[oc0 + n0w + nt * 16 + lm];
#pragma unroll
        for (int mt = 0; mt < 4; ++mt)
#pragma unroll
            for (int r = 0; r < 4; ++r) acc[mt][nt][r] = b;
    }

    unsigned pfa[XIT];
    unsigned pfb[16];

    auto load_chunk = [&](int ch) {
        const unsigned* cb = xbase + (size_t)(ch * 2) * (H * W);
#pragma unroll
        for (int s = 0; s < XIT; ++s) {
            unsigned v = 0;
            if (gok[s]) v = cb[goff[s]];
            pfa[s] = v;
        }
        const unsigned* wc = wbase + ch * 32;
#pragma unroll
        for (int s = 0; s < 16; ++s) pfb[s] = wc[(size_t)s * 8 * K];
    };
    auto store_chunk = [&]() {
#pragma unroll
        for (int s = 0; s < XIT; ++s) {
            int i = tid + 256 * s;
            if (i < XEL) raw[i] = pfa[s];
        }
#pragma unroll
        for (int s = 0; s < 16; ++s) wb[wlds0 + s * 288] = pfb[s];
    };

    load_chunk(0);
#pragma unroll 1
    for (int ch = 0; ch < NC; ++ch) {
        __syncthreads();
        store_chunk();
        __syncthreads();
        if (ch + 1 < NC) load_chunk(ch + 1);

        FragU bhi[2], blo[2];
#pragma unroll
        for (int nt = 0; nt < 2; ++nt) {
            const unsigned* bp = &wb[(n0w + nt * 16 + lm) * 36 + q * 8];
            uint4 p0 = *(const uint4*)bp;
            uint4 p1 = *(const uint4*)(bp + 4);
            unsigned e0 = p0.x, e1 = p0.y, e2 = p0.z, e3 = p0.w;
            unsigned e4 = p1.x, e5 = p1.y, e6 = p1.z, e7 = p1.w;
            bhi[nt].u[0] = (e0 & 0xffffu) | (e1 << 16);
            bhi[nt].u[1] = (e2 & 0xffffu) | (e3 << 16);
            bhi[nt].u[2] = (e4 & 0xffffu) | (e5 << 16);
            bhi[nt].u[3] = (e6 & 0xffffu) | (e7 << 16);
            blo[nt].u[0] = (e0 >> 16) | (e1 & 0xffff0000u);
            blo[nt].u[1] = (e2 >> 16) | (e3 & 0xffff0000u);
            blo[nt].u[2] = (e4 >> 16) | (e5 & 0xffff0000u);
            blo[nt].u[3] = (e6 >> 16) | (e7 & 0xffff0000u);
        }
#pragma unroll
        for (int mt = 0; mt < 4; ++mt) {
            int m = mt * 16 + lm;
            int oyl = m >> LOG_OW, oxl = m & (OW - 1);
            int c = q >> 1, rb = 2 * oyl + (q & 1) * 2;
            const unsigned* rp = &raw[(c * RT + rb) * CS + 2 * oxl];
            uint2 a0 = *(const uint2*)rp;
            uint2 a1 = *(const uint2*)(rp + 2);
            uint2 a2 = *(const uint2*)(rp + CS);
            uint2 a3 = *(const uint2*)(rp + CS + 2);
            FragU ahi, alo;
            ahi.u[0] = (a0.x & 0xffffu) | (a0.y << 16);
            ahi.u[1] = (a1.x & 0xffffu) | (a1.y << 16);
            ahi.u[2] = (a2.x & 0xffffu) | (a2.y << 16);
            ahi.u[3] = (a3.x & 0xffffu) | (a3.y << 16);
            alo.u[0] = (a0.x >> 16) | (a0.y & 0xffff0000u);
            alo.u[1] = (a1.x >> 16) | (a1.y & 0xffff0000u);
            alo.u[2] = (a2.x >> 16) | (a2.y & 0xffff0000u);
            alo.u[3] = (a3.x >> 16) | (a3.y & 0xffff0000u);
#pragma unroll
            for (int nt = 0; nt < 2; ++nt) {
                acc[mt][nt] = __builtin_amdgcn_mfma_f32_16x16x32_bf16(
                    ahi.v, bhi[nt].v, acc[mt][nt], 0, 0, 0);
                acc[mt][nt] = __builtin_amdgcn_mfma_f32_16x16x32_bf16(
                    ahi.v, blo[nt].v, acc[mt][nt], 0, 0, 0);
                acc[mt][nt] = __builtin_amdgcn_mfma_f32_16x16x32_bf16(
                    alo.v, bhi[nt].v, acc[mt][nt], 0, 0, 0);
            }
        }
    }

    __syncthreads();
    float* cs = (float*)smem;
#pragma unroll
    for (int mt = 0; mt < 4; ++mt)
#pragma unroll
        for (int nt = 0; nt < 2; ++nt) {
            int nl = n0w + nt * 16 + lm;
#pragma unroll
            for (int r = 0; r < 4; ++r)
                cs[nl * 68 + mt * 16 + q * 4 + r] = acc[mt][nt][r];
        }
    __syncthreads();
    {
        int nl = tid >> 1, half = tid & 1;
        size_t gb = ((size_t)(nimg * Cout + oc0 + nl)) * (OH * OW) + sp0 + half * 32;
#pragma unroll
        for (int i2 = 0; i2 < 8; ++i2) {
            float4 v = *(float4*)&cs[nl * 68 + half * 32 + 4 * i2];
            v.x = fmaxf(v.x, 0.0f); v.y = fmaxf(v.y, 0.0f);
            v.z = fmaxf(v.z, 0.0f); v.w = fmaxf(v.w, 0.0f);
            if (PACKO) {
                uint4 p;
                p.x = pack_split(v.x); p.y = pack_split(v.y);
                p.z = pack_split(v.z); p.w = pack_split(v.w);
                *(uint4*)((unsigned*)y + gb + 4 * i2) = p;
            } else {
                *(float4*)(y + gb + 4 * i2) = v;
            }
        }
    }
}

// ========== generalized MFMA conv (sub-row tiles + zero-padded K) ==========
// For conv1: Cin=4 (padded), CINR=3 real channels, OW=128 -> block = 64 cols
// of one output row. Wave layout MT/NT as in convt4s2_mfma.
template<int Cin, int CINR, int H, int W, int Cout, int MT, int NT, int PACKO>
__global__ void __launch_bounds__(256) conv4s2_mfma_g(
    const unsigned* __restrict__ xp, const unsigned* __restrict__ wp,
    const float* __restrict__ bias, float* __restrict__ y)
{
    constexpr int OH = H / 2, OW = W / 2;
    constexpr int OWB = (OW >= 64) ? 64 : OW;     // out cols per block
    constexpr int LOG_OWB = (OWB == 64) ? 6 : (OWB == 32) ? 5 : 4;
    constexpr int LOG_OW  = (OW == 128) ? 7 : (OW == 64) ? 6 : (OW == 32) ? 5 : 4;
    constexpr int R   = 64 / OWB;                 // out rows per block
    constexpr int RT  = 2 * R + 2;                // staged input rows
    constexpr int CS  = 2 * OWB + 2;              // staged input cols
    constexpr int XEL = 2 * RT * CS;              // per chunk (2 channels)
    constexpr int XIT = (XEL + 255) / 256;
    constexpr int K   = Cin * 16;
    constexpr int NC  = Cin / 2;
    constexpr int NB  = Cout;
    constexpr int WIT = NB / 8;                   // B-load iters
    constexpr int WN  = Cout / (16 * NT);
    constexpr int WM  = 4 / WN;
    static_assert(WM * MT * 16 == 64, "M tiling");
    static_assert(WN * NT * 16 == Cout, "N tiling");
    constexpr int MBC = 32 * OH * OW / 64;
    constexpr int XPAD = (XEL + 7) & ~7;
    constexpr int SM1 = XPAD + NB * 36;
    constexpr int SM2 = NB * 68;
    constexpr int SMEM = SM1 > SM2 ? SM1 : SM2;

    __shared__ unsigned smem[SMEM];
    unsigned* raw = smem;
    unsigned* wb  = smem + XPAD;

    int bid = blockIdx.x;
    int mb = bid % MBC, ng = bid / MBC;
    int oc0 = ng * NB;
    int m0 = mb * 64;
    int nimg = m0 / (OH * OW);
    int sp0 = m0 % (OH * OW);
    int oyb = sp0 >> LOG_OW;
    int oxb = sp0 & (OW - 1);                     // multiple of OWB

    int tid  = threadIdx.x;
    int lane = tid & 63, wv = tid >> 6;
    int lm = lane & 15, q = lane >> 4;
    int wm = wv / WN, wn = wv % WN;

    const unsigned* xbase = xp + (size_t)nimg * CINR * H * W;

    int  goff[XIT];
    bool gok[XIT];
    int  cidx[XIT];
#pragma unroll
    for (int s = 0; s < XIT; ++s) {
        int i = tid + 256 * s;
        goff[s] = 0; gok[s] = false; cidx[s] = 0;
        if (i < XEL) {
            int lc = i % CS;
            int t2 = i / CS;
            int lr = t2 % RT;
            int c  = t2 / RT;
            int gr = 2 * oyb - 1 + lr;
            int gc = 2 * oxb - 1 + lc;
            bool ok = ((unsigned)gr < (unsigned)H) && ((unsigned)gc < (unsigned)W);
            goff[s] = ok ? (c * H * W + gr * W + gc) : 0;
            gok[s]  = ok;
            cidx[s] = c;
        }
    }
    const unsigned* wbase = wp + (size_t)(oc0 + (tid >> 5)) * K + (tid & 31);
    int wlds0 = (tid >> 5) * 36 + (tid & 31);

    f32x4 acc[MT][NT];
#pragma unroll
    for (int nt = 0; nt < NT; ++nt) {
        float b = bias[oc0 + wn * NT * 16 + nt * 16 + lm];
#pragma unroll
        for (int mt = 0; mt < MT; ++mt)
#pragma unroll
            for (int r = 0; r < 4; ++r) acc[mt][nt][r] = b;
    }

    unsigned pfa[XIT];
    unsigned pfb[WIT];

    auto load_chunk = [&](int ch) {
        const unsigned* cb = xbase + (size_t)(ch * 2) * (H * W);
#pragma unroll
        for (int s = 0; s < XIT; ++s) {
            unsigned v = 0;
            bool okc = (2 * ch + cidx[s]) < CINR;
            if (gok[s] && okc) v = cb[goff[s]];
            pfa[s] = v;
        }
        const unsigned* wc = wbase + ch * 32;
#pragma unroll
        for (int s = 0; s < WIT; ++s) pfb[s] = wc[(size_t)s * 8 * K];
    };
    auto store_chunk = [&]() {
#pragma unroll
        for (int s = 0; s < XIT; ++s) {
            int i = tid + 256 * s;
            if (i < XEL) raw[i] = pfa[s];
        }
#pragma unroll
        for (int s = 0; s < WIT; ++s) wb[wlds0 + s * 288] = pfb[s];
    };

    load_chunk(0);
#pragma unroll 1
    for (int ch = 0; ch < NC; ++ch) {
        __syncthreads();
        store_chunk();
        __syncthreads();
        if (ch + 1 < NC) load_chunk(ch + 1);

        FragU bhi[NT], blo[NT];
#pragma unroll
        for (int nt = 0; nt < NT; ++nt) {
            const unsigned* bp = &wb[(wn * NT * 16 + nt * 16 + lm) * 36 + q * 8];
            uint4 p0 = *(const uint4*)bp;
            uint4 p1 = *(const uint4*)(bp + 4);
            unsigned e0 = p0.x, e1 = p0.y, e2 = p0.z, e3 = p0.w;
            unsigned e4 = p1.x, e5 = p1.y, e6 = p1.z, e7 = p1.w;
            bhi[nt].u[0] = (e0 & 0xffffu) | (e1 << 16);
            bhi[nt].u[1] = (e2 & 0xffffu) | (e3 << 16);
            bhi[nt].u[2] = (e4 & 0xffffu) | (e5 << 16);
            bhi[nt].u[3] = (e6 & 0xffffu) | (e7 << 16);
            blo[nt].u[0] = (e0 >> 16) | (e1 & 0xffff0000u);
            blo[nt].u[1] = (e2 >> 16) | (e3 & 0xffff0000u);
            blo[nt].u[2] = (e4 >> 16) | (e5 & 0xffff0000u);
            blo[nt].u[3] = (e6 >> 16) | (e7 & 0xffff0000u);
        }
#pragma unroll
        for (int mt = 0; mt < MT; ++mt) {
            int m = wm * (MT * 16) + mt * 16 + lm;
            int oyl = m >> LOG_OWB, oxl = m & (OWB - 1);
            int c = q >> 1, rb = 2 * oyl + (q & 1) * 2;
            const unsigned* rp = &raw[(c * RT + rb) * CS + 2 * oxl];
            uint2 a0 = *(const uint2*)rp;
            uint2 a1 = *(const uint2*)(rp + 2);
            uint2 a2 = *(const uint2*)(rp + CS);
            uint2 a3 = *(const uint2*)(rp + CS + 2);
            FragU ahi, alo;
            ahi.u[0] = (a0.x & 0xffffu) | (a0.y << 16);
            ahi.u[1] = (a1.x & 0xffffu) | (a1.y << 16);
            ahi.u[2] = (a2.x & 0xffffu) | (a2.y << 16);
            ahi.u[3] = (a3.x & 0xffffu) | (a3.y << 16);
            alo.u[0] = (a0.x >> 16) | (a0.y & 0xffff0000u);
            alo.u[1] = (a1.x >> 16) | (a1.y & 0xffff0000u);
            alo.u[2] = (a2.x >> 16) | (a2.y & 0xffff0000u);
            alo.u[3] = (a3.x >> 16) | (a3.y & 0xffff0000u);
#pragma unroll
            for (int nt = 0; nt < NT; ++nt) {
                acc[mt][nt] = __builtin_amdgcn_mfma_f32_16x16x32_bf16(
                    ahi.v, bhi[nt].v, acc[mt][nt], 0, 0, 0);
                acc[mt][nt] = __builtin_amdgcn_mfma_f32_16x16x32_bf16(
                    ahi.v, blo[nt].v, acc[mt][nt], 0, 0, 0);
                acc[mt][nt] = __builtin_amdgcn_mfma_f32_16x16x32_bf16(
                    alo.v, bhi[nt].v, acc[mt][nt], 0, 0, 0);
            }
        }
    }

    // epilogue: LDS transpose, relu, coalesced contiguous store (64 m / ch)
    __syncthreads();
    float* cs = (float*)smem;
#pragma unroll
    for (int mt = 0; mt < MT; ++mt)
#pragma unroll
        for (int nt = 0; nt < NT; ++nt) {
            int nl  = wn * NT * 16 + nt * 16 + lm;
            int mb2 = wm * (MT * 16) + mt * 16 + q * 4;
#pragma unroll
            for (int r = 0; r < 4; ++r)
                cs[nl * 68 + mb2 + r] = acc[mt][nt][r];
        }
    __syncthreads();
    {
        constexpr int QT = 256 / NB;              // m-quarters per channel
        int nl = tid / QT, qt = tid % QT;
        constexpr int MQ = 64 / QT;               // m per thread
        size_t gb = ((size_t)(nimg * Cout + oc0 + nl)) * (OH * OW) + sp0 + qt * MQ;
#pragma unroll
        for (int i2 = 0; i2 < MQ / 4; ++i2) {
            float4 v = *(float4*)&cs[nl * 68 + qt * MQ + 4 * i2];
            v.x = fmaxf(v.x, 0.0f); v.y = fmaxf(v.y, 0.0f);
            v.z = fmaxf(v.z, 0.0f); v.w = fmaxf(v.w, 0.0f);
            if (PACKO) {
                uint4 p;
                p.x = pack_split(v.x); p.y = pack_split(v.y);
                p.z = pack_split(v.z); p.w = pack_split(v.w);
                *(uint4*)((unsigned*)y + gb + 4 * i2) = p;
            } else {
                *(float4*)(y + gb + 4 * i2) = v;
            }
        }
    }
}

// ============ MFMA ConvTranspose k=4 s=2 p=1 + ReLU (parity GEMM) ==========
template<int Cin, int Hh, int Wh, int Cout, int MT, int NT, int PACKO>
__global__ void __launch_bounds__(256) convt4s2_mfma(
    const unsigned* __restrict__ xp, const unsigned* __restrict__ wq,
    const float* __restrict__ bias, float* __restrict__ y)
{
    constexpr int W = Wh;
    constexpr int LOG_W = (W == 64) ? 6 : (W == 32) ? 5 : 4;
    constexpr int R   = 64 / W;
    constexpr int RT  = R + 1;
    constexpr int CS  = W + 2;
    constexpr int XEL = 8 * RT * CS;
    constexpr int XIT = (XEL + 255) / 256;
    constexpr int K   = Cin * 4;
    constexpr int NC  = Cin / 8;
    constexpr int NB  = Cout;
    constexpr int WIT = NB / 8;
    constexpr int WN  = Cout / (16 * NT);
    constexpr int WM  = 4 / WN;
    static_assert(WM * MT * 16 == 64, "M tiling");
    static_assert(WN * NT * 16 == Cout, "N tiling");
    constexpr int MBC = 32 * Hh * W / 64;
    constexpr int XPAD = (XEL + 7) & ~7;
    constexpr int SM1 = XPAD + NB * 36;
    constexpr int SM2 = NB * 68;
    constexpr int SMEM = SM1 > SM2 ? SM1 : SM2;

    __shared__ unsigned smem[SMEM];
    unsigned* raw = smem;
    unsigned* wb  = smem + XPAD;

    int bid = blockIdx.x;
    int mb  = bid % MBC;
    int par = bid / MBC;
    int dy = par >> 1, dx = par & 1;

    int m0   = mb * 64;
    int nimg = m0 / (Hh * W);
    int sp0  = m0 % (Hh * W);
    int il0  = sp0 >> LOG_W;

    int tid = threadIdx.x;
    int lane = tid & 63, wv = tid >> 6;
    int lm = lane & 15, q = lane >> 4;
    int wm = wv / WN, wn = wv % WN;

    const unsigned* xbase = xp + (size_t)nimg * Cin * Hh * W;

    int  goff[XIT];
    bool gok[XIT];
#pragma unroll
    for (int s = 0; s < XIT; ++s) {
        int i = tid + 256 * s;
        goff[s] = 0; gok[s] = false;
        if (i < XEL) {
            int lc = i % CS;
            int t2 = i / CS;
            int lr = t2 % RT;
            int c  = t2 / RT;
            int gr = il0 - 1 + dy + lr;
            int gc = lc - 1;
            bool ok = ((unsigned)gr < (unsigned)Hh) && ((unsigned)gc < (unsigned)W);
            goff[s] = ok ? (c * Hh * W + gr * W + gc) : 0;
            gok[s]  = ok;
        }
    }
    const unsigned* wbase = wq + (size_t)(par * Cout + (tid >> 5)) * K + (tid & 31);
    int wlds0 = (tid >> 5) * 36 + (tid & 31);

    f32x4 acc[MT][NT];
#pragma unroll
    for (int nt = 0; nt < NT; ++nt) {
        float b = bias[wn * NT * 16 + nt * 16 + lm];
#pragma unroll
        for (int mt = 0; mt < MT; ++mt)
#pragma unroll
            for (int r = 0; r < 4; ++r) acc[mt][nt][r] = b;
    }

    unsigned pfa[XIT];
    unsigned pfb[WIT];

    auto load_chunk = [&](int ch) {
        const unsigned* cb = xbase + (size_t)(ch * 8) * (Hh * W);
#pragma unroll
        for (int s = 0; s < XIT; ++s) {
            unsigned v = 0;
            if (gok[s]) v = cb[goff[s]];
            pfa[s] = v;
        }
        const unsigned* wc = wbase + ch * 32;
#pragma unroll
        for (int s = 0; s < WIT; ++s) pfb[s] = wc[(size_t)s * 8 * K];
    };
    auto store_chunk = [&]() {
#pragma unroll
        for (int s = 0; s < XIT; ++s) {
            int i = tid + 256 * s;
            if (i < XEL) raw[i] = pfa[s];
        }
#pragma unroll
        for (int s = 0; s < WIT; ++s) wb[wlds0 + s * 288] = pfb[s];
    };

    load_chunk(0);
#pragma unroll 1
    for (int ch = 0; ch < NC; ++ch) {
        __syncthreads();
        store_chunk();
        __syncthreads();
        if (ch + 1 < NC) load_chunk(ch + 1);

        FragU bhi[NT], blo[NT];
#pragma unroll
        for (int nt = 0; nt < NT; ++nt) {
            const unsigned* bp = &wb[(wn * NT * 16 + nt * 16 + lm) * 36 + q * 8];
            uint4 p0 = *(const uint4*)bp;
            uint4 p1 = *(const uint4*)(bp + 4);
            unsigned e0 = p0.x, e1 = p0.y, e2 = p0.z, e3 = p0.w;
            unsigned e4 = p1.x, e5 = p1.y, e6 = p1.z, e7 = p1.w;
            bhi[nt].u[0] = (e0 & 0xffffu) | (e1 << 16);
            bhi[nt].u[1] = (e2 & 0xffffu) | (e3 << 16);
            bhi[nt].u[2] = (e4 & 0xffffu) | (e5 << 16);
            bhi[nt].u[3] = (e6 & 0xffffu) | (e7 << 16);
            blo[nt].u[0] = (e0 >> 16) | (e1 & 0xffff0000u);
            blo[nt].u[1] = (e2 >> 16) | (e3 & 0xffff0000u);
            blo[nt].u[2] = (e4 >> 16) | (e5 & 0xffff0000u);
            blo[nt].u[3] = (e6 >> 16) | (e7 & 0xffff0000u);
        }
#pragma unroll
        for (int mt = 0; mt < MT; ++mt) {
            int ml = wm * (MT * 16) + mt * 16 + lm;
            int il = ml >> LOG_W, jl = ml & (W - 1);
            const unsigned* rp = &raw[((2 * q) * RT + il) * CS + jl + dx];
            unsigned a00 = rp[0],               a01 = rp[1];
            unsigned a10 = rp[CS],              a11 = rp[CS + 1];
            unsigned a20 = rp[RT * CS],         a21 = rp[RT * CS + 1];
            unsigned a30 = rp[RT * CS + CS],    a31 = rp[RT * CS + CS + 1];
            FragU ahi, alo;
            ahi.u[0] = (a00 & 0xffffu) | (a01 << 16);
            ahi.u[1] = (a10 & 0xffffu) | (a11 << 16);
            ahi.u[2] = (a20 & 0xffffu) | (a21 << 16);
            ahi.u[3] = (a30 & 0xffffu) | (a31 << 16);
            alo.u[0] = (a00 >> 16) | (a01 & 0xffff0000u);
            alo.u[1] = (a10 >> 16) | (a11 & 0xffff0000u);
            alo.u[2] = (a20 >> 16) | (a21 & 0xffff0000u);
            alo.u[3] = (a30 >> 16) | (a31 & 0xffff0000u);
#pragma unroll
            for (int nt = 0; nt < NT; ++nt) {
                acc[mt][nt] = __builtin_amdgcn_mfma_f32_16x16x32_bf16(
                    ahi.v, bhi[nt].v, acc[mt][nt], 0, 0, 0);
                acc[mt][nt] = __builtin_amdgcn_mfma_f32_16x16x32_bf16(
                    ahi.v, blo[nt].v, acc[mt][nt], 0, 0, 0);
                acc[mt][nt] = __builtin_amdgcn_mfma_f32_16x16x32_bf16(
                    alo.v, bhi[nt].v, acc[mt][nt], 0, 0, 0);
            }
        }
    }

    __syncthreads();
    float* cs = (float*)smem;
#pragma unroll
    for (int mt = 0; mt < MT; ++mt)
#pragma unroll
        for (int nt = 0; nt < NT; ++nt) {
            int nl  = wn * NT * 16 + nt * 16 + lm;
            int mb2 = wm * (MT * 16) + mt * 16 + q * 4;
#pragma unroll
            for (int r = 0; r < 4; ++r)
                cs[nl * 68 + mb2 + r] = acc[mt][nt][r];
        }
    __syncthreads();
    constexpr int EIT = NB * 64 / 256;
#pragma unroll
    for (int it = 0; it < EIT; ++it) {
        int idx = tid + 256 * it;
        int c = idx >> 6, m = idx & 63;
        int il = m >> LOG_W, jl = m & (W - 1);
        int oy = 2 * (il0 + il) + dy;
        int ox = 2 * jl + dx;
        float v = fmaxf(cs[c * 68 + m], 0.0f);
        size_t go = (((size_t)(nimg * Cout + c)) * (2 * Hh) + oy) * (2 * W) + ox;
        if (PACKO) ((unsigned*)y)[go] = pack_split(v);
        else       y[go] = v;
    }
}

// ================= direct convT (g4, tanh) =================================
template<int Cin, int H, int W, int Cout, int COT, int ACT, int UNR>
__global__ void __launch_bounds__(256) convt4s2_k(
    const float* __restrict__ x, const float* __restrict__ w,
    const float* __restrict__ bias, float* __restrict__ y)
{
    constexpr int OH = 2 * H, OW = 2 * W, OWq = OW / 4;
    int id = blockIdx.x * 256 + threadIdx.x;
    int ox4 = id % OWq; int t = id / OWq;
    int oy  = t % OH;   t /= OH;
    int cog = t % (Cout / COT);
    int n   = t / (Cout / COT);
    int co0 = __builtin_amdgcn_readfirstlane(cog * COT);
    n       = __builtin_amdgcn_readfirstlane(n);

    int p   = (oy + 1) & 1;
    int iyA = (oy + 1 - p) >> 1;
    int iyB = iyA - 1;
    bool vA = (iyA < H);
    bool vB = (iyB >= 0);
    int iyAc = vA ? iyA : 0, iyBc = vB ? iyB : 0;

    int t0 = 2 * ox4;
    bool c0 = (t0 - 1 >= 0);
    bool c3 = (t0 + 2 <= W - 1);
    int j0 = c0 ? t0 - 1 : 0;
    int j3 = c3 ? t0 + 2 : 0;

    float acc[COT][4];
#pragma unroll
    for (int o = 0; o < COT; ++o) {
        float b = bias[co0 + o];
#pragma unroll
        for (int j = 0; j < 4; ++j) acc[o][j] = b;
    }

    const float* xn = x + (size_t)n * Cin * H * W;

#pragma unroll UNR
    for (int ci = 0; ci < Cin; ++ci) {
        const float* xc  = xn + (size_t)ci * (H * W);
        const float* xrA = xc + (size_t)iyAc * W;
        const float* xrB = xc + (size_t)iyBc * W;
        float a0 = (vA && c0) ? xrA[j0]     : 0.0f;
        float a1 =  vA        ? xrA[t0]     : 0.0f;
        float a2 =  vA        ? xrA[t0 + 1] : 0.0f;
        float a3 = (vA && c3) ? xrA[j3]     : 0.0f;
        float b0 = (vB && c0) ? xrB[j0]     : 0.0f;
        float b1 =  vB        ? xrB[t0]     : 0.0f;
        float b2 =  vB        ? xrB[t0 + 1] : 0.0f;
        float b3 = (vB && c3) ? xrB[j3]     : 0.0f;

        const float* wci = w + ((size_t)ci * Cout + co0) * 16;
#pragma unroll
        for (int o = 0; o < COT; ++o) {
            const float* wr = wci + (size_t)o * 16;
            float wA0 = wr[p * 4 + 0], wA1 = wr[p * 4 + 1];
            float wA2 = wr[p * 4 + 2], wA3 = wr[p * 4 + 3];
            float wB0 = wr[(p + 2) * 4 + 0], wB1 = wr[(p + 2) * 4 + 1];
            float wB2 = wr[(p + 2) * 4 + 2], wB3 = wr[(p + 2) * 4 + 3];
            acc[o][0] = fmaf(a1, wA1, acc[o][0]); acc[o][0] = fmaf(a0, wA3, acc[o][0]);
            acc[o][0] = fmaf(b1, wB1, acc[o][0]); acc[o][0] = fmaf(b0, wB3, acc[o][0]);
            acc[o][1] = fmaf(a2, wA0, acc[o][1]); acc[o][1] = fmaf(a1, wA2, acc[o][1]);
            acc[o][1] = fmaf(b2, wB0, acc[o][1]); acc[o][1] = fmaf(b1, wB2, acc[o][1]);
            acc[o][2] = fmaf(a2, wA1, acc[o][2]); acc[o][2] = fmaf(a1, wA3, acc[o][2]);
            acc[o][2] = fmaf(b2, wB1, acc[o][2]); acc[o][2] = fmaf(b1, wB3, acc[o][2]);
            acc[o][3] = fmaf(a3, wA0, acc[o][3]); acc[o][3] = fmaf(a2, wA2, acc[o][3]);
            acc[o][3] = fmaf(b3, wB0, acc[o][3]); acc[o][3] = fmaf(b2, wB2, acc[o][3]);
        }
    }

    int ox0 = ox4 * 4;
#pragma unroll
    for (int o = 0; o < COT; ++o) {
        float* yr = y + (((size_t)n * Cout + co0 + o) * OH + oy) * OW + ox0;
#pragma unroll
        for (int j = 0; j < 4; ++j) {
            float v = acc[o][j];
            yr[j] = (ACT == 0) ? fmaxf(v, 0.0f) : tanhf(v);
        }
    }
}

// =============================== quantizer =================================
__global__ void __launch_bounds__(256) embed_norms(
    const float* __restrict__ embed, float* __restrict__ norms)
{
    int c = blockIdx.x * 256 + threadIdx.x;
    const float* e = embed + (size_t)c * 512;
    float s = 0.0f;
    for (int k = 0; k < 512; ++k) s = fmaf(e[k], e[k], s);
    norms[c] = s;
}

// Register-tiled GEMM argmin (proven R10)
__global__ void __launch_bounds__(256) vq_argmin16(
    const float* __restrict__ z, const float* __restrict__ et,
    const float* __restrict__ norms, int* __restrict__ out)
{
    constexpr int ZS = 516;
    int row0 = blockIdx.x * 16;
    int n    = row0 >> 8;
    int yx0  = row0 & 255;
    int tid  = threadIdx.x;

    __shared__ float zr[16 * ZS];

    const float* zn = z + ((size_t)n * 512) * 256;
#pragma unroll
    for (int it = 0; it < 8; ++it) {
        int i  = tid + 256 * it;
        int rq = i & 3, kc = i >> 2;
        float4 v = *(const float4*)&zn[(size_t)kc * 256 + yx0 + 4 * rq];
        zr[(4 * rq + 0) * ZS + kc] = v.x;
        zr[(4 * rq + 1) * ZS + kc] = v.y;
        zr[(4 * rq + 2) * ZS + kc] = v.z;
        zr[(4 * rq + 3) * ZS + kc] = v.w;
    }
    __syncthreads();

    float acc[16][4];
#pragma unroll
    for (int r = 0; r < 16; ++r)
#pragma unroll
        for (int j = 0; j < 4; ++j) acc[r][j] = 0.0f;

    const float* ebase = et + 4 * tid;
#pragma unroll 1
    for (int k4 = 0; k4 < 128; ++k4) {
        float4 e0 = *(const float4*)&ebase[(size_t)(4 * k4 + 0) * 1024];
        float4 e1 = *(const float4*)&ebase[(size_t)(4 * k4 + 1) * 1024];
        float4 e2 = *(const float4*)&ebase[(size_t)(4 * k4 + 2) * 1024];
        float4 e3 = *(const float4*)&ebase[(size_t)(4 * k4 + 3) * 1024];
#pragma unroll
        for (int r = 0; r < 16; ++r) {
            float4 zz = *(const float4*)&zr[r * ZS + 4 * k4];
            float a0 = acc[r][0], a1 = acc[r][1], a2 = acc[r][2], a3 = acc[r][3];
            a0 = fmaf(zz.x, e0.x, a0); a0 = fmaf(zz.y, e1.x, a0);
            a0 = fmaf(zz.z, e2.x, a0); a0 = fmaf(zz.w, e3.x, a0);
            a1 = fmaf(zz.x, e0.y, a1); a1 = fmaf(zz.y, e1.y, a1);
            a1 = fmaf(zz.z, e2.y, a1); a1 = fmaf(zz.w, e3.y, a1);
            a2 = fmaf(zz.x, e0.z, a2); a2 = fmaf(zz.y, e1.z, a2);
            a2 = fmaf(zz.z, e2.z, a2); a2 = fmaf(zz.w, e3.z, a2);
            a3 = fmaf(zz.x, e0.w, a3); a3 = fmaf(zz.y, e1.w, a3);
            a3 = fmaf(zz.z, e2.w, a3); a3 = fmaf(zz.w, e3.w, a3);
            acc[r][0] = a0; acc[r][1] = a1; acc[r][2] = a2; acc[r][3] = a3;
        }
    }

    float4 nb = *(const float4*)&norms[4 * tid];
    float best[16]; int bi[16];
#pragma unroll
    for (int r = 0; r < 16; ++r) {
        float d0 = nb.x - 2.0f * acc[r][0];
        float d1 = nb.y - 2.0f * acc[r][1];
        float d2 = nb.z - 2.0f * acc[r][2];
        float d3 = nb.w - 2.0f * acc[r][3];
        float b = d0; int ix = 4 * tid;
        if (d1 < b) { b = d1; ix = 4 * tid + 1; }
        if (d2 < b) { b = d2; ix = 4 * tid + 2; }
        if (d3 < b) { b = d3; ix = 4 * tid + 3; }
        best[r] = b; bi[r] = ix;
    }

    __syncthreads();
    float* rbd = zr;
    int*   rbi = (int*)(zr + 4096);
#pragma unroll
    for (int r = 0; r < 16; ++r) {
        rbd[r * 256 + tid] = best[r];
        rbi[r * 256 + tid] = bi[r];
    }
    __syncthreads();
    for (int s = 128; s > 0; s >>= 1) {
        if (tid < s) {
#pragma unroll
            for (int r = 0; r < 16; ++r) {
                int i0 = r * 256 + tid;
                float od = rbd[i0 + s]; int oi = rbi[i0 + s];
                float md = rbd[i0];     int mi = rbi[i0];
                if (od < md || (od == md && oi < mi)) { rbd[i0] = od; rbi[i0] = oi; }
            }
        }
        __syncthreads();
    }
    if (tid < 16) out[row0 + tid] = rbi[tid * 256];
}

__global__ void __launch_bounds__(256) vq_gather_pack(
    const int* __restrict__ vidx, const float* __restrict__ embed,
    unsigned* __restrict__ zq)
{
    int i = blockIdx.x * 256 + threadIdx.x;
    int yx = i & 255;
    int t  = i >> 8;
    int c  = t & 511;
    int n  = t >> 9;
    int row = (n << 8) + yx;
    zq[i] = pack_split(embed[(size_t)vidx[row] * 512 + c]);
}

// ================================ launch ===================================
extern "C" void kernel_launch(void* const* d_in, const int* in_sizes, int n_in,
                              void* d_out, int out_size, void* d_ws, size_t ws_size,
                              hipStream_t stream)
{
    (void)in_sizes; (void)n_in; (void)out_size; (void)ws_size;
    const float* x     = (const float*)d_in[0];
    const float* ew1   = (const float*)d_in[1];
    const float* eb1   = (const float*)d_in[2];
    const float* ew2   = (const float*)d_in[3];
    const float* eb2   = (const float*)d_in[4];
    const float* ew3   = (const float*)d_in[5];
    const float* eb3   = (const float*)d_in[6];
    const float* ew4   = (const float*)d_in[7];
    const float* eb4   = (const float*)d_in[8];
    const float* dw1   = (const float*)d_in[9];
    const float* db1   = (const float*)d_in[10];
    const float* dw2   = (const float*)d_in[11];
    const float* db2   = (const float*)d_in[12];
    const float* dw3   = (const float*)d_in[13];
    const float* db3   = (const float*)d_in[14];
    const float* dw4   = (const float*)d_in[15];
    const float* db4   = (const float*)d_in[16];
    const float* embed = (const float*)d_in[17];
    float* out = (float*)d_out;

    // ---- workspace layout (u32 units). Peak identical to R10 usage.
    unsigned* W0   = (unsigned*)d_ws;
    unsigned* h1p  = W0;                          // conv1 out (dead after conv2)
    unsigned* h2p  = W0 + 33554432;               // conv2 out
    unsigned* xp1  = W0 + 33554432;               // packed x (dead before conv2)
    unsigned* h3p  = W0;                          // overlays dead h1p
    float*    z    = (float*)(W0 + 8388608);      // conv4 out fp32
    unsigned* zq   = W0 + 12582912;               // quantized, packed u32
    float*    P0   = (float*)(W0 + 16777216);     // convt1 out (packed u32)
    float*    P1   = (float*)(W0 + 20971520);     // convt2 out (packed u32)
    int*      vidx = (int*)(W0 + 29360128);
    float*    norms= (float*)(W0 + 29368320);
    float*    g3o  = (float*)h2p;                 // convt3 out fp32 (h2p dead)

    // packed weights + transposed codebook live in d_out until g4 overwrites
    unsigned* wp2 = (unsigned*)d_out;             // 131,072
    unsigned* wp3 = wp2 + 131072;                 // 524,288
    unsigned* wp4 = wp2 + 655360;                 // 2,097,152
    unsigned* wq1 = wp2 + 2752512;                // 1,048,576 (4x128x2048)
    unsigned* wq2 = wq1 + 1048576;                // 131,072   (4x64x512)
    unsigned* wq3 = wq2 + 131072;                 // 32,768    (4x32x256)
    float*    et  = (float*)(wq3 + 32768);        // 524,288 (512x1024)
    unsigned* wp1 = (unsigned*)(et + 524288);     // 4,096 (64x64 padded)

    dim3 b256(256);

    // ---- pre-pass: pack weights/input, repack decoder weights, et ----
    pack_tensor<<<dim3(512),  b256, 0, stream>>>(ew2, wp2, 131072);
    pack_tensor<<<dim3(2048), b256, 0, stream>>>(ew3, wp3, 524288);
    pack_tensor<<<dim3(8192), b256, 0, stream>>>(ew4, wp4, 2097152);
    pack_w1<<<dim3(16), b256, 0, stream>>>(ew1, wp1);
    pack_tensor<<<dim3(24576), b256, 0, stream>>>(x, xp1, 6291456);
    repack_wt<512, 128><<<dim3(4096), b256, 0, stream>>>(dw1, wq1);
    repack_wt<128,  64><<<dim3(512),  b256, 0, stream>>>(dw2, wq2);
    repack_wt< 64,  32><<<dim3(128),  b256, 0, stream>>>(dw3, wq3);
    embed_transpose<<<dim3(2048), b256, 0, stream>>>(embed, et);

    // ---- encoder ----
    conv4s2_mfma_g<4, 3, 256, 256, 64, 4, 1, 1><<<dim3(8192), b256, 0, stream>>>(
        xp1, wp1, eb1, (float*)h1p);                       // h1 (packed)
    conv4s2_mfma<64, 128, 128, 128, 1><<<dim3(2048), b256, 0, stream>>>(
        h1p, wp2, eb2, (float*)h2p);                       // h2 (packed)
    conv4s2_mfma<128, 64, 64, 256, 1><<<dim3(1024), b256, 0, stream>>>(
        h2p, wp3, eb3, (float*)h3p);                       // h3 (packed)
    conv4s2_mfma<256, 32, 32, 512, 0><<<dim3(512), b256, 0, stream>>>(
        h3p, wp4, eb4, z);                                 // z (fp32)

    // ---- quantizer ----
    embed_norms<<<dim3(4), b256, 0, stream>>>(embed, norms);
    vq_argmin16<<<dim3(512), b256, 0, stream>>>(z, et, norms, vidx);
    vq_gather_pack<<<dim3(16384), b256, 0, stream>>>(vidx, embed, zq);

    // ---- decoder (MFMA parity-GEMM convT) ----
    convt4s2_mfma<512, 16, 16, 128, 4, 2, 1><<<dim3(4 * 128), b256, 0, stream>>>(
        zq, wq1, db1, P0);                                 // P0 (packed)
    convt4s2_mfma<128, 32, 32, 64, 4, 1, 1><<<dim3(4 * 512), b256, 0, stream>>>(
        (const unsigned*)P0, wq2, db2, P1);                // P1 (packed)
    convt4s2_mfma<64, 64, 64, 32, 2, 1, 0><<<dim3(4 * 2048), b256, 0, stream>>>(
        (const unsigned*)P1, wq3, db3, g3o);               // g3o (fp32)
    convt4s2_k<32, 128, 128, 3, 3, 1, 2><<<dim3(2048), b256, 0, stream>>>(
        g3o, dw4, db4, out);                               // tanh -> d_out
}

// Round 5
// 1152.040 us; speedup vs baseline: 1.6519x; 1.0128x over previous
//
#include <hip/hip_runtime.h>
#include <math.h>

// ---------------------------------------------------------------------------
// VQ-VAE forward. Round 12: vq_argmin restructured for occupancy.
// R11 analysis: 512-block grid = 2 blocks/CU hard occupancy cap (20%), and
// 64 acc/thread overflowed the arch-VGPR budget (VGPR_Count=52 -> AGPR
// shuffling). Now: 8 rows/block (1024 blocks, 4/CU), 32 acc/thread,
// launch_bounds(256,4), explicit e-prefetch double buffer. Distances remain
// bit-identical fp32. Everything else identical to proven R11 kernel.
// ---------------------------------------------------------------------------

typedef __attribute__((ext_vector_type(8))) short bf16x8;
typedef __attribute__((ext_vector_type(4))) float f32x4;
union FragU { unsigned u[4]; bf16x8 v; };

__device__ __forceinline__ unsigned bf16_rne(unsigned u) {
    return (u + 0x7FFFu + ((u >> 16) & 1u)) >> 16;
}
// pack fp32 -> u32: low16 = bf16(v), high16 = bf16(v - bf16(v))
__device__ __forceinline__ unsigned pack_split(float v) {
    unsigned u = __builtin_bit_cast(unsigned, v);
    unsigned hi = bf16_rne(u);
    float hif = __builtin_bit_cast(float, hi << 16);
    float r = v - hif;
    unsigned lo = bf16_rne(__builtin_bit_cast(unsigned, r));
    return hi | (lo << 16);
}

__global__ void __launch_bounds__(256) pack_tensor(
    const float* __restrict__ s, unsigned* __restrict__ d, int n)
{
    int i = blockIdx.x * 256 + threadIdx.x;
    if (i < n) d[i] = pack_split(s[i]);
}

// conv1 weights (64,3,4,4) -> padded packed [64][64] (k>=48 zero)
__global__ void __launch_bounds__(256) pack_w1(
    const float* __restrict__ w, unsigned* __restrict__ wq)
{
    int idx = blockIdx.x * 256 + threadIdx.x;
    if (idx >= 64 * 64) return;
    int k = idx & 63, oc = idx >> 6;
    float v = (k < 48) ? w[oc * 48 + k] : 0.0f;
    wq[idx] = pack_split(v);
}

// repack ConvTranspose weights (torch layout Cin,Cout,4,4) into
// wq[par][co][ci*4 + t], t = 2r+s, packed hi/lo. par = dy*2+dx.
template<int Cin, int Cout>
__global__ void __launch_bounds__(256) repack_wt(
    const float* __restrict__ w, unsigned* __restrict__ wq)
{
    constexpr int TOT = 16 * Cin * Cout;
    int idx = blockIdx.x * 256 + threadIdx.x;
    if (idx >= TOT) return;
    int t  = idx & 3;
    int ci = (idx >> 2) % Cin;
    int rest = (idx >> 2) / Cin;
    int co  = rest % Cout;
    int par = rest / Cout;
    int dy = par >> 1, dx = par & 1;
    int r = t >> 1, s = t & 1;
    int ky = 3 - dy - 2 * r;
    int kx = 3 - dx - 2 * s;
    float v = w[(((size_t)ci * Cout + co) * 4 + ky) * 4 + kx];
    wq[idx] = pack_split(v);
}

// transpose codebook: embed[1024][512] -> et[512][1024]
__global__ void __launch_bounds__(256) embed_transpose(
    const float* __restrict__ embed, float* __restrict__ et)
{
    int idx = blockIdx.x * 256 + threadIdx.x;   // 2048 blocks x 256
    int c = idx & 1023, k = idx >> 10;
    et[idx] = embed[(size_t)c * 512 + k];
}

// ================= MFMA conv k=4 s=2 p=1 + ReLU (implicit GEMM) ============
// (conv2..4; unchanged)
template<int Cin, int H, int W, int Cout, int PACKO>
__global__ void __launch_bounds__(256) conv4s2_mfma(
    const unsigned* __restrict__ xp, const unsigned* __restrict__ wp,
    const float* __restrict__ bias, float* __restrict__ y)
{
    constexpr int OH = H / 2, OW = W / 2;
    constexpr int LOG_OW = (OW == 64) ? 6 : (OW == 32) ? 5 : 4;
    constexpr int R   = 64 / OW;
    constexpr int RT  = 2 * R + 2;
    constexpr int CS  = W + 2;
    constexpr int XEL = 2 * RT * CS;
    constexpr int XIT = (XEL + 255) / 256;
    constexpr int K   = Cin * 16;
    constexpr int NC  = Cin / 2;
    constexpr int NB  = 128;
    constexpr int MBC = 32 * OH * OW / 64;

    __shared__ unsigned smem[8704];
    unsigned* raw = smem;
    unsigned* wb  = smem + ((XEL + 7) & ~7);

    int bid = blockIdx.x;
    int mb = bid % MBC, ng = bid / MBC;
    int oc0 = ng * NB;
    int m0 = mb * 64;
    int nimg = m0 / (OH * OW);
    int sp0 = m0 % (OH * OW);
    int oyb = sp0 >> LOG_OW;

    int tid  = threadIdx.x;
    int lane = tid & 63, wv = tid >> 6;
    int lm = lane & 15, q = lane >> 4;
    int n0w = wv * 32;

    const unsigned* xbase = xp + (size_t)nimg * Cin * H * W;

    int  goff[XIT];
    bool gok[XIT];
#pragma unroll
    for (int s = 0; s < XIT; ++s) {
        int i = tid + 256 * s;
        goff[s] = 0; gok[s] = false;
        if (i < XEL) {
            int lc = i % CS;
            int t2 = i / CS;
            int lr = t2 % RT;
            int c  = t2 / RT;
            int gr = 2 * oyb - 1 + lr;
            int gc = lc - 1;
            bool ok = ((unsigned)gr < (unsigned)H) && ((unsigned)gc < (unsigned)W);
            goff[s] = ok ? (c * H * W + gr * W + gc) : 0;
            gok[s]  = ok;
        }
    }
    const unsigned* wbase = wp + (size_t)(oc0 + (tid >> 5)) * K + (tid & 31);
    int wlds0 = (tid >> 5) * 36 + (tid & 31);

    f32x4 acc[4][2];
#pragma unroll
    for (int nt = 0; nt < 2; ++nt) {
        float b = bias[oc0 + n0w + nt * 16 + lm];
#pragma unroll
        for (int mt = 0; mt < 4; ++mt)
#pragma unroll
            for (int r = 0; r < 4; ++r) acc[mt][nt][r] = b;
    }

    unsigned pfa[XIT];
    unsigned pfb[16];

    auto load_chunk = [&](int ch) {
        const unsigned* cb = xbase + (size_t)(ch * 2) * (H * W);
#pragma unroll
        for (int s = 0; s < XIT; ++s) {
            unsigned v = 0;
            if (gok[s]) v = cb[goff[s]];
            pfa[s] = v;
        }
        const unsigned* wc = wbase + ch * 32;
#pragma unroll
        for (int s = 0; s < 16; ++s) pfb[s] = wc[(size_t)s * 8 * K];
    };
    auto store_chunk = [&]() {
#pragma unroll
        for (int s = 0; s < XIT; ++s) {
            int i = tid + 256 * s;
            if (i < XEL) raw[i] = pfa[s];
        }
#pragma unroll
        for (int s = 0; s < 16; ++s) wb[wlds0 + s * 288] = pfb[s];
    };

    load_chunk(0);
#pragma unroll 1
    for (int ch = 0; ch < NC; ++ch) {
        __syncthreads();
        store_chunk();
        __syncthreads();
        if (ch + 1 < NC) load_chunk(ch + 1);

        FragU bhi[2], blo[2];
#pragma unroll
        for (int nt = 0; nt < 2; ++nt) {
            const unsigned* bp = &wb[(n0w + nt * 16 + lm) * 36 + q * 8];
            uint4 p0 = *(const uint4*)bp;
            uint4 p1 = *(const uint4*)(bp + 4);
            unsigned e0 = p0.x, e1 = p0.y, e2 = p0.z, e3 = p0.w;
            unsigned e4 = p1.x, e5 = p1.y, e6 = p1.z, e7 = p1.w;
            bhi[nt].u[0] = (e0 & 0xffffu) | (e1 << 16);
            bhi[nt].u[1] = (e2 & 0xffffu) | (e3 << 16);
            bhi[nt].u[2] = (e4 & 0xffffu) | (e5 << 16);
            bhi[nt].u[3] = (e6 & 0xffffu) | (e7 << 16);
            blo[nt].u[0] = (e0 >> 16) | (e1 & 0xffff0000u);
            blo[nt].u[1] = (e2 >> 16) | (e3 & 0xffff0000u);
            blo[nt].u[2] = (e4 >> 16) | (e5 & 0xffff0000u);
            blo[nt].u[3] = (e6 >> 16) | (e7 & 0xffff0000u);
        }
#pragma unroll
        for (int mt = 0; mt < 4; ++mt) {
            int m = mt * 16 + lm;
            int oyl = m >> LOG_OW, oxl = m & (OW - 1);
            int c = q >> 1, rb = 2 * oyl + (q & 1) * 2;
            const unsigned* rp = &raw[(c * RT + rb) * CS + 2 * oxl];
            uint2 a0 = *(const uint2*)rp;
            uint2 a1 = *(const uint2*)(rp + 2);
            uint2 a2 = *(const uint2*)(rp + CS);
            uint2 a3 = *(const uint2*)(rp + CS + 2);
            FragU ahi, alo;
            ahi.u[0] = (a0.x & 0xffffu) | (a0.y << 16);
            ahi.u[1] = (a1.x & 0xffffu) | (a1.y << 16);
            ahi.u[2] = (a2.x & 0xffffu) | (a2.y << 16);
            ahi.u[3] = (a3.x & 0xffffu) | (a3.y << 16);
            alo.u[0] = (a0.x >> 16) | (a0.y & 0xffff0000u);
            alo.u[1] = (a1.x >> 16) | (a1.y & 0xffff0000u);
            alo.u[2] = (a2.x >> 16) | (a2.y & 0xffff0000u);
            alo.u[3] = (a3.x >> 16) | (a3.y & 0xffff0000u);
#pragma unroll
            for (int nt = 0; nt < 2; ++nt) {
                acc[mt][nt] = __builtin_amdgcn_mfma_f32_16x16x32_bf16(
                    ahi.v, bhi[nt].v, acc[mt][nt], 0, 0, 0);
                acc[mt][nt] = __builtin_amdgcn_mfma_f32_16x16x32_bf16(
                    ahi.v, blo[nt].v, acc[mt][nt], 0, 0, 0);
                acc[mt][nt] = __builtin_amdgcn_mfma_f32_16x16x32_bf16(
                    alo.v, bhi[nt].v, acc[mt][nt], 0, 0, 0);
            }
        }
    }

    __syncthreads();
    float* cs = (float*)smem;
#pragma unroll
    for (int mt = 0; mt < 4; ++mt)
#pragma unroll
        for (int nt = 0; nt < 2; ++nt) {
            int nl = n0w + nt * 16 + lm;
#pragma unroll
            for (int r = 0; r < 4; ++r)
                cs[nl * 68 + mt * 16 + q * 4 + r] = acc[mt][nt][r];
        }
    __syncthreads();
    {
        int nl = tid >> 1, half = tid & 1;
        size_t gb = ((size_t)(nimg * Cout + oc0 + nl)) * (OH * OW) + sp0 + half * 32;
#pragma unroll
        for (int i2 = 0; i2 < 8; ++i2) {
            float4 v = *(float4*)&cs[nl * 68 + half * 32 + 4 * i2];
            v.x = fmaxf(v.x, 0.0f); v.y = fmaxf(v.y, 0.0f);
            v.z = fmaxf(v.z, 0.0f); v.w = fmaxf(v.w, 0.0f);
            if (PACKO) {
                uint4 p;
                p.x = pack_split(v.x); p.y = pack_split(v.y);
                p.z = pack_split(v.z); p.w = pack_split(v.w);
                *(uint4*)((unsigned*)y + gb + 4 * i2) = p;
            } else {
                *(float4*)(y + gb + 4 * i2) = v;
            }
        }
    }
}

// ========== generalized MFMA conv (sub-row tiles + zero-padded K) ==========
template<int Cin, int CINR, int H, int W, int Cout, int MT, int NT, int PACKO>
__global__ void __launch_bounds__(256) conv4s2_mfma_g(
    const unsigned* __restrict__ xp, const unsigned* __restrict__ wp,
    const float* __restrict__ bias, float* __restrict__ y)
{
    constexpr int OH = H / 2, OW = W / 2;
    constexpr int OWB = (OW >= 64) ? 64 : OW;
    constexpr int LOG_OWB = (OWB == 64) ? 6 : (OWB == 32) ? 5 : 4;
    constexpr int LOG_OW  = (OW == 128) ? 7 : (OW == 64) ? 6 : (OW == 32) ? 5 : 4;
    constexpr int R   = 64 / OWB;
    constexpr int RT  = 2 * R + 2;
    constexpr int CS  = 2 * OWB + 2;
    constexpr int XEL = 2 * RT * CS;
    constexpr int XIT = (XEL + 255) / 256;
    constexpr int K   = Cin * 16;
    constexpr int NC  = Cin / 2;
    constexpr int NB  = Cout;
    constexpr int WIT = NB / 8;
    constexpr int WN  = Cout / (16 * NT);
    constexpr int WM  = 4 / WN;
    static_assert(WM * MT * 16 == 64, "M tiling");
    static_assert(WN * NT * 16 == Cout, "N tiling");
    constexpr int MBC = 32 * OH * OW / 64;
    constexpr int XPAD = (XEL + 7) & ~7;
    constexpr int SM1 = XPAD + NB * 36;
    constexpr int SM2 = NB * 68;
    constexpr int SMEM = SM1 > SM2 ? SM1 : SM2;

    __shared__ unsigned smem[SMEM];
    unsigned* raw = smem;
    unsigned* wb  = smem + XPAD;

    int bid = blockIdx.x;
    int mb = bid % MBC, ng = bid / MBC;
    int oc0 = ng * NB;
    int m0 = mb * 64;
    int nimg = m0 / (OH * OW);
    int sp0 = m0 % (OH * OW);
    int oyb = sp0 >> LOG_OW;
    int oxb = sp0 & (OW - 1);

    int tid  = threadIdx.x;
    int lane = tid & 63, wv = tid >> 6;
    int lm = lane & 15, q = lane >> 4;
    int wm = wv / WN, wn = wv % WN;

    const unsigned* xbase = xp + (size_t)nimg * CINR * H * W;

    int  goff[XIT];
    bool gok[XIT];
    int  cidx[XIT];
#pragma unroll
    for (int s = 0; s < XIT; ++s) {
        int i = tid + 256 * s;
        goff[s] = 0; gok[s] = false; cidx[s] = 0;
        if (i < XEL) {
            int lc = i % CS;
            int t2 = i / CS;
            int lr = t2 % RT;
            int c  = t2 / RT;
            int gr = 2 * oyb - 1 + lr;
            int gc = 2 * oxb - 1 + lc;
            bool ok = ((unsigned)gr < (unsigned)H) && ((unsigned)gc < (unsigned)W);
            goff[s] = ok ? (c * H * W + gr * W + gc) : 0;
            gok[s]  = ok;
            cidx[s] = c;
        }
    }
    const unsigned* wbase = wp + (size_t)(oc0 + (tid >> 5)) * K + (tid & 31);
    int wlds0 = (tid >> 5) * 36 + (tid & 31);

    f32x4 acc[MT][NT];
#pragma unroll
    for (int nt = 0; nt < NT; ++nt) {
        float b = bias[oc0 + wn * NT * 16 + nt * 16 + lm];
#pragma unroll
        for (int mt = 0; mt < MT; ++mt)
#pragma unroll
            for (int r = 0; r < 4; ++r) acc[mt][nt][r] = b;
    }

    unsigned pfa[XIT];
    unsigned pfb[WIT];

    auto load_chunk = [&](int ch) {
        const unsigned* cb = xbase + (size_t)(ch * 2) * (H * W);
#pragma unroll
        for (int s = 0; s < XIT; ++s) {
            unsigned v = 0;
            bool okc = (2 * ch + cidx[s]) < CINR;
            if (gok[s] && okc) v = cb[goff[s]];
            pfa[s] = v;
        }
        const unsigned* wc = wbase + ch * 32;
#pragma unroll
        for (int s = 0; s < WIT; ++s) pfb[s] = wc[(size_t)s * 8 * K];
    };
    auto store_chunk = [&]() {
#pragma unroll
        for (int s = 0; s < XIT; ++s) {
            int i = tid + 256 * s;
            if (i < XEL) raw[i] = pfa[s];
        }
#pragma unroll
        for (int s = 0; s < WIT; ++s) wb[wlds0 + s * 288] = pfb[s];
    };

    load_chunk(0);
#pragma unroll 1
    for (int ch = 0; ch < NC; ++ch) {
        __syncthreads();
        store_chunk();
        __syncthreads();
        if (ch + 1 < NC) load_chunk(ch + 1);

        FragU bhi[NT], blo[NT];
#pragma unroll
        for (int nt = 0; nt < NT; ++nt) {
            const unsigned* bp = &wb[(wn * NT * 16 + nt * 16 + lm) * 36 + q * 8];
            uint4 p0 = *(const uint4*)bp;
            uint4 p1 = *(const uint4*)(bp + 4);
            unsigned e0 = p0.x, e1 = p0.y, e2 = p0.z, e3 = p0.w;
            unsigned e4 = p1.x, e5 = p1.y, e6 = p1.z, e7 = p1.w;
            bhi[nt].u[0] = (e0 & 0xffffu) | (e1 << 16);
            bhi[nt].u[1] = (e2 & 0xffffu) | (e3 << 16);
            bhi[nt].u[2] = (e4 & 0xffffu) | (e5 << 16);
            bhi[nt].u[3] = (e6 & 0xffffu) | (e7 << 16);
            blo[nt].u[0] = (e0 >> 16) | (e1 & 0xffff0000u);
            blo[nt].u[1] = (e2 >> 16) | (e3 & 0xffff0000u);
            blo[nt].u[2] = (e4 >> 16) | (e5 & 0xffff0000u);
            blo[nt].u[3] = (e6 >> 16) | (e7 & 0xffff0000u);
        }
#pragma unroll
        for (int mt = 0; mt < MT; ++mt) {
            int m = wm * (MT * 16) + mt * 16 + lm;
            int oyl = m >> LOG_OWB, oxl = m & (OWB - 1);
            int c = q >> 1, rb = 2 * oyl + (q & 1) * 2;
            const unsigned* rp = &raw[(c * RT + rb) * CS + 2 * oxl];
            uint2 a0 = *(const uint2*)rp;
            uint2 a1 = *(const uint2*)(rp + 2);
            uint2 a2 = *(const uint2*)(rp + CS);
            uint2 a3 = *(const uint2*)(rp + CS + 2);
            FragU ahi, alo;
            ahi.u[0] = (a0.x & 0xffffu) | (a0.y << 16);
            ahi.u[1] = (a1.x & 0xffffu) | (a1.y << 16);
            ahi.u[2] = (a2.x & 0xffffu) | (a2.y << 16);
            ahi.u[3] = (a3.x & 0xffffu) | (a3.y << 16);
            alo.u[0] = (a0.x >> 16) | (a0.y & 0xffff0000u);
            alo.u[1] = (a1.x >> 16) | (a1.y & 0xffff0000u);
            alo.u[2] = (a2.x >> 16) | (a2.y & 0xffff0000u);
            alo.u[3] = (a3.x >> 16) | (a3.y & 0xffff0000u);
#pragma unroll
            for (int nt = 0; nt < NT; ++nt) {
                acc[mt][nt] = __builtin_amdgcn_mfma_f32_16x16x32_bf16(
                    ahi.v, bhi[nt].v, acc[mt][nt], 0, 0, 0);
                acc[mt][nt] = __builtin_amdgcn_mfma_f32_16x16x32_bf16(
                    ahi.v, blo[nt].v, acc[mt][nt], 0, 0, 0);
                acc[mt][nt] = __builtin_amdgcn_mfma_f32_16x16x32_bf16(
                    alo.v, bhi[nt].v, acc[mt][nt], 0, 0, 0);
            }
        }
    }

    __syncthreads();
    float* cs = (float*)smem;
#pragma unroll
    for (int mt = 0; mt < MT; ++mt)
#pragma unroll
        for (int nt = 0; nt < NT; ++nt) {
            int nl  = wn * NT * 16 + nt * 16 + lm;
            int mb2 = wm * (MT * 16) + mt * 16 + q * 4;
#pragma unroll
            for (int r = 0; r < 4; ++r)
                cs[nl * 68 + mb2 + r] = acc[mt][nt][r];
        }
    __syncthreads();
    {
        constexpr int QT = 256 / NB;
        int nl = tid / QT, qt = tid % QT;
        constexpr int MQ = 64 / QT;
        size_t gb = ((size_t)(nimg * Cout + oc0 + nl)) * (OH * OW) + sp0 + qt * MQ;
#pragma unroll
        for (int i2 = 0; i2 < MQ / 4; ++i2) {
            float4 v = *(float4*)&cs[nl * 68 + qt * MQ + 4 * i2];
            v.x = fmaxf(v.x, 0.0f); v.y = fmaxf(v.y, 0.0f);
            v.z = fmaxf(v.z, 0.0f); v.w = fmaxf(v.w, 0.0f);
            if (PACKO) {
                uint4 p;
                p.x = pack_split(v.x); p.y = pack_split(v.y);
                p.z = pack_split(v.z); p.w = pack_split(v.w);
                *(uint4*)((unsigned*)y + gb + 4 * i2) = p;
            } else {
                *(float4*)(y + gb + 4 * i2) = v;
            }
        }
    }
}

// ============ MFMA ConvTranspose k=4 s=2 p=1 + ReLU (parity GEMM) ==========
template<int Cin, int Hh, int Wh, int Cout, int MT, int NT, int PACKO>
__global__ void __launch_bounds__(256) convt4s2_mfma(
    const unsigned* __restrict__ xp, const unsigned* __restrict__ wq,
    const float* __restrict__ bias, float* __restrict__ y)
{
    constexpr int W = Wh;
    constexpr int LOG_W = (W == 64) ? 6 : (W == 32) ? 5 : 4;
    constexpr int R   = 64 / W;
    constexpr int RT  = R + 1;
    constexpr int CS  = W + 2;
    constexpr int XEL = 8 * RT * CS;
    constexpr int XIT = (XEL + 255) / 256;
    constexpr int K   = Cin * 4;
    constexpr int NC  = Cin / 8;
    constexpr int NB  = Cout;
    constexpr int WIT = NB / 8;
    constexpr int WN  = Cout / (16 * NT);
    constexpr int WM  = 4 / WN;
    static_assert(WM * MT * 16 == 64, "M tiling");
    static_assert(WN * NT * 16 == Cout, "N tiling");
    constexpr int MBC = 32 * Hh * W / 64;
    constexpr int XPAD = (XEL + 7) & ~7;
    constexpr int SM1 = XPAD + NB * 36;
    constexpr int SM2 = NB * 68;
    constexpr int SMEM = SM1 > SM2 ? SM1 : SM2;

    __shared__ unsigned smem[SMEM];
    unsigned* raw = smem;
    unsigned* wb  = smem + XPAD;

    int bid = blockIdx.x;
    int mb  = bid % MBC;
    int par = bid / MBC;
    int dy = par >> 1, dx = par & 1;

    int m0   = mb * 64;
    int nimg = m0 / (Hh * W);
    int sp0  = m0 % (Hh * W);
    int il0  = sp0 >> LOG_W;

    int tid = threadIdx.x;
    int lane = tid & 63, wv = tid >> 6;
    int lm = lane & 15, q = lane >> 4;
    int wm = wv / WN, wn = wv % WN;

    const unsigned* xbase = xp + (size_t)nimg * Cin * Hh * W;

    int  goff[XIT];
    bool gok[XIT];
#pragma unroll
    for (int s = 0; s < XIT; ++s) {
        int i = tid + 256 * s;
        goff[s] = 0; gok[s] = false;
        if (i < XEL) {
            int lc = i % CS;
            int t2 = i / CS;
            int lr = t2 % RT;
            int c  = t2 / RT;
            int gr = il0 - 1 + dy + lr;
            int gc = lc - 1;
            bool ok = ((unsigned)gr < (unsigned)Hh) && ((unsigned)gc < (unsigned)W);
            goff[s] = ok ? (c * Hh * W + gr * W + gc) : 0;
            gok[s]  = ok;
        }
    }
    const unsigned* wbase = wq + (size_t)(par * Cout + (tid >> 5)) * K + (tid & 31);
    int wlds0 = (tid >> 5) * 36 + (tid & 31);

    f32x4 acc[MT][NT];
#pragma unroll
    for (int nt = 0; nt < NT; ++nt) {
        float b = bias[wn * NT * 16 + nt * 16 + lm];
#pragma unroll
        for (int mt = 0; mt < MT; ++mt)
#pragma unroll
            for (int r = 0; r < 4; ++r) acc[mt][nt][r] = b;
    }

    unsigned pfa[XIT];
    unsigned pfb[WIT];

    auto load_chunk = [&](int ch) {
        const unsigned* cb = xbase + (size_t)(ch * 8) * (Hh * W);
#pragma unroll
        for (int s = 0; s < XIT; ++s) {
            unsigned v = 0;
            if (gok[s]) v = cb[goff[s]];
            pfa[s] = v;
        }
        const unsigned* wc = wbase + ch * 32;
#pragma unroll
        for (int s = 0; s < WIT; ++s) pfb[s] = wc[(size_t)s * 8 * K];
    };
    auto store_chunk = [&]() {
#pragma unroll
        for (int s = 0; s < XIT; ++s) {
            int i = tid + 256 * s;
            if (i < XEL) raw[i] = pfa[s];
        }
#pragma unroll
        for (int s = 0; s < WIT; ++s) wb[wlds0 + s * 288] = pfb[s];
    };

    load_chunk(0);
#pragma unroll 1
    for (int ch = 0; ch < NC; ++ch) {
        __syncthreads();
        store_chunk();
        __syncthreads();
        if (ch + 1 < NC) load_chunk(ch + 1);

        FragU bhi[NT], blo[NT];
#pragma unroll
        for (int nt = 0; nt < NT; ++nt) {
            const unsigned* bp = &wb[(wn * NT * 16 + nt * 16 + lm) * 36 + q * 8];
            uint4 p0 = *(const uint4*)bp;
            uint4 p1 = *(const uint4*)(bp + 4);
            unsigned e0 = p0.x, e1 = p0.y, e2 = p0.z, e3 = p0.w;
            unsigned e4 = p1.x, e5 = p1.y, e6 = p1.z, e7 = p1.w;
            bhi[nt].u[0] = (e0 & 0xffffu) | (e1 << 16);
            bhi[nt].u[1] = (e2 & 0xffffu) | (e3 << 16);
            bhi[nt].u[2] = (e4 & 0xffffu) | (e5 << 16);
            bhi[nt].u[3] = (e6 & 0xffffu) | (e7 << 16);
            blo[nt].u[0] = (e0 >> 16) | (e1 & 0xffff0000u);
            blo[nt].u[1] = (e2 >> 16) | (e3 & 0xffff0000u);
            blo[nt].u[2] = (e4 >> 16) | (e5 & 0xffff0000u);
            blo[nt].u[3] = (e6 >> 16) | (e7 & 0xffff0000u);
        }
#pragma unroll
        for (int mt = 0; mt < MT; ++mt) {
            int ml = wm * (MT * 16) + mt * 16 + lm;
            int il = ml >> LOG_W, jl = ml & (W - 1);
            const unsigned* rp = &raw[((2 * q) * RT + il) * CS + jl + dx];
            unsigned a00 = rp[0],               a01 = rp[1];
            unsigned a10 = rp[CS],              a11 = rp[CS + 1];
            unsigned a20 = rp[RT * CS],         a21 = rp[RT * CS + 1];
            unsigned a30 = rp[RT * CS + CS],    a31 = rp[RT * CS + CS + 1];
            FragU ahi, alo;
            ahi.u[0] = (a00 & 0xffffu) | (a01 << 16);
            ahi.u[1] = (a10 & 0xffffu) | (a11 << 16);
            ahi.u[2] = (a20 & 0xffffu) | (a21 << 16);
            ahi.u[3] = (a30 & 0xffffu) | (a31 << 16);
            alo.u[0] = (a00 >> 16) | (a01 & 0xffff0000u);
            alo.u[1] = (a10 >> 16) | (a11 & 0xffff0000u);
            alo.u[2] = (a20 >> 16) | (a21 & 0xffff0000u);
            alo.u[3] = (a30 >> 16) | (a31 & 0xffff0000u);
#pragma unroll
            for (int nt = 0; nt < NT; ++nt) {
                acc[mt][nt] = __builtin_amdgcn_mfma_f32_16x16x32_bf16(
                    ahi.v, bhi[nt].v, acc[mt][nt], 0, 0, 0);
                acc[mt][nt] = __builtin_amdgcn_mfma_f32_16x16x32_bf16(
                    ahi.v, blo[nt].v, acc[mt][nt], 0, 0, 0);
                acc[mt][nt] = __builtin_amdgcn_mfma_f32_16x16x32_bf16(
                    alo.v, bhi[nt].v, acc[mt][nt], 0, 0, 0);
            }
        }
    }

    __syncthreads();
    float* cs = (float*)smem;
#pragma unroll
    for (int mt = 0; mt < MT; ++mt)
#pragma unroll
        for (int nt = 0; nt < NT; ++nt) {
            int nl  = wn * NT * 16 + nt * 16 + lm;
            int mb2 = wm * (MT * 16) + mt * 16 + q * 4;
#pragma unroll
            for (int r = 0; r < 4; ++r)
                cs[nl * 68 + mb2 + r] = acc[mt][nt][r];
        }
    __syncthreads();
    constexpr int EIT = NB * 64 / 256;
#pragma unroll
    for (int it = 0; it < EIT; ++it) {
        int idx = tid + 256 * it;
        int c = idx >> 6, m = idx & 63;
        int il = m >> LOG_W, jl = m & (W - 1);
        int oy = 2 * (il0 + il) + dy;
        int ox = 2 * jl + dx;
        float v = fmaxf(cs[c * 68 + m], 0.0f);
        size_t go = (((size_t)(nimg * Cout + c)) * (2 * Hh) + oy) * (2 * W) + ox;
        if (PACKO) ((unsigned*)y)[go] = pack_split(v);
        else       y[go] = v;
    }
}

// ================= direct convT (g4, tanh) =================================
template<int Cin, int H, int W, int Cout, int COT, int ACT, int UNR>
__global__ void __launch_bounds__(256) convt4s2_k(
    const float* __restrict__ x, const float* __restrict__ w,
    const float* __restrict__ bias, float* __restrict__ y)
{
    constexpr int OH = 2 * H, OW = 2 * W, OWq = OW / 4;
    int id = blockIdx.x * 256 + threadIdx.x;
    int ox4 = id % OWq; int t = id / OWq;
    int oy  = t % OH;   t /= OH;
    int cog = t % (Cout / COT);
    int n   = t / (Cout / COT);
    int co0 = __builtin_amdgcn_readfirstlane(cog * COT);
    n       = __builtin_amdgcn_readfirstlane(n);

    int p   = (oy + 1) & 1;
    int iyA = (oy + 1 - p) >> 1;
    int iyB = iyA - 1;
    bool vA = (iyA < H);
    bool vB = (iyB >= 0);
    int iyAc = vA ? iyA : 0, iyBc = vB ? iyB : 0;

    int t0 = 2 * ox4;
    bool c0 = (t0 - 1 >= 0);
    bool c3 = (t0 + 2 <= W - 1);
    int j0 = c0 ? t0 - 1 : 0;
    int j3 = c3 ? t0 + 2 : 0;

    float acc[COT][4];
#pragma unroll
    for (int o = 0; o < COT; ++o) {
        float b = bias[co0 + o];
#pragma unroll
        for (int j = 0; j < 4; ++j) acc[o][j] = b;
    }

    const float* xn = x + (size_t)n * Cin * H * W;

#pragma unroll UNR
    for (int ci = 0; ci < Cin; ++ci) {
        const float* xc  = xn + (size_t)ci * (H * W);
        const float* xrA = xc + (size_t)iyAc * W;
        const float* xrB = xc + (size_t)iyBc * W;
        float a0 = (vA && c0) ? xrA[j0]     : 0.0f;
        float a1 =  vA        ? xrA[t0]     : 0.0f;
        float a2 =  vA        ? xrA[t0 + 1] : 0.0f;
        float a3 = (vA && c3) ? xrA[j3]     : 0.0f;
        float b0 = (vB && c0) ? xrB[j0]     : 0.0f;
        float b1 =  vB        ? xrB[t0]     : 0.0f;
        float b2 =  vB        ? xrB[t0 + 1] : 0.0f;
        float b3 = (vB && c3) ? xrB[j3]     : 0.0f;

        const float* wci = w + ((size_t)ci * Cout + co0) * 16;
#pragma unroll
        for (int o = 0; o < COT; ++o) {
            const float* wr = wci + (size_t)o * 16;
            float wA0 = wr[p * 4 + 0], wA1 = wr[p * 4 + 1];
            float wA2 = wr[p * 4 + 2], wA3 = wr[p * 4 + 3];
            float wB0 = wr[(p + 2) * 4 + 0], wB1 = wr[(p + 2) * 4 + 1];
            float wB2 = wr[(p + 2) * 4 + 2], wB3 = wr[(p + 2) * 4 + 3];
            acc[o][0] = fmaf(a1, wA1, acc[o][0]); acc[o][0] = fmaf(a0, wA3, acc[o][0]);
            acc[o][0] = fmaf(b1, wB1, acc[o][0]); acc[o][0] = fmaf(b0, wB3, acc[o][0]);
            acc[o][1] = fmaf(a2, wA0, acc[o][1]); acc[o][1] = fmaf(a1, wA2, acc[o][1]);
            acc[o][1] = fmaf(b2, wB0, acc[o][1]); acc[o][1] = fmaf(b1, wB2, acc[o][1]);
            acc[o][2] = fmaf(a2, wA1, acc[o][2]); acc[o][2] = fmaf(a1, wA3, acc[o][2]);
            acc[o][2] = fmaf(b2, wB1, acc[o][2]); acc[o][2] = fmaf(b1, wB3, acc[o][2]);
            acc[o][3] = fmaf(a3, wA0, acc[o][3]); acc[o][3] = fmaf(a2, wA2, acc[o][3]);
            acc[o][3] = fmaf(b3, wB0, acc[o][3]); acc[o][3] = fmaf(b2, wB2, acc[o][3]);
        }
    }

    int ox0 = ox4 * 4;
#pragma unroll
    for (int o = 0; o < COT; ++o) {
        float* yr = y + (((size_t)n * Cout + co0 + o) * OH + oy) * OW + ox0;
#pragma unroll
        for (int j = 0; j < 4; ++j) {
            float v = acc[o][j];
            yr[j] = (ACT == 0) ? fmaxf(v, 0.0f) : tanhf(v);
        }
    }
}

// =============================== quantizer =================================
__global__ void __launch_bounds__(256) embed_norms(
    const float* __restrict__ embed, float* __restrict__ norms)
{
    int c = blockIdx.x * 256 + threadIdx.x;
    const float* e = embed + (size_t)c * 512;
    float s = 0.0f;
    for (int k = 0; k < 512; ++k) s = fmaf(e[k], e[k], s);
    norms[c] = s;
}

// Register-tiled GEMM argmin, occupancy-fixed: 8 rows x 1024 codes per block
// (1024 blocks = 4/CU), 32 acc/thread, e-prefetch double buffer.
// Distances accumulate over k ascending in fp32 -> identical to prior rounds.
__global__ void __launch_bounds__(256, 4) vq_argmin8r(
    const float* __restrict__ z, const float* __restrict__ et,
    const float* __restrict__ norms, int* __restrict__ out)
{
    constexpr int ZS = 516;                 // padded LDS row stride (floats)
    int row0 = blockIdx.x * 8;              // 1024 blocks
    int n    = row0 >> 8;
    int yx0  = row0 & 255;
    int tid  = threadIdx.x;

    __shared__ float zr[8 * ZS];            // 16,512 B

    // stage 8 z rows: zr[r][k] = z[n][k][yx0+r]
    const float* zn = z + ((size_t)n * 512) * 256;
#pragma unroll
    for (int it = 0; it < 4; ++it) {
        int i  = tid + 256 * it;            // 0..1023
        int rq = i & 1, kc = i >> 1;        // rq: which half of 8 rows
        float4 v = *(const float4*)&zn[(size_t)kc * 256 + yx0 + 4 * rq];
        zr[(4 * rq + 0) * ZS + kc] = v.x;
        zr[(4 * rq + 1) * ZS + kc] = v.y;
        zr[(4 * rq + 2) * ZS + kc] = v.z;
        zr[(4 * rq + 3) * ZS + kc] = v.w;
    }
    __syncthreads();

    float acc[8][4];
#pragma unroll
    for (int r = 0; r < 8; ++r)
#pragma unroll
        for (int j = 0; j < 4; ++j) acc[r][j] = 0.0f;

    const float* ebase = et + 4 * tid;      // codes 4*tid .. 4*tid+3
    float4 e0 = *(const float4*)&ebase[0 * 1024];
    float4 e1 = *(const float4*)&ebase[1 * 1024];
    float4 e2 = *(const float4*)&ebase[2 * 1024];
    float4 e3 = *(const float4*)&ebase[3 * 1024];
#pragma unroll 1
    for (int k4 = 0; k4 < 128; ++k4) {
        // prefetch next iteration's codebook slice (k4=127 reloads last rows)
        int kn = (k4 + 1 < 128) ? k4 + 1 : 127;
        float4 f0 = *(const float4*)&ebase[(size_t)(4 * kn + 0) * 1024];
        float4 f1 = *(const float4*)&ebase[(size_t)(4 * kn + 1) * 1024];
        float4 f2 = *(const float4*)&ebase[(size_t)(4 * kn + 2) * 1024];
        float4 f3 = *(const float4*)&ebase[(size_t)(4 * kn + 3) * 1024];
#pragma unroll
        for (int r = 0; r < 8; ++r) {
            float4 zz = *(const float4*)&zr[r * ZS + 4 * k4];
            float a0 = acc[r][0], a1 = acc[r][1], a2 = acc[r][2], a3 = acc[r][3];
            a0 = fmaf(zz.x, e0.x, a0); a0 = fmaf(zz.y, e1.x, a0);
            a0 = fmaf(zz.z, e2.x, a0); a0 = fmaf(zz.w, e3.x, a0);
            a1 = fmaf(zz.x, e0.y, a1); a1 = fmaf(zz.y, e1.y, a1);
            a1 = fmaf(zz.z, e2.y, a1); a1 = fmaf(zz.w, e3.y, a1);
            a2 = fmaf(zz.x, e0.z, a2); a2 = fmaf(zz.y, e1.z, a2);
            a2 = fmaf(zz.z, e2.z, a2); a2 = fmaf(zz.w, e3.z, a2);
            a3 = fmaf(zz.x, e0.w, a3); a3 = fmaf(zz.y, e1.w, a3);
            a3 = fmaf(zz.z, e2.w, a3); a3 = fmaf(zz.w, e3.w, a3);
            acc[r][0] = a0; acc[r][1] = a1; acc[r][2] = a2; acc[r][3] = a3;
        }
        e0 = f0; e1 = f1; e2 = f2; e3 = f3;
    }

    // thread-local best over its 4 codes (ascending code order, ties -> low)
    float4 nb = *(const float4*)&norms[4 * tid];
    float best[8]; int bi[8];
#pragma unroll
    for (int r = 0; r < 8; ++r) {
        float d0 = nb.x - 2.0f * acc[r][0];
        float d1 = nb.y - 2.0f * acc[r][1];
        float d2 = nb.z - 2.0f * acc[r][2];
        float d3 = nb.w - 2.0f * acc[r][3];
        float b = d0; int ix = 4 * tid;
        if (d1 < b) { b = d1; ix = 4 * tid + 1; }
        if (d2 < b) { b = d2; ix = 4 * tid + 2; }
        if (d3 < b) { b = d3; ix = 4 * tid + 3; }
        best[r] = b; bi[r] = ix;
    }

    // block reduction (reuse zr LDS: 2048 floats + 2048 ints <= 8*516)
    __syncthreads();
    float* rbd = zr;
    int*   rbi = (int*)(zr + 2048);
#pragma unroll
    for (int r = 0; r < 8; ++r) {
        rbd[r * 256 + tid] = best[r];
        rbi[r * 256 + tid] = bi[r];
    }
    __syncthreads();
    for (int s = 128; s > 0; s >>= 1) {
        if (tid < s) {
#pragma unroll
            for (int r = 0; r < 8; ++r) {
                int i0 = r * 256 + tid;
                float od = rbd[i0 + s]; int oi = rbi[i0 + s];
                float md = rbd[i0];     int mi = rbi[i0];
                if (od < md || (od == md && oi < mi)) { rbd[i0] = od; rbi[i0] = oi; }
            }
        }
        __syncthreads();
    }
    if (tid < 8) out[row0 + tid] = rbi[tid * 256];
}

__global__ void __launch_bounds__(256) vq_gather_pack(
    const int* __restrict__ vidx, const float* __restrict__ embed,
    unsigned* __restrict__ zq)
{
    int i = blockIdx.x * 256 + threadIdx.x;
    int yx = i & 255;
    int t  = i >> 8;
    int c  = t & 511;
    int n  = t >> 9;
    int row = (n << 8) + yx;
    zq[i] = pack_split(embed[(size_t)vidx[row] * 512 + c]);
}

// ================================ launch ===================================
extern "C" void kernel_launch(void* const* d_in, const int* in_sizes, int n_in,
                              void* d_out, int out_size, void* d_ws, size_t ws_size,
                              hipStream_t stream)
{
    (void)in_sizes; (void)n_in; (void)out_size; (void)ws_size;
    const float* x     = (const float*)d_in[0];
    const float* ew1   = (const float*)d_in[1];
    const float* eb1   = (const float*)d_in[2];
    const float* ew2   = (const float*)d_in[3];
    const float* eb2   = (const float*)d_in[4];
    const float* ew3   = (const float*)d_in[5];
    const float* eb3   = (const float*)d_in[6];
    const float* ew4   = (const float*)d_in[7];
    const float* eb4   = (const float*)d_in[8];
    const float* dw1   = (const float*)d_in[9];
    const float* db1   = (const float*)d_in[10];
    const float* dw2   = (const float*)d_in[11];
    const float* db2   = (const float*)d_in[12];
    const float* dw3   = (const float*)d_in[13];
    const float* db3   = (const float*)d_in[14];
    const float* dw4   = (const float*)d_in[15];
    const float* db4   = (const float*)d_in[16];
    const float* embed = (const float*)d_in[17];
    float* out = (float*)d_out;

    // ---- workspace layout (u32 units). Peak identical to R11 usage.
    unsigned* W0   = (unsigned*)d_ws;
    unsigned* h1p  = W0;                          // conv1 out (dead after conv2)
    unsigned* h2p  = W0 + 33554432;               // conv2 out
    unsigned* xp1  = W0 + 33554432;               // packed x (dead before conv2)
    unsigned* h3p  = W0;                          // overlays dead h1p
    float*    z    = (float*)(W0 + 8388608);      // conv4 out fp32
    unsigned* zq   = W0 + 12582912;               // quantized, packed u32
    float*    P0   = (float*)(W0 + 16777216);     // convt1 out (packed u32)
    float*    P1   = (float*)(W0 + 20971520);     // convt2 out (packed u32)
    int*      vidx = (int*)(W0 + 29360128);
    float*    norms= (float*)(W0 + 29368320);
    float*    g3o  = (float*)h2p;                 // convt3 out fp32 (h2p dead)

    // packed weights + transposed codebook live in d_out until g4 overwrites
    unsigned* wp2 = (unsigned*)d_out;             // 131,072
    unsigned* wp3 = wp2 + 131072;                 // 524,288
    unsigned* wp4 = wp2 + 655360;                 // 2,097,152
    unsigned* wq1 = wp2 + 2752512;                // 1,048,576 (4x128x2048)
    unsigned* wq2 = wq1 + 1048576;                // 131,072   (4x64x512)
    unsigned* wq3 = wq2 + 131072;                 // 32,768    (4x32x256)
    float*    et  = (float*)(wq3 + 32768);        // 524,288 (512x1024)
    unsigned* wp1 = (unsigned*)(et + 524288);     // 4,096 (64x64 padded)

    dim3 b256(256);

    // ---- pre-pass: pack weights/input, repack decoder weights, et ----
    pack_tensor<<<dim3(512),  b256, 0, stream>>>(ew2, wp2, 131072);
    pack_tensor<<<dim3(2048), b256, 0, stream>>>(ew3, wp3, 524288);
    pack_tensor<<<dim3(8192), b256, 0, stream>>>(ew4, wp4, 2097152);
    pack_w1<<<dim3(16), b256, 0, stream>>>(ew1, wp1);
    pack_tensor<<<dim3(24576), b256, 0, stream>>>(x, xp1, 6291456);
    repack_wt<512, 128><<<dim3(4096), b256, 0, stream>>>(dw1, wq1);
    repack_wt<128,  64><<<dim3(512),  b256, 0, stream>>>(dw2, wq2);
    repack_wt< 64,  32><<<dim3(128),  b256, 0, stream>>>(dw3, wq3);
    embed_transpose<<<dim3(2048), b256, 0, stream>>>(embed, et);

    // ---- encoder ----
    conv4s2_mfma_g<4, 3, 256, 256, 64, 4, 1, 1><<<dim3(8192), b256, 0, stream>>>(
        xp1, wp1, eb1, (float*)h1p);                       // h1 (packed)
    conv4s2_mfma<64, 128, 128, 128, 1><<<dim3(2048), b256, 0, stream>>>(
        h1p, wp2, eb2, (float*)h2p);                       // h2 (packed)
    conv4s2_mfma<128, 64, 64, 256, 1><<<dim3(1024), b256, 0, stream>>>(
        h2p, wp3, eb3, (float*)h3p);                       // h3 (packed)
    conv4s2_mfma<256, 32, 32, 512, 0><<<dim3(512), b256, 0, stream>>>(
        h3p, wp4, eb4, z);                                 // z (fp32)

    // ---- quantizer ----
    embed_norms<<<dim3(4), b256, 0, stream>>>(embed, norms);
    vq_argmin8r<<<dim3(1024), b256, 0, stream>>>(z, et, norms, vidx);
    vq_gather_pack<<<dim3(16384), b256, 0, stream>>>(vidx, embed, zq);

    // ---- decoder (MFMA parity-GEMM convT) ----
    convt4s2_mfma<512, 16, 16, 128, 4, 2, 1><<<dim3(4 * 128), b256, 0, stream>>>(
        zq, wq1, db1, P0);                                 // P0 (packed)
    convt4s2_mfma<128, 32, 32, 64, 4, 1, 1><<<dim3(4 * 512), b256, 0, stream>>>(
        (const unsigned*)P0, wq2, db2, P1);                // P1 (packed)
    convt4s2_mfma<64, 64, 64, 32, 2, 1, 0><<<dim3(4 * 2048), b256, 0, stream>>>(
        (const unsigned*)P1, wq3, db3, g3o);               // g3o (fp32)
    convt4s2_k<32, 128, 128, 3, 3, 1, 2><<<dim3(2048), b256, 0, stream>>>(
        g3o, dw4, db4, out);                               // tanh -> d_out
}

// Round 6
// 1132.406 us; speedup vs baseline: 1.6805x; 1.0173x over previous
//
#include <hip/hip_runtime.h>
#include <math.h>

// ---------------------------------------------------------------------------
// VQ-VAE forward. Round 13:
// (a) conv4s2_mfma gains an NB (oc-group) template param; conv4 (256->512)
//     runs NB=64 -> 1024 blocks (4/CU, was 2/CU grid-starved at 191us).
// (b) vq_argmin rewritten with f32x4 vector accumulators, fully static
//     indexing (R11 showed VGPR_Count=52 for 64+ live accs -> scratch spill).
// Everything else identical to proven R12 kernel.
// ---------------------------------------------------------------------------

typedef __attribute__((ext_vector_type(8))) short bf16x8;
typedef __attribute__((ext_vector_type(4))) float f32x4;
union FragU { unsigned u[4]; bf16x8 v; };

__device__ __forceinline__ unsigned bf16_rne(unsigned u) {
    return (u + 0x7FFFu + ((u >> 16) & 1u)) >> 16;
}
// pack fp32 -> u32: low16 = bf16(v), high16 = bf16(v - bf16(v))
__device__ __forceinline__ unsigned pack_split(float v) {
    unsigned u = __builtin_bit_cast(unsigned, v);
    unsigned hi = bf16_rne(u);
    float hif = __builtin_bit_cast(float, hi << 16);
    float r = v - hif;
    unsigned lo = bf16_rne(__builtin_bit_cast(unsigned, r));
    return hi | (lo << 16);
}

__global__ void __launch_bounds__(256) pack_tensor(
    const float* __restrict__ s, unsigned* __restrict__ d, int n)
{
    int i = blockIdx.x * 256 + threadIdx.x;
    if (i < n) d[i] = pack_split(s[i]);
}

// conv1 weights (64,3,4,4) -> padded packed [64][64] (k>=48 zero)
__global__ void __launch_bounds__(256) pack_w1(
    const float* __restrict__ w, unsigned* __restrict__ wq)
{
    int idx = blockIdx.x * 256 + threadIdx.x;
    if (idx >= 64 * 64) return;
    int k = idx & 63, oc = idx >> 6;
    float v = (k < 48) ? w[oc * 48 + k] : 0.0f;
    wq[idx] = pack_split(v);
}

// repack ConvTranspose weights (torch layout Cin,Cout,4,4) into
// wq[par][co][ci*4 + t], t = 2r+s, packed hi/lo. par = dy*2+dx.
template<int Cin, int Cout>
__global__ void __launch_bounds__(256) repack_wt(
    const float* __restrict__ w, unsigned* __restrict__ wq)
{
    constexpr int TOT = 16 * Cin * Cout;
    int idx = blockIdx.x * 256 + threadIdx.x;
    if (idx >= TOT) return;
    int t  = idx & 3;
    int ci = (idx >> 2) % Cin;
    int rest = (idx >> 2) / Cin;
    int co  = rest % Cout;
    int par = rest / Cout;
    int dy = par >> 1, dx = par & 1;
    int r = t >> 1, s = t & 1;
    int ky = 3 - dy - 2 * r;
    int kx = 3 - dx - 2 * s;
    float v = w[(((size_t)ci * Cout + co) * 4 + ky) * 4 + kx];
    wq[idx] = pack_split(v);
}

// transpose codebook: embed[1024][512] -> et[512][1024]
__global__ void __launch_bounds__(256) embed_transpose(
    const float* __restrict__ embed, float* __restrict__ et)
{
    int idx = blockIdx.x * 256 + threadIdx.x;   // 2048 blocks x 256
    int c = idx & 1023, k = idx >> 10;
    et[idx] = embed[(size_t)c * 512 + k];
}

// ================= MFMA conv k=4 s=2 p=1 + ReLU (implicit GEMM) ============
// NB = oc per block (64 or 128). 4 waves, each owns 16*NT oc (NT = NB/64).
template<int Cin, int H, int W, int Cout, int NB, int PACKO>
__global__ void __launch_bounds__(256) conv4s2_mfma(
    const unsigned* __restrict__ xp, const unsigned* __restrict__ wp,
    const float* __restrict__ bias, float* __restrict__ y)
{
    constexpr int OH = H / 2, OW = W / 2;
    constexpr int LOG_OW = (OW == 64) ? 6 : (OW == 32) ? 5 : 4;
    constexpr int R   = 64 / OW;
    constexpr int RT  = 2 * R + 2;
    constexpr int CS  = W + 2;
    constexpr int XEL = 2 * RT * CS;
    constexpr int XIT = (XEL + 255) / 256;
    constexpr int K   = Cin * 16;
    constexpr int NC  = Cin / 2;
    constexpr int NT  = NB / 64;            // oc 16-tiles per wave
    constexpr int WIT = NB / 8;             // B-load iterations
    constexpr int MBC = 32 * OH * OW / 64;
    constexpr int XPAD = (XEL + 7) & ~7;
    constexpr int SM1 = XPAD + NB * 36;
    constexpr int SM2 = NB * 68;
    constexpr int SMEM = SM1 > SM2 ? SM1 : SM2;

    __shared__ unsigned smem[SMEM];
    unsigned* raw = smem;
    unsigned* wb  = smem + XPAD;

    int bid = blockIdx.x;
    int mb = bid % MBC, ng = bid / MBC;
    int oc0 = ng * NB;
    int m0 = mb * 64;
    int nimg = m0 / (OH * OW);
    int sp0 = m0 % (OH * OW);
    int oyb = sp0 >> LOG_OW;

    int tid  = threadIdx.x;
    int lane = tid & 63, wv = tid >> 6;
    int lm = lane & 15, q = lane >> 4;
    int n0w = wv * 16 * NT;

    const unsigned* xbase = xp + (size_t)nimg * Cin * H * W;

    int  goff[XIT];
    bool gok[XIT];
#pragma unroll
    for (int s = 0; s < XIT; ++s) {
        int i = tid + 256 * s;
        goff[s] = 0; gok[s] = false;
        if (i < XEL) {
            int lc = i % CS;
            int t2 = i / CS;
            int lr = t2 % RT;
            int c  = t2 / RT;
            int gr = 2 * oyb - 1 + lr;
            int gc = lc - 1;
            bool ok = ((unsigned)gr < (unsigned)H) && ((unsigned)gc < (unsigned)W);
            goff[s] = ok ? (c * H * W + gr * W + gc) : 0;
            gok[s]  = ok;
        }
    }
    const unsigned* wbase = wp + (size_t)(oc0 + (tid >> 5)) * K + (tid & 31);
    int wlds0 = (tid >> 5) * 36 + (tid & 31);

    f32x4 acc[4][NT];
#pragma unroll
    for (int nt = 0; nt < NT; ++nt) {
        float b = bias[oc0 + n0w + nt * 16 + lm];
#pragma unroll
        for (int mt = 0; mt < 4; ++mt)
#pragma unroll
            for (int r = 0; r < 4; ++r) acc[mt][nt][r] = b;
    }

    unsigned pfa[XIT];
    unsigned pfb[WIT];

    auto load_chunk = [&](int ch) {
        const unsigned* cb = xbase + (size_t)(ch * 2) * (H * W);
#pragma unroll
        for (int s = 0; s < XIT; ++s) {
            unsigned v = 0;
            if (gok[s]) v = cb[goff[s]];
            pfa[s] = v;
        }
        const unsigned* wc = wbase + ch * 32;
#pragma unroll
        for (int s = 0; s < WIT; ++s) pfb[s] = wc[(size_t)s * 8 * K];
    };
    auto store_chunk = [&]() {
#pragma unroll
        for (int s = 0; s < XIT; ++s) {
            int i = tid + 256 * s;
            if (i < XEL) raw[i] = pfa[s];
        }
#pragma unroll
        for (int s = 0; s < WIT; ++s) wb[wlds0 + s * 288] = pfb[s];
    };

    load_chunk(0);
#pragma unroll 1
    for (int ch = 0; ch < NC; ++ch) {
        __syncthreads();
        store_chunk();
        __syncthreads();
        if (ch + 1 < NC) load_chunk(ch + 1);

        FragU bhi[NT], blo[NT];
#pragma unroll
        for (int nt = 0; nt < NT; ++nt) {
            const unsigned* bp = &wb[(n0w + nt * 16 + lm) * 36 + q * 8];
            uint4 p0 = *(const uint4*)bp;
            uint4 p1 = *(const uint4*)(bp + 4);
            unsigned e0 = p0.x, e1 = p0.y, e2 = p0.z, e3 = p0.w;
            unsigned e4 = p1.x, e5 = p1.y, e6 = p1.z, e7 = p1.w;
            bhi[nt].u[0] = (e0 & 0xffffu) | (e1 << 16);
            bhi[nt].u[1] = (e2 & 0xffffu) | (e3 << 16);
            bhi[nt].u[2] = (e4 & 0xffffu) | (e5 << 16);
            bhi[nt].u[3] = (e6 & 0xffffu) | (e7 << 16);
            blo[nt].u[0] = (e0 >> 16) | (e1 & 0xffff0000u);
            blo[nt].u[1] = (e2 >> 16) | (e3 & 0xffff0000u);
            blo[nt].u[2] = (e4 >> 16) | (e5 & 0xffff0000u);
            blo[nt].u[3] = (e6 >> 16) | (e7 & 0xffff0000u);
        }
#pragma unroll
        for (int mt = 0; mt < 4; ++mt) {
            int m = mt * 16 + lm;
            int oyl = m >> LOG_OW, oxl = m & (OW - 1);
            int c = q >> 1, rb = 2 * oyl + (q & 1) * 2;
            const unsigned* rp = &raw[(c * RT + rb) * CS + 2 * oxl];
            uint2 a0 = *(const uint2*)rp;
            uint2 a1 = *(const uint2*)(rp + 2);
            uint2 a2 = *(const uint2*)(rp + CS);
            uint2 a3 = *(const uint2*)(rp + CS + 2);
            FragU ahi, alo;
            ahi.u[0] = (a0.x & 0xffffu) | (a0.y << 16);
            ahi.u[1] = (a1.x & 0xffffu) | (a1.y << 16);
            ahi.u[2] = (a2.x & 0xffffu) | (a2.y << 16);
            ahi.u[3] = (a3.x & 0xffffu) | (a3.y << 16);
            alo.u[0] = (a0.x >> 16) | (a0.y & 0xffff0000u);
            alo.u[1] = (a1.x >> 16) | (a1.y & 0xffff0000u);
            alo.u[2] = (a2.x >> 16) | (a2.y & 0xffff0000u);
            alo.u[3] = (a3.x >> 16) | (a3.y & 0xffff0000u);
#pragma unroll
            for (int nt = 0; nt < NT; ++nt) {
                acc[mt][nt] = __builtin_amdgcn_mfma_f32_16x16x32_bf16(
                    ahi.v, bhi[nt].v, acc[mt][nt], 0, 0, 0);
                acc[mt][nt] = __builtin_amdgcn_mfma_f32_16x16x32_bf16(
                    ahi.v, blo[nt].v, acc[mt][nt], 0, 0, 0);
                acc[mt][nt] = __builtin_amdgcn_mfma_f32_16x16x32_bf16(
                    alo.v, bhi[nt].v, acc[mt][nt], 0, 0, 0);
            }
        }
    }

    __syncthreads();
    float* cs = (float*)smem;
#pragma unroll
    for (int mt = 0; mt < 4; ++mt)
#pragma unroll
        for (int nt = 0; nt < NT; ++nt) {
            int nl = n0w + nt * 16 + lm;
#pragma unroll
            for (int r = 0; r < 4; ++r)
                cs[nl * 68 + mt * 16 + q * 4 + r] = acc[mt][nt][r];
        }
    __syncthreads();
    {
        constexpr int QT = 256 / NB;            // threads per channel
        constexpr int MQ = 64 / QT;             // m per thread
        int nl = tid / QT, qt = tid % QT;
        size_t gb = ((size_t)(nimg * Cout + oc0 + nl)) * (OH * OW) + sp0 + qt * MQ;
#pragma unroll
        for (int i2 = 0; i2 < MQ / 4; ++i2) {
            float4 v = *(float4*)&cs[nl * 68 + qt * MQ + 4 * i2];
            v.x = fmaxf(v.x, 0.0f); v.y = fmaxf(v.y, 0.0f);
            v.z = fmaxf(v.z, 0.0f); v.w = fmaxf(v.w, 0.0f);
            if (PACKO) {
                uint4 p;
                p.x = pack_split(v.x); p.y = pack_split(v.y);
                p.z = pack_split(v.z); p.w = pack_split(v.w);
                *(uint4*)((unsigned*)y + gb + 4 * i2) = p;
            } else {
                *(float4*)(y + gb + 4 * i2) = v;
            }
        }
    }
}

// ========== generalized MFMA conv (sub-row tiles + zero-padded K) ==========
template<int Cin, int CINR, int H, int W, int Cout, int MT, int NT, int PACKO>
__global__ void __launch_bounds__(256) conv4s2_mfma_g(
    const unsigned* __restrict__ xp, const unsigned* __restrict__ wp,
    const float* __restrict__ bias, float* __restrict__ y)
{
    constexpr int OH = H / 2, OW = W / 2;
    constexpr int OWB = (OW >= 64) ? 64 : OW;
    constexpr int LOG_OWB = (OWB == 64) ? 6 : (OWB == 32) ? 5 : 4;
    constexpr int LOG_OW  = (OW == 128) ? 7 : (OW == 64) ? 6 : (OW == 32) ? 5 : 4;
    constexpr int R   = 64 / OWB;
    constexpr int RT  = 2 * R + 2;
    constexpr int CS  = 2 * OWB + 2;
    constexpr int XEL = 2 * RT * CS;
    constexpr int XIT = (XEL + 255) / 256;
    constexpr int K   = Cin * 16;
    constexpr int NC  = Cin / 2;
    constexpr int NB  = Cout;
    constexpr int WIT = NB / 8;
    constexpr int WN  = Cout / (16 * NT);
    constexpr int WM  = 4 / WN;
    static_assert(WM * MT * 16 == 64, "M tiling");
    static_assert(WN * NT * 16 == Cout, "N tiling");
    constexpr int MBC = 32 * OH * OW / 64;
    constexpr int XPAD = (XEL + 7) & ~7;
    constexpr int SM1 = XPAD + NB * 36;
    constexpr int SM2 = NB * 68;
    constexpr int SMEM = SM1 > SM2 ? SM1 : SM2;

    __shared__ unsigned smem[SMEM];
    unsigned* raw = smem;
    unsigned* wb  = smem + XPAD;

    int bid = blockIdx.x;
    int mb = bid % MBC, ng = bid / MBC;
    int oc0 = ng * NB;
    int m0 = bid % MBC * 64;
    m0 = mb * 64;
    int nimg = m0 / (OH * OW);
    int sp0 = m0 % (OH * OW);
    int oyb = sp0 >> LOG_OW;
    int oxb = sp0 & (OW - 1);

    int tid  = threadIdx.x;
    int lane = tid & 63, wv = tid >> 6;
    int lm = lane & 15, q = lane >> 4;
    int wm = wv / WN, wn = wv % WN;

    const unsigned* xbase = xp + (size_t)nimg * CINR * H * W;

    int  goff[XIT];
    bool gok[XIT];
    int  cidx[XIT];
#pragma unroll
    for (int s = 0; s < XIT; ++s) {
        int i = tid + 256 * s;
        goff[s] = 0; gok[s] = false; cidx[s] = 0;
        if (i < XEL) {
            int lc = i % CS;
            int t2 = i / CS;
            int lr = t2 % RT;
            int c  = t2 / RT;
            int gr = 2 * oyb - 1 + lr;
            int gc = 2 * oxb - 1 + lc;
            bool ok = ((unsigned)gr < (unsigned)H) && ((unsigned)gc < (unsigned)W);
            goff[s] = ok ? (c * H * W + gr * W + gc) : 0;
            gok[s]  = ok;
            cidx[s] = c;
        }
    }
    const unsigned* wbase = wp + (size_t)(oc0 + (tid >> 5)) * K + (tid & 31);
    int wlds0 = (tid >> 5) * 36 + (tid & 31);

    f32x4 acc[MT][NT];
#pragma unroll
    for (int nt = 0; nt < NT; ++nt) {
        float b = bias[oc0 + wn * NT * 16 + nt * 16 + lm];
#pragma unroll
        for (int mt = 0; mt < MT; ++mt)
#pragma unroll
            for (int r = 0; r < 4; ++r) acc[mt][nt][r] = b;
    }

    unsigned pfa[XIT];
    unsigned pfb[WIT];

    auto load_chunk = [&](int ch) {
        const unsigned* cb = xbase + (size_t)(ch * 2) * (H * W);
#pragma unroll
        for (int s = 0; s < XIT; ++s) {
            unsigned v = 0;
            bool okc = (2 * ch + cidx[s]) < CINR;
            if (gok[s] && okc) v = cb[goff[s]];
            pfa[s] = v;
        }
        const unsigned* wc = wbase + ch * 32;
#pragma unroll
        for (int s = 0; s < WIT; ++s) pfb[s] = wc[(size_t)s * 8 * K];
    };
    auto store_chunk = [&]() {
#pragma unroll
        for (int s = 0; s < XIT; ++s) {
            int i = tid + 256 * s;
            if (i < XEL) raw[i] = pfa[s];
        }
#pragma unroll
        for (int s = 0; s < WIT; ++s) wb[wlds0 + s * 288] = pfb[s];
    };

    load_chunk(0);
#pragma unroll 1
    for (int ch = 0; ch < NC; ++ch) {
        __syncthreads();
        store_chunk();
        __syncthreads();
        if (ch + 1 < NC) load_chunk(ch + 1);

        FragU bhi[NT], blo[NT];
#pragma unroll
        for (int nt = 0; nt < NT; ++nt) {
            const unsigned* bp = &wb[(wn * NT * 16 + nt * 16 + lm) * 36 + q * 8];
            uint4 p0 = *(const uint4*)bp;
            uint4 p1 = *(const uint4*)(bp + 4);
            unsigned e0 = p0.x, e1 = p0.y, e2 = p0.z, e3 = p0.w;
            unsigned e4 = p1.x, e5 = p1.y, e6 = p1.z, e7 = p1.w;
            bhi[nt].u[0] = (e0 & 0xffffu) | (e1 << 16);
            bhi[nt].u[1] = (e2 & 0xffffu) | (e3 << 16);
            bhi[nt].u[2] = (e4 & 0xffffu) | (e5 << 16);
            bhi[nt].u[3] = (e6 & 0xffffu) | (e7 << 16);
            blo[nt].u[0] = (e0 >> 16) | (e1 & 0xffff0000u);
            blo[nt].u[1] = (e2 >> 16) | (e3 & 0xffff0000u);
            blo[nt].u[2] = (e4 >> 16) | (e5 & 0xffff0000u);
            blo[nt].u[3] = (e6 >> 16) | (e7 & 0xffff0000u);
        }
#pragma unroll
        for (int mt = 0; mt < MT; ++mt) {
            int m = wm * (MT * 16) + mt * 16 + lm;
            int oyl = m >> LOG_OWB, oxl = m & (OWB - 1);
            int c = q >> 1, rb = 2 * oyl + (q & 1) * 2;
            const unsigned* rp = &raw[(c * RT + rb) * CS + 2 * oxl];
            uint2 a0 = *(const uint2*)rp;
            uint2 a1 = *(const uint2*)(rp + 2);
            uint2 a2 = *(const uint2*)(rp + CS);
            uint2 a3 = *(const uint2*)(rp + CS + 2);
            FragU ahi, alo;
            ahi.u[0] = (a0.x & 0xffffu) | (a0.y << 16);
            ahi.u[1] = (a1.x & 0xffffu) | (a1.y << 16);
            ahi.u[2] = (a2.x & 0xffffu) | (a2.y << 16);
            ahi.u[3] = (a3.x & 0xffffu) | (a3.y << 16);
            alo.u[0] = (a0.x >> 16) | (a0.y & 0xffff0000u);
            alo.u[1] = (a1.x >> 16) | (a1.y & 0xffff0000u);
            alo.u[2] = (a2.x >> 16) | (a2.y & 0xffff0000u);
            alo.u[3] = (a3.x >> 16) | (a3.y & 0xffff0000u);
#pragma unroll
            for (int nt = 0; nt < NT; ++nt) {
                acc[mt][nt] = __builtin_amdgcn_mfma_f32_16x16x32_bf16(
                    ahi.v, bhi[nt].v, acc[mt][nt], 0, 0, 0);
                acc[mt][nt] = __builtin_amdgcn_mfma_f32_16x16x32_bf16(
                    ahi.v, blo[nt].v, acc[mt][nt], 0, 0, 0);
                acc[mt][nt] = __builtin_amdgcn_mfma_f32_16x16x32_bf16(
                    alo.v, bhi[nt].v, acc[mt][nt], 0, 0, 0);
            }
        }
    }

    __syncthreads();
    float* cs = (float*)smem;
#pragma unroll
    for (int mt = 0; mt < MT; ++mt)
#pragma unroll
        for (int nt = 0; nt < NT; ++nt) {
            int nl  = wn * NT * 16 + nt * 16 + lm;
            int mb2 = wm * (MT * 16) + mt * 16 + q * 4;
#pragma unroll
            for (int r = 0; r < 4; ++r)
                cs[nl * 68 + mb2 + r] = acc[mt][nt][r];
        }
    __syncthreads();
    {
        constexpr int QT = 256 / NB;
        constexpr int MQ = 64 / QT;
        int nl = tid / QT, qt = tid % QT;
        size_t gb = ((size_t)(nimg * Cout + oc0 + nl)) * (OH * OW) + sp0 + qt * MQ;
#pragma unroll
        for (int i2 = 0; i2 < MQ / 4; ++i2) {
            float4 v = *(float4*)&cs[nl * 68 + qt * MQ + 4 * i2];
            v.x = fmaxf(v.x, 0.0f); v.y = fmaxf(v.y, 0.0f);
            v.z = fmaxf(v.z, 0.0f); v.w = fmaxf(v.w, 0.0f);
            if (PACKO) {
                uint4 p;
                p.x = pack_split(v.x); p.y = pack_split(v.y);
                p.z = pack_split(v.z); p.w = pack_split(v.w);
                *(uint4*)((unsigned*)y + gb + 4 * i2) = p;
            } else {
                *(float4*)(y + gb + 4 * i2) = v;
            }
        }
    }
}

// ============ MFMA ConvTranspose k=4 s=2 p=1 + ReLU (parity GEMM) ==========
template<int Cin, int Hh, int Wh, int Cout, int MT, int NT, int PACKO>
__global__ void __launch_bounds__(256) convt4s2_mfma(
    const unsigned* __restrict__ xp, const unsigned* __restrict__ wq,
    const float* __restrict__ bias, float* __restrict__ y)
{
    constexpr int W = Wh;
    constexpr int LOG_W = (W == 64) ? 6 : (W == 32) ? 5 : 4;
    constexpr int R   = 64 / W;
    constexpr int RT  = R + 1;
    constexpr int CS  = W + 2;
    constexpr int XEL = 8 * RT * CS;
    constexpr int XIT = (XEL + 255) / 256;
    constexpr int K   = Cin * 4;
    constexpr int NC  = Cin / 8;
    constexpr int NB  = Cout;
    constexpr int WIT = NB / 8;
    constexpr int WN  = Cout / (16 * NT);
    constexpr int WM  = 4 / WN;
    static_assert(WM * MT * 16 == 64, "M tiling");
    static_assert(WN * NT * 16 == Cout, "N tiling");
    constexpr int MBC = 32 * Hh * W / 64;
    constexpr int XPAD = (XEL + 7) & ~7;
    constexpr int SM1 = XPAD + NB * 36;
    constexpr int SM2 = NB * 68;
    constexpr int SMEM = SM1 > SM2 ? SM1 : SM2;

    __shared__ unsigned smem[SMEM];
    unsigned* raw = smem;
    unsigned* wb  = smem + XPAD;

    int bid = blockIdx.x;
    int mb  = bid % MBC;
    int par = bid / MBC;
    int dy = par >> 1, dx = par & 1;

    int m0   = mb * 64;
    int nimg = m0 / (Hh * W);
    int sp0  = m0 % (Hh * W);
    int il0  = sp0 >> LOG_W;

    int tid = threadIdx.x;
    int lane = tid & 63, wv = tid >> 6;
    int lm = lane & 15, q = lane >> 4;
    int wm = wv / WN, wn = wv % WN;

    const unsigned* xbase = xp + (size_t)nimg * Cin * Hh * W;

    int  goff[XIT];
    bool gok[XIT];
#pragma unroll
    for (int s = 0; s < XIT; ++s) {
        int i = tid + 256 * s;
        goff[s] = 0; gok[s] = false;
        if (i < XEL) {
            int lc = i % CS;
            int t2 = i / CS;
            int lr = t2 % RT;
            int c  = t2 / RT;
            int gr = il0 - 1 + dy + lr;
            int gc = lc - 1;
            bool ok = ((unsigned)gr < (unsigned)Hh) && ((unsigned)gc < (unsigned)W);
            goff[s] = ok ? (c * Hh * W + gr * W + gc) : 0;
            gok[s]  = ok;
        }
    }
    const unsigned* wbase = wq + (size_t)(par * Cout + (tid >> 5)) * K + (tid & 31);
    int wlds0 = (tid >> 5) * 36 + (tid & 31);

    f32x4 acc[MT][NT];
#pragma unroll
    for (int nt = 0; nt < NT; ++nt) {
        float b = bias[wn * NT * 16 + nt * 16 + lm];
#pragma unroll
        for (int mt = 0; mt < MT; ++mt)
#pragma unroll
            for (int r = 0; r < 4; ++r) acc[mt][nt][r] = b;
    }

    unsigned pfa[XIT];
    unsigned pfb[WIT];

    auto load_chunk = [&](int ch) {
        const unsigned* cb = xbase + (size_t)(ch * 8) * (Hh * W);
#pragma unroll
        for (int s = 0; s < XIT; ++s) {
            unsigned v = 0;
            if (gok[s]) v = cb[goff[s]];
            pfa[s] = v;
        }
        const unsigned* wc = wbase + ch * 32;
#pragma unroll
        for (int s = 0; s < WIT; ++s) pfb[s] = wc[(size_t)s * 8 * K];
    };
    auto store_chunk = [&]() {
#pragma unroll
        for (int s = 0; s < XIT; ++s) {
            int i = tid + 256 * s;
            if (i < XEL) raw[i] = pfa[s];
        }
#pragma unroll
        for (int s = 0; s < WIT; ++s) wb[wlds0 + s * 288] = pfb[s];
    };

    load_chunk(0);
#pragma unroll 1
    for (int ch = 0; ch < NC; ++ch) {
        __syncthreads();
        store_chunk();
        __syncthreads();
        if (ch + 1 < NC) load_chunk(ch + 1);

        FragU bhi[NT], blo[NT];
#pragma unroll
        for (int nt = 0; nt < NT; ++nt) {
            const unsigned* bp = &wb[(wn * NT * 16 + nt * 16 + lm) * 36 + q * 8];
            uint4 p0 = *(const uint4*)bp;
            uint4 p1 = *(const uint4*)(bp + 4);
            unsigned e0 = p0.x, e1 = p0.y, e2 = p0.z, e3 = p0.w;
            unsigned e4 = p1.x, e5 = p1.y, e6 = p1.z, e7 = p1.w;
            bhi[nt].u[0] = (e0 & 0xffffu) | (e1 << 16);
            bhi[nt].u[1] = (e2 & 0xffffu) | (e3 << 16);
            bhi[nt].u[2] = (e4 & 0xffffu) | (e5 << 16);
            bhi[nt].u[3] = (e6 & 0xffffu) | (e7 << 16);
            blo[nt].u[0] = (e0 >> 16) | (e1 & 0xffff0000u);
            blo[nt].u[1] = (e2 >> 16) | (e3 & 0xffff0000u);
            blo[nt].u[2] = (e4 >> 16) | (e5 & 0xffff0000u);
            blo[nt].u[3] = (e6 >> 16) | (e7 & 0xffff0000u);
        }
#pragma unroll
        for (int mt = 0; mt < MT; ++mt) {
            int ml = wm * (MT * 16) + mt * 16 + lm;
            int il = ml >> LOG_W, jl = ml & (W - 1);
            const unsigned* rp = &raw[((2 * q) * RT + il) * CS + jl + dx];
            unsigned a00 = rp[0],               a01 = rp[1];
            unsigned a10 = rp[CS],              a11 = rp[CS + 1];
            unsigned a20 = rp[RT * CS],         a21 = rp[RT * CS + 1];
            unsigned a30 = rp[RT * CS + CS],    a31 = rp[RT * CS + CS + 1];
            FragU ahi, alo;
            ahi.u[0] = (a00 & 0xffffu) | (a01 << 16);
            ahi.u[1] = (a10 & 0xffffu) | (a11 << 16);
            ahi.u[2] = (a20 & 0xffffu) | (a21 << 16);
            ahi.u[3] = (a30 & 0xffffu) | (a31 << 16);
            alo.u[0] = (a00 >> 16) | (a01 & 0xffff0000u);
            alo.u[1] = (a10 >> 16) | (a11 & 0xffff0000u);
            alo.u[2] = (a20 >> 16) | (a21 & 0xffff0000u);
            alo.u[3] = (a30 >> 16) | (a31 & 0xffff0000u);
#pragma unroll
            for (int nt = 0; nt < NT; ++nt) {
                acc[mt][nt] = __builtin_amdgcn_mfma_f32_16x16x32_bf16(
                    ahi.v, bhi[nt].v, acc[mt][nt], 0, 0, 0);
                acc[mt][nt] = __builtin_amdgcn_mfma_f32_16x16x32_bf16(
                    ahi.v, blo[nt].v, acc[mt][nt], 0, 0, 0);
                acc[mt][nt] = __builtin_amdgcn_mfma_f32_16x16x32_bf16(
                    alo.v, bhi[nt].v, acc[mt][nt], 0, 0, 0);
            }
        }
    }

    __syncthreads();
    float* cs = (float*)smem;
#pragma unroll
    for (int mt = 0; mt < MT; ++mt)
#pragma unroll
        for (int nt = 0; nt < NT; ++nt) {
            int nl  = wn * NT * 16 + nt * 16 + lm;
            int mb2 = wm * (MT * 16) + mt * 16 + q * 4;
#pragma unroll
            for (int r = 0; r < 4; ++r)
                cs[nl * 68 + mb2 + r] = acc[mt][nt][r];
        }
    __syncthreads();
    constexpr int EIT = NB * 64 / 256;
#pragma unroll
    for (int it = 0; it < EIT; ++it) {
        int idx = tid + 256 * it;
        int c = idx >> 6, m = idx & 63;
        int il = m >> LOG_W, jl = m & (W - 1);
        int oy = 2 * (il0 + il) + dy;
        int ox = 2 * jl + dx;
        float v = fmaxf(cs[c * 68 + m], 0.0f);
        size_t go = (((size_t)(nimg * Cout + c)) * (2 * Hh) + oy) * (2 * W) + ox;
        if (PACKO) ((unsigned*)y)[go] = pack_split(v);
        else       y[go] = v;
    }
}

// ================= direct convT (g4, tanh) =================================
template<int Cin, int H, int W, int Cout, int COT, int ACT, int UNR>
__global__ void __launch_bounds__(256) convt4s2_k(
    const float* __restrict__ x, const float* __restrict__ w,
    const float* __restrict__ bias, float* __restrict__ y)
{
    constexpr int OH = 2 * H, OW = 2 * W, OWq = OW / 4;
    int id = blockIdx.x * 256 + threadIdx.x;
    int ox4 = id % OWq; int t = id / OWq;
    int oy  = t % OH;   t /= OH;
    int cog = t % (Cout / COT);
    int n   = t / (Cout / COT);
    int co0 = __builtin_amdgcn_readfirstlane(cog * COT);
    n       = __builtin_amdgcn_readfirstlane(n);

    int p   = (oy + 1) & 1;
    int iyA = (oy + 1 - p) >> 1;
    int iyB = iyA - 1;
    bool vA = (iyA < H);
    bool vB = (iyB >= 0);
    int iyAc = vA ? iyA : 0, iyBc = vB ? iyB : 0;

    int t0 = 2 * ox4;
    bool c0 = (t0 - 1 >= 0);
    bool c3 = (t0 + 2 <= W - 1);
    int j0 = c0 ? t0 - 1 : 0;
    int j3 = c3 ? t0 + 2 : 0;

    float acc[COT][4];
#pragma unroll
    for (int o = 0; o < COT; ++o) {
        float b = bias[co0 + o];
#pragma unroll
        for (int j = 0; j < 4; ++j) acc[o][j] = b;
    }

    const float* xn = x + (size_t)n * Cin * H * W;

#pragma unroll UNR
    for (int ci = 0; ci < Cin; ++ci) {
        const float* xc  = xn + (size_t)ci * (H * W);
        const float* xrA = xc + (size_t)iyAc * W;
        const float* xrB = xc + (size_t)iyBc * W;
        float a0 = (vA && c0) ? xrA[j0]     : 0.0f;
        float a1 =  vA        ? xrA[t0]     : 0.0f;
        float a2 =  vA        ? xrA[t0 + 1] : 0.0f;
        float a3 = (vA && c3) ? xrA[j3]     : 0.0f;
        float b0 = (vB && c0) ? xrB[j0]     : 0.0f;
        float b1 =  vB        ? xrB[t0]     : 0.0f;
        float b2 =  vB        ? xrB[t0 + 1] : 0.0f;
        float b3 = (vB && c3) ? xrB[j3]     : 0.0f;

        const float* wci = w + ((size_t)ci * Cout + co0) * 16;
#pragma unroll
        for (int o = 0; o < COT; ++o) {
            const float* wr = wci + (size_t)o * 16;
            float wA0 = wr[p * 4 + 0], wA1 = wr[p * 4 + 1];
            float wA2 = wr[p * 4 + 2], wA3 = wr[p * 4 + 3];
            float wB0 = wr[(p + 2) * 4 + 0], wB1 = wr[(p + 2) * 4 + 1];
            float wB2 = wr[(p + 2) * 4 + 2], wB3 = wr[(p + 2) * 4 + 3];
            acc[o][0] = fmaf(a1, wA1, acc[o][0]); acc[o][0] = fmaf(a0, wA3, acc[o][0]);
            acc[o][0] = fmaf(b1, wB1, acc[o][0]); acc[o][0] = fmaf(b0, wB3, acc[o][0]);
            acc[o][1] = fmaf(a2, wA0, acc[o][1]); acc[o][1] = fmaf(a1, wA2, acc[o][1]);
            acc[o][1] = fmaf(b2, wB0, acc[o][1]); acc[o][1] = fmaf(b1, wB2, acc[o][1]);
            acc[o][2] = fmaf(a2, wA1, acc[o][2]); acc[o][2] = fmaf(a1, wA3, acc[o][2]);
            acc[o][2] = fmaf(b2, wB1, acc[o][2]); acc[o][2] = fmaf(b1, wB3, acc[o][2]);
            acc[o][3] = fmaf(a3, wA0, acc[o][3]); acc[o][3] = fmaf(a2, wA2, acc[o][3]);
            acc[o][3] = fmaf(b3, wB0, acc[o][3]); acc[o][3] = fmaf(b2, wB2, acc[o][3]);
        }
    }

    int ox0 = ox4 * 4;
#pragma unroll
    for (int o = 0; o < COT; ++o) {
        float* yr = y + (((size_t)n * Cout + co0 + o) * OH + oy) * OW + ox0;
#pragma unroll
        for (int j = 0; j < 4; ++j) {
            float v = acc[o][j];
            yr[j] = (ACT == 0) ? fmaxf(v, 0.0f) : tanhf(v);
        }
    }
}

// =============================== quantizer =================================
__global__ void __launch_bounds__(256) embed_norms(
    const float* __restrict__ embed, float* __restrict__ norms)
{
    int c = blockIdx.x * 256 + threadIdx.x;
    const float* e = embed + (size_t)c * 512;
    float s = 0.0f;
    for (int k = 0; k < 512; ++k) s = fmaf(e[k], e[k], s);
    norms[c] = s;
}

// Register-tiled GEMM argmin with f32x4 vector accumulators (static indices
// -> guaranteed VGPR allocation; R11 showed the scalar form spilled).
// 8 rows x 1024 codes per block, 1024 blocks. Per-element fp32 accumulation
// order over k unchanged.
__global__ void __launch_bounds__(256, 4) vq_argmin8v(
    const float* __restrict__ z, const float* __restrict__ et,
    const float* __restrict__ norms, int* __restrict__ out)
{
    constexpr int ZS = 516;                 // padded LDS row stride (floats)
    int row0 = blockIdx.x * 8;              // 1024 blocks
    int n    = row0 >> 8;
    int yx0  = row0 & 255;
    int tid  = threadIdx.x;

    __shared__ float zr[8 * ZS];            // 16,512 B

    // stage 8 z rows: zr[r][k] = z[n][k][yx0+r]
    const float* zn = z + ((size_t)n * 512) * 256;
#pragma unroll
    for (int it = 0; it < 4; ++it) {
        int i  = tid + 256 * it;            // 0..1023
        int rq = i & 1, kc = i >> 1;
        float4 v = *(const float4*)&zn[(size_t)kc * 256 + yx0 + 4 * rq];
        zr[(4 * rq + 0) * ZS + kc] = v.x;
        zr[(4 * rq + 1) * ZS + kc] = v.y;
        zr[(4 * rq + 2) * ZS + kc] = v.z;
        zr[(4 * rq + 3) * ZS + kc] = v.w;
    }
    __syncthreads();

    f32x4 acc[8];
#pragma unroll
    for (int r = 0; r < 8; ++r) acc[r] = (f32x4){0.f, 0.f, 0.f, 0.f};

    const float* ebase = et + 4 * tid;      // codes 4*tid .. 4*tid+3
    f32x4 ev[4], fv[4];
#pragma unroll
    for (int j = 0; j < 4; ++j)
        ev[j] = *(const f32x4*)&ebase[(size_t)j * 1024];

#pragma unroll 1
    for (int k4 = 0; k4 < 128; ++k4) {
        int kn = (k4 + 1 < 128) ? k4 + 1 : 127;
#pragma unroll
        for (int j = 0; j < 4; ++j)
            fv[j] = *(const f32x4*)&ebase[(size_t)(4 * kn + j) * 1024];
#pragma unroll
        for (int r = 0; r < 8; ++r) {
            float4 zz = *(const float4*)&zr[r * ZS + 4 * k4];
            f32x4 a = acc[r];
            a += ev[0] * zz.x;
            a += ev[1] * zz.y;
            a += ev[2] * zz.z;
            a += ev[3] * zz.w;
            acc[r] = a;
        }
#pragma unroll
        for (int j = 0; j < 4; ++j) ev[j] = fv[j];
    }

    // thread-local best over its 4 codes (ascending code order, ties -> low)
    float4 nb = *(const float4*)&norms[4 * tid];
    float best[8]; int bi[8];
#pragma unroll
    for (int r = 0; r < 8; ++r) {
        float d0 = nb.x - 2.0f * acc[r][0];
        float d1 = nb.y - 2.0f * acc[r][1];
        float d2 = nb.z - 2.0f * acc[r][2];
        float d3 = nb.w - 2.0f * acc[r][3];
        float b = d0; int ix = 4 * tid;
        if (d1 < b) { b = d1; ix = 4 * tid + 1; }
        if (d2 < b) { b = d2; ix = 4 * tid + 2; }
        if (d3 < b) { b = d3; ix = 4 * tid + 3; }
        best[r] = b; bi[r] = ix;
    }

    // block reduction (reuse zr LDS: 2048 floats + 2048 ints <= 8*516)
    __syncthreads();
    float* rbd = zr;
    int*   rbi = (int*)(zr + 2048);
#pragma unroll
    for (int r = 0; r < 8; ++r) {
        rbd[r * 256 + tid] = best[r];
        rbi[r * 256 + tid] = bi[r];
    }
    __syncthreads();
    for (int s = 128; s > 0; s >>= 1) {
        if (tid < s) {
#pragma unroll
            for (int r = 0; r < 8; ++r) {
                int i0 = r * 256 + tid;
                float od = rbd[i0 + s]; int oi = rbi[i0 + s];
                float md = rbd[i0];     int mi = rbi[i0];
                if (od < md || (od == md && oi < mi)) { rbd[i0] = od; rbi[i0] = oi; }
            }
        }
        __syncthreads();
    }
    if (tid < 8) out[row0 + tid] = rbi[tid * 256];
}

__global__ void __launch_bounds__(256) vq_gather_pack(
    const int* __restrict__ vidx, const float* __restrict__ embed,
    unsigned* __restrict__ zq)
{
    int i = blockIdx.x * 256 + threadIdx.x;
    int yx = i & 255;
    int t  = i >> 8;
    int c  = t & 511;
    int n  = t >> 9;
    int row = (n << 8) + yx;
    zq[i] = pack_split(embed[(size_t)vidx[row] * 512 + c]);
}

// ================================ launch ===================================
extern "C" void kernel_launch(void* const* d_in, const int* in_sizes, int n_in,
                              void* d_out, int out_size, void* d_ws, size_t ws_size,
                              hipStream_t stream)
{
    (void)in_sizes; (void)n_in; (void)out_size; (void)ws_size;
    const float* x     = (const float*)d_in[0];
    const float* ew1   = (const float*)d_in[1];
    const float* eb1   = (const float*)d_in[2];
    const float* ew2   = (const float*)d_in[3];
    const float* eb2   = (const float*)d_in[4];
    const float* ew3   = (const float*)d_in[5];
    const float* eb3   = (const float*)d_in[6];
    const float* ew4   = (const float*)d_in[7];
    const float* eb4   = (const float*)d_in[8];
    const float* dw1   = (const float*)d_in[9];
    const float* db1   = (const float*)d_in[10];
    const float* dw2   = (const float*)d_in[11];
    const float* db2   = (const float*)d_in[12];
    const float* dw3   = (const float*)d_in[13];
    const float* db3   = (const float*)d_in[14];
    const float* dw4   = (const float*)d_in[15];
    const float* db4   = (const float*)d_in[16];
    const float* embed = (const float*)d_in[17];
    float* out = (float*)d_out;

    // ---- workspace layout (u32 units). Peak identical to R12 usage.
    unsigned* W0   = (unsigned*)d_ws;
    unsigned* h1p  = W0;                          // conv1 out (dead after conv2)
    unsigned* h2p  = W0 + 33554432;               // conv2 out
    unsigned* xp1  = W0 + 33554432;               // packed x (dead before conv2)
    unsigned* h3p  = W0;                          // overlays dead h1p
    float*    z    = (float*)(W0 + 8388608);      // conv4 out fp32
    unsigned* zq   = W0 + 12582912;               // quantized, packed u32
    float*    P0   = (float*)(W0 + 16777216);     // convt1 out (packed u32)
    float*    P1   = (float*)(W0 + 20971520);     // convt2 out (packed u32)
    int*      vidx = (int*)(W0 + 29360128);
    float*    norms= (float*)(W0 + 29368320);
    float*    g3o  = (float*)h2p;                 // convt3 out fp32 (h2p dead)

    // packed weights + transposed codebook live in d_out until g4 overwrites
    unsigned* wp2 = (unsigned*)d_out;             // 131,072
    unsigned* wp3 = wp2 + 131072;                 // 524,288
    unsigned* wp4 = wp2 + 655360;                 // 2,097,152
    unsigned* wq1 = wp2 + 2752512;                // 1,048,576 (4x128x2048)
    unsigned* wq2 = wq1 + 1048576;                // 131,072   (4x64x512)
    unsigned* wq3 = wq2 + 131072;                 // 32,768    (4x32x256)
    float*    et  = (float*)(wq3 + 32768);        // 524,288 (512x1024)
    unsigned* wp1 = (unsigned*)(et + 524288);     // 4,096 (64x64 padded)

    dim3 b256(256);

    // ---- pre-pass: pack weights/input, repack decoder weights, et ----
    pack_tensor<<<dim3(512),  b256, 0, stream>>>(ew2, wp2, 131072);
    pack_tensor<<<dim3(2048), b256, 0, stream>>>(ew3, wp3, 524288);
    pack_tensor<<<dim3(8192), b256, 0, stream>>>(ew4, wp4, 2097152);
    pack_w1<<<dim3(16), b256, 0, stream>>>(ew1, wp1);
    pack_tensor<<<dim3(24576), b256, 0, stream>>>(x, xp1, 6291456);
    repack_wt<512, 128><<<dim3(4096), b256, 0, stream>>>(dw1, wq1);
    repack_wt<128,  64><<<dim3(512),  b256, 0, stream>>>(dw2, wq2);
    repack_wt< 64,  32><<<dim3(128),  b256, 0, stream>>>(dw3, wq3);
    embed_transpose<<<dim3(2048), b256, 0, stream>>>(embed, et);

    // ---- encoder ----
    conv4s2_mfma_g<4, 3, 256, 256, 64, 4, 1, 1><<<dim3(8192), b256, 0, stream>>>(
        xp1, wp1, eb1, (float*)h1p);                       // h1 (packed)
    conv4s2_mfma<64, 128, 128, 128, 128, 1><<<dim3(2048), b256, 0, stream>>>(
        h1p, wp2, eb2, (float*)h2p);                       // h2 (packed)
    conv4s2_mfma<128, 64, 64, 256, 128, 1><<<dim3(1024), b256, 0, stream>>>(
        h2p, wp3, eb3, (float*)h3p);                       // h3 (packed)
    conv4s2_mfma<256, 32, 32, 512, 64, 0><<<dim3(1024), b256, 0, stream>>>(
        h3p, wp4, eb4, z);                                 // z (fp32)

    // ---- quantizer ----
    embed_norms<<<dim3(4), b256, 0, stream>>>(embed, norms);
    vq_argmin8v<<<dim3(1024), b256, 0, stream>>>(z, et, norms, vidx);
    vq_gather_pack<<<dim3(16384), b256, 0, stream>>>(vidx, embed, zq);

    // ---- decoder (MFMA parity-GEMM convT) ----
    convt4s2_mfma<512, 16, 16, 128, 4, 2, 1><<<dim3(4 * 128), b256, 0, stream>>>(
        zq, wq1, db1, P0);                                 // P0 (packed)
    convt4s2_mfma<128, 32, 32, 64, 4, 1, 1><<<dim3(4 * 512), b256, 0, stream>>>(
        (const unsigned*)P0, wq2, db2, P1);                // P1 (packed)
    convt4s2_mfma<64, 64, 64, 32, 2, 1, 0><<<dim3(4 * 2048), b256, 0, stream>>>(
        (const unsigned*)P1, wq3, db3, g3o);               // g3o (fp32)
    convt4s2_k<32, 128, 128, 3, 3, 1, 2><<<dim3(2048), b256, 0, stream>>>(
        g3o, dw4, db4, out);                               // tanh -> d_out
}